// Round 5
// baseline (1541.017 us; speedup 1.0000x reference)
//
#include <hip/hip_runtime.h>

// Problem constants (fixed in the reference file)
#define GT 8192      // time steps
#define GN 1024      // state dim
#define GM 512       // input dim
#define CCH 1024     // scan chunks
#define SCH 8        // steps per chunk

typedef __attribute__((ext_vector_type(8))) short bf16x8;
typedef __attribute__((ext_vector_type(4))) float f32x4;

__device__ __forceinline__ unsigned short f2bf(float x) {   // RNE fp32->bf16
    unsigned int u = __float_as_uint(x);
    u += 0x7FFF + ((u >> 16) & 1);
    return (unsigned short)(u >> 16);
}
__device__ __forceinline__ float bf2f(unsigned short b) {
    return __uint_as_float(((unsigned int)b) << 16);
}
__device__ __forceinline__ void split2(float x, unsigned short& h0, unsigned short& h1) {
    h0 = f2bf(x);
    h1 = f2bf(x - bf2f(h0));
}
__device__ __forceinline__ void split3(float x, unsigned short& s0,
                                       unsigned short& s1, unsigned short& s2) {
    s0 = f2bf(x); float r = x - bf2f(s0);
    s1 = f2bf(r); r -= bf2f(s1);
    s2 = f2bf(r);
}

// async 16B global->LDS (dest is wave-uniform base; HW scatters lane*16)
__device__ __forceinline__ void gl16(const unsigned short* g, unsigned short* l) {
    __builtin_amdgcn_global_load_lds(
        (const __attribute__((address_space(1))) unsigned int*)g,
        (__attribute__((address_space(3))) unsigned int*)l, 16, 0, 0);
}

// ---------------------------------------------------------------------------
// Plane x plane GEMM.  Out = alpha * A2limb @ B2limb^T (+beta*Cin) (+I).
// A: 2-limb bf16 planes, element (r,k) at  f = r*alda + k, stored at
//    f ^ (((f>>aldsh)&3)<<3); limb1 at +asz.  (alda may be < K: PU concat trick.)
// B: 2-limb planes [1024][1024], lda 1024, limb1 at +bsz.
// K = 1024, N = 1024 always.  3 limb-products (a0b0,a0b1,a1b0) per tile.
// Pout: optional 2-limb plane emission of the result (pmode 1: final v,
//       pmode 2: pure alpha*acc), plane row = (pstep8 ? gr>>3 : gr)+prowoff.
// ---------------------------------------------------------------------------
template <int BM>
__global__ __launch_bounds__(256) void gemm_pp(
    const unsigned short* __restrict__ Ap, long asz, int alda, int aldsh,
    const unsigned short* __restrict__ Bp, long bsz,
    const float* __restrict__ Cin, long cb, long ldc, float beta,
    float* __restrict__ Out, long ob, long ldo,
    unsigned short* __restrict__ Pout, long psz, int pstep8, int prowoff, int pmode,
    int M, float alpha, int add_id)
{
    constexpr int MT = BM / 32;            // 16-tiles per wave dim
    __shared__ __align__(16) unsigned short At[2][BM][32];
    __shared__ __align__(16) unsigned short Bt[2][BM][32];

    const int tid = threadIdx.x;
    const int lane = tid & 63;
    const int w = tid >> 6;                // 4 waves, 2x2
    const int wr = (w >> 1) * (BM / 2);
    const int wc = (w & 1) * (BM / 2);
    const int l16 = lane & 15, koff = lane >> 4;
    const int row0 = blockIdx.x * BM;
    const int col0 = blockIdx.y * BM;

    f32x4 acc[MT][MT] = {};

    constexpr int CPL = BM / 16;           // 1KB chunks per limb per operand
    constexpr int CHW = CPL;               // chunks per wave (4*CPL total / 4 waves)
    const int lr4 = lane >> 2;             // row within 16-row chunk
    const int lg = lane & 3;               // 16B granule

    for (int k0 = 0; k0 < 1024; k0 += 32) {
        #pragma unroll
        for (int ci = 0; ci < CHW; ++ci) {
            const int c = w * CHW + ci;
            const int op = c / (2 * CPL);
            const int limb = (c / CPL) & 1;
            const int rb = (c % CPL) * 16;
            const int lr = rb + lr4;
            const int kl = ((lg ^ (lr & 3)) << 3);
            const unsigned short* g;
            unsigned short* l;
            if (op == 0) {
                long f = (long)(row0 + lr) * alda + (k0 + kl);
                f ^= ((f >> aldsh) & 3) << 3;
                g = Ap + (limb ? asz : 0) + f;
                l = &At[limb][rb][0];
            } else {
                long f = (long)(col0 + lr) * 1024 + (k0 + kl);
                f ^= ((f >> 10) & 3) << 3;
                g = Bp + (limb ? bsz : 0) + f;
                l = &Bt[limb][rb][0];
            }
            gl16(g, l);
        }
        __syncthreads();

        bf16x8 a0[MT], a1[MT], b0[MT], b1[MT];
        #pragma unroll
        for (int mi = 0; mi < MT; ++mi) {
            int lr = wr + mi * 16 + l16;
            int off = (koff * 8) ^ ((lr & 3) << 3);
            a0[mi] = *(const bf16x8*)&At[0][lr][off];
            a1[mi] = *(const bf16x8*)&At[1][lr][off];
        }
        #pragma unroll
        for (int ni = 0; ni < MT; ++ni) {
            int lr = wc + ni * 16 + l16;
            int off = (koff * 8) ^ ((lr & 3) << 3);
            b0[ni] = *(const bf16x8*)&Bt[0][lr][off];
            b1[ni] = *(const bf16x8*)&Bt[1][lr][off];
        }
        #pragma unroll
        for (int mi = 0; mi < MT; ++mi)
            #pragma unroll
            for (int ni = 0; ni < MT; ++ni) {
                f32x4 cc = acc[mi][ni];
                cc = __builtin_amdgcn_mfma_f32_16x16x32_bf16(a0[mi], b0[ni], cc, 0, 0, 0);
                cc = __builtin_amdgcn_mfma_f32_16x16x32_bf16(a0[mi], b1[ni], cc, 0, 0, 0);
                cc = __builtin_amdgcn_mfma_f32_16x16x32_bf16(a1[mi], b0[ni], cc, 0, 0, 0);
                acc[mi][ni] = cc;
            }
        __syncthreads();
    }

    #pragma unroll
    for (int mi = 0; mi < MT; ++mi) {
        #pragma unroll
        for (int r = 0; r < 4; ++r) {
            const int gr = row0 + wr + mi * 16 + koff * 4 + r;
            if (gr >= M) continue;
            #pragma unroll
            for (int ni = 0; ni < MT; ++ni) {
                const int gc = col0 + wc + ni * 16 + l16;
                float vp = alpha * acc[mi][ni][r];
                float v = vp;
                if (Cin) v += beta * Cin[cb + (long)gr * ldc + gc];
                if (add_id && gr == gc) v += 1.f;
                Out[ob + (long)gr * ldo + gc] = v;
                if (Pout && (!pstep8 || (gr & 7) == 0)) {
                    int prow = (pstep8 ? (gr >> 3) : gr) + prowoff;
                    float pv = (pmode == 2) ? vp : v;
                    long f = (long)prow * 1024 + gc;
                    f ^= (long)((prow & 3) << 3);
                    unsigned short h0 = f2bf(pv);
                    Pout[f] = h0;
                    Pout[psz + f] = f2bf(pv - bf2f(h0));
                }
            }
        }
    }
}

// ---- X (cnt fp32, row length 2^ldsh) -> swizzled 2-limb planes (scaled) ----
__global__ void split_pl_k(const float* __restrict__ X, unsigned short* __restrict__ P,
                           long psz, int ldsh, float s, long cnt)
{
    long i = (long)blockIdx.x * 256 + threadIdx.x;
    if (i >= cnt) return;
    float v = s * X[i];
    long f = i ^ (((i >> ldsh) & 3) << 3);
    unsigned short h0 = f2bf(v);
    P[f] = h0;
    P[psz + f] = f2bf(v - bf2f(h0));
}

// ---- out[r][c] = s*in[c][r] + id  (out R x C, in C x R) + optional planes ----
__global__ void tr_scale_pl(float* __restrict__ out, const float* __restrict__ in,
                            int R, int C, float s, int add_id,
                            unsigned short* __restrict__ P, long psz)
{
    __shared__ float t[32][33];
    const int tx = threadIdx.x & 31, ty4 = threadIdx.x >> 5;
    const int r0 = blockIdx.x * 32, c0 = blockIdx.y * 32;
    #pragma unroll
    for (int i = 0; i < 4; ++i)
        t[ty4 * 4 + i][tx] = in[(long)(c0 + ty4 * 4 + i) * R + r0 + tx];
    __syncthreads();
    #pragma unroll
    for (int i = 0; i < 4; ++i) {
        int r = r0 + ty4 * 4 + i, c = c0 + tx;
        float v = s * t[tx][ty4 * 4 + i];
        if (add_id && r == c) v += 1.f;
        out[(long)r * C + c] = v;
        if (P) {
            long f = (long)r * C + c;
            f ^= (long)((r & 3) << 3);
            unsigned short h0 = f2bf(v);
            P[f] = h0;
            P[psz + f] = f2bf(v - bf2f(h0));
        }
    }
}

// ---- X [1024][1024] fp32 -> PS=planes(X), PT=planes(X^T) (swizzled) ----
__global__ void tsp_k(const float* __restrict__ X, unsigned short* __restrict__ PS,
                      unsigned short* __restrict__ PT)
{
    __shared__ float t[32][33];
    const int tx = threadIdx.x & 31, ty4 = threadIdx.x >> 5;
    const int r0 = blockIdx.x * 32, c0 = blockIdx.y * 32;
    #pragma unroll
    for (int i = 0; i < 4; ++i)
        t[ty4 * 4 + i][tx] = X[(long)(r0 + ty4 * 4 + i) * 1024 + c0 + tx];
    __syncthreads();
    if (PS) {
        #pragma unroll
        for (int i = 0; i < 4; ++i) {
            int r = r0 + ty4 * 4 + i;
            long f = (long)r * 1024 + c0 + tx;
            f ^= (long)((r & 3) << 3);
            float v = t[ty4 * 4 + i][tx];
            unsigned short h0 = f2bf(v);
            PS[f] = h0;
            PS[(long)(1 << 20) + f] = f2bf(v - bf2f(h0));
        }
    }
    if (PT) {
        #pragma unroll
        for (int i = 0; i < 4; ++i) {
            int r = c0 + ty4 * 4 + i;
            long f = (long)r * 1024 + r0 + tx;
            f ^= (long)((r & 3) << 3);
            float v = t[tx][ty4 * 4 + i];
            unsigned short h0 = f2bf(v);
            PT[f] = h0;
            PT[(long)(1 << 20) + f] = f2bf(v - bf2f(h0));
        }
    }
}

// ---- Gcat planes: PG[n][k] = k<512 ? h*(V1T[k][n]-V2T[k][n]) : h*V2T[k-512][n] ----
__global__ void gtsp_k(const float* __restrict__ V1T, const float* __restrict__ V2T,
                       unsigned short* __restrict__ PG, float h)
{
    __shared__ float t[32][33];
    const int tx = threadIdx.x & 31, ty4 = threadIdx.x >> 5;
    const int k0 = blockIdx.x * 32, n0 = blockIdx.y * 32, z = blockIdx.z;
    #pragma unroll
    for (int i = 0; i < 4; ++i) {
        long idx = (long)(k0 + ty4 * 4 + i) * 1024 + n0 + tx;
        t[ty4 * 4 + i][tx] = (z == 0) ? h * (V1T[idx] - V2T[idx]) : h * V2T[idx];
    }
    __syncthreads();
    #pragma unroll
    for (int i = 0; i < 4; ++i) {
        int r = n0 + ty4 * 4 + i;
        long f = (long)r * 1024 + z * 512 + k0 + tx;
        f ^= (long)((r & 3) << 3);
        float v = t[tx][ty4 * 4 + i];
        unsigned short h0 = f2bf(v);
        PG[f] = h0;
        PG[(long)(1 << 20) + f] = f2bf(v - bf2f(h0));
    }
}

// dst[db + r*ds + c] = src[sb + r*ss + c]
__global__ void copy_rows_k(float* __restrict__ dst, long db, long ds,
                            const float* __restrict__ src, long sb, long ss, int ncols)
{
    int r = blockIdx.y;
    int c = blockIdx.x * 256 + threadIdx.x;
    if (c < ncols) dst[db + (long)r * ds + c] = src[sb + (long)r * ss + c];
}

// dst[db + r*ds + c] += src[r*ncols + c]
__global__ void add_rows_k(float* __restrict__ dst, long db, long ds,
                           const float* __restrict__ src, int ncols)
{
    int r = blockIdx.y;
    int c = blockIdx.x * 256 + threadIdx.x;
    if (c < ncols) dst[db + (long)r * ds + c] += src[(long)r * ncols + c];
}

__global__ void scale_add_id_k(float* __restrict__ dst, const float* __restrict__ src,
                               float s, int n)
{
    int r = blockIdx.y;
    int c = blockIdx.x * 256 + threadIdx.x;
    if (c < n) dst[(long)r * n + c] = s * src[(long)r * n + c] + ((r == c) ? 1.f : 0.f);
}

__global__ void scale_copy_k(float* __restrict__ dst, const float* __restrict__ src,
                             float s, long cnt)
{
    long i = (long)blockIdx.x * 256 + threadIdx.x;
    if (i < cnt) dst[i] = s * src[i];
}

__global__ void g1g2_k(float* __restrict__ g1, float* __restrict__ g2,
                       const float* __restrict__ v1, const float* __restrict__ v2,
                       float h, long cnt)
{
    long i = (long)blockIdx.x * 256 + threadIdx.x;
    if (i < cnt) {
        float a = v1[i], b = v2[i];
        g1[i] = h * (a - b);
        g2[i] = h * b;
    }
}

// ---------------------------------------------------------------------------
// FALLBACK (round-3, 3-limb, 30 MB ws) — only if ws_size < 46 MB.
// ---------------------------------------------------------------------------
template <int BM, int BN, bool TRANSB>
__global__ __launch_bounds__(256) void gemm_mfma(
    const float* __restrict__ A, long ab, long lda,
    const float* __restrict__ B,
    const float* __restrict__ Cin, long cb, long ldc, float beta,
    float* __restrict__ Out, long ob, long ldo,
    int M, int Nn, int K, float alpha, int add_id)
{
    constexpr int LDT = 40;
    __shared__ unsigned short At[3][BM][LDT];
    __shared__ unsigned short Bt[3][BN][LDT];
    const int tid = threadIdx.x;
    const int lane = tid & 63;
    const int wid = tid >> 6;
    const int row0 = blockIdx.x * BM;
    const int col0 = blockIdx.y * BN;
    constexpr int MR = BM / 32;
    constexpr int NR = BN / 32;
    const int wrow = (wid >> 1) * (BM / 2);
    const int wcol = (wid & 1) * (BN / 2);
    const int l16 = lane & 15;
    const int koff = lane >> 4;
    f32x4 acc[MR][NR] = {};

    for (int k0 = 0; k0 < K; k0 += 32) {
        #pragma unroll
        for (int i = 0; i < BM / 32; ++i) {
            int r = i * 32 + (tid >> 3);
            int kl = (tid & 7) * 4;
            int gr = row0 + r;
            float4 v = make_float4(0.f, 0.f, 0.f, 0.f);
            if (gr < M) v = *(const float4*)&A[ab + (long)gr * lda + (k0 + kl)];
            unsigned short h0[4], h1[4], h2[4];
            split3(v.x, h0[0], h1[0], h2[0]);
            split3(v.y, h0[1], h1[1], h2[1]);
            split3(v.z, h0[2], h1[2], h2[2]);
            split3(v.w, h0[3], h1[3], h2[3]);
            *(ushort4*)&At[0][r][kl] = make_ushort4(h0[0], h0[1], h0[2], h0[3]);
            *(ushort4*)&At[1][r][kl] = make_ushort4(h1[0], h1[1], h1[2], h1[3]);
            *(ushort4*)&At[2][r][kl] = make_ushort4(h2[0], h2[1], h2[2], h2[3]);
        }
        if (TRANSB) {
            #pragma unroll
            for (int i = 0; i < BN / 32; ++i) {
                int r = i * 32 + (tid >> 3);
                int kl = (tid & 7) * 4;
                float4 v = *(const float4*)&B[(long)(col0 + r) * K + (k0 + kl)];
                unsigned short h0[4], h1[4], h2[4];
                split3(v.x, h0[0], h1[0], h2[0]);
                split3(v.y, h0[1], h1[1], h2[1]);
                split3(v.z, h0[2], h1[2], h2[2]);
                split3(v.w, h0[3], h1[3], h2[3]);
                *(ushort4*)&Bt[0][r][kl] = make_ushort4(h0[0], h0[1], h0[2], h0[3]);
                *(ushort4*)&Bt[1][r][kl] = make_ushort4(h1[0], h1[1], h1[2], h1[3]);
                *(ushort4*)&Bt[2][r][kl] = make_ushort4(h2[0], h2[1], h2[2], h2[3]);
            }
        } else {
            constexpr int TPK = BN / 4;
            #pragma unroll
            for (int i = 0; i < BN / 32; ++i) {
                int kl = i * (256 / TPK) + tid / TPK;
                int nl = (tid % TPK) * 4;
                float4 v = *(const float4*)&B[(long)(k0 + kl) * Nn + (col0 + nl)];
                unsigned short s0, s1, s2;
                split3(v.x, s0, s1, s2);
                Bt[0][nl + 0][kl] = s0; Bt[1][nl + 0][kl] = s1; Bt[2][nl + 0][kl] = s2;
                split3(v.y, s0, s1, s2);
                Bt[0][nl + 1][kl] = s0; Bt[1][nl + 1][kl] = s1; Bt[2][nl + 1][kl] = s2;
                split3(v.z, s0, s1, s2);
                Bt[0][nl + 2][kl] = s0; Bt[1][nl + 2][kl] = s1; Bt[2][nl + 2][kl] = s2;
                split3(v.w, s0, s1, s2);
                Bt[0][nl + 3][kl] = s0; Bt[1][nl + 3][kl] = s1; Bt[2][nl + 3][kl] = s2;
            }
        }
        __syncthreads();
        bf16x8 bf[NR][3];
        #pragma unroll
        for (int nr = 0; nr < NR; ++nr) {
            int brow = wcol + nr * 16 + l16;
            #pragma unroll
            for (int s = 0; s < 3; ++s)
                bf[nr][s] = *(const bf16x8*)&Bt[s][brow][koff * 8];
        }
        #pragma unroll
        for (int mr = 0; mr < MR; ++mr) {
            int arow = wrow + mr * 16 + l16;
            bf16x8 a0 = *(const bf16x8*)&At[0][arow][koff * 8];
            bf16x8 a1 = *(const bf16x8*)&At[1][arow][koff * 8];
            bf16x8 a2 = *(const bf16x8*)&At[2][arow][koff * 8];
            #pragma unroll
            for (int nr = 0; nr < NR; ++nr) {
                f32x4 c = acc[mr][nr];
                c = __builtin_amdgcn_mfma_f32_16x16x32_bf16(a0, bf[nr][0], c, 0, 0, 0);
                c = __builtin_amdgcn_mfma_f32_16x16x32_bf16(a0, bf[nr][1], c, 0, 0, 0);
                c = __builtin_amdgcn_mfma_f32_16x16x32_bf16(a1, bf[nr][0], c, 0, 0, 0);
                c = __builtin_amdgcn_mfma_f32_16x16x32_bf16(a0, bf[nr][2], c, 0, 0, 0);
                c = __builtin_amdgcn_mfma_f32_16x16x32_bf16(a1, bf[nr][1], c, 0, 0, 0);
                c = __builtin_amdgcn_mfma_f32_16x16x32_bf16(a2, bf[nr][0], c, 0, 0, 0);
                acc[mr][nr] = c;
            }
        }
        __syncthreads();
    }
    #pragma unroll
    for (int mr = 0; mr < MR; ++mr) {
        #pragma unroll
        for (int r = 0; r < 4; ++r) {
            int gr = row0 + wrow + mr * 16 + koff * 4 + r;
            if (gr >= M) continue;
            #pragma unroll
            for (int nr = 0; nr < NR; ++nr) {
                int gc = col0 + wcol + nr * 16 + l16;
                float v = alpha * acc[mr][nr][r];
                if (Cin) v += beta * Cin[cb + (long)gr * ldc + gc];
                if (add_id && gr == gc) v += 1.f;
                Out[ob + (long)gr * ldo + gc] = v;
            }
        }
    }
}

static void fallback_launch(void* const* d_in, void* d_out, void* d_ws,
                            hipStream_t stream)
{
    const float* y0 = (const float*)d_in[1];
    const float* u  = (const float*)d_in[2];
    const float* Am = (const float*)d_in[3];
    const float* Bm = (const float*)d_in[4];
    float* Yout = (float*)d_out;
    float* w = (float*)d_ws;
    const float h = 0.01f;
    const int N = GN;

    float* Eyy = w;
    float* T1  = Eyy + (long)N * N;
    float* T2  = T1  + (long)N * N;
    float* V1  = T2  + (long)N * N;
    float* Vt  = V1  + (long)N * GM;
    float* V2  = Vt  + (long)N * GM;
    float* G1  = V2  + (long)N * GM;
    float* G2  = G1  + (long)N * GM;
    float* Z   = G2  + (long)N * GM;
    float* Zt  = Z   + (long)CCH * N;
    dim3 blk(256);

    auto gemm = [&](bool transb, const float* A, long ab, long lda,
                    const float* B, const float* Cin, long cb, long ldc, float beta,
                    float* Out, long ob, long ldo,
                    int M, int Nn, int K, float alpha, int add_id) {
        if (M > 1536 && (Nn % 128) == 0) {
            dim3 grid((M + 127) / 128, Nn / 128);
            if (transb)
                gemm_mfma<128, 128, true><<<grid, blk, 0, stream>>>(A, ab, lda, B, Cin, cb, ldc, beta, Out, ob, ldo, M, Nn, K, alpha, add_id);
            else
                gemm_mfma<128, 128, false><<<grid, blk, 0, stream>>>(A, ab, lda, B, Cin, cb, ldc, beta, Out, ob, ldo, M, Nn, K, alpha, add_id);
        } else {
            dim3 grid((M + 63) / 64, Nn / 64);
            if (transb)
                gemm_mfma<64, 64, true><<<grid, blk, 0, stream>>>(A, ab, lda, B, Cin, cb, ldc, beta, Out, ob, ldo, M, Nn, K, alpha, add_id);
            else
                gemm_mfma<64, 64, false><<<grid, blk, 0, stream>>>(A, ab, lda, B, Cin, cb, ldc, beta, Out, ob, ldo, M, Nn, K, alpha, add_id);
        }
    };

    scale_add_id_k<<<dim3(4, N), blk, 0, stream>>>(T1, Am, h / 5.f, N);
    {
        float* pc = T1; float* pn = T2;
        for (int k = 4; k >= 1; --k) {
            float* out = (k == 1) ? Eyy : pn;
            gemm(false, Am, 0, N, pc, nullptr, 0, 0, 0.f, out, 0, N, N, N, N, h / (float)k, 1);
            pn = pc; pc = out;
        }
    }
    const long NM = (long)N * GM;
    scale_copy_k<<<dim3((unsigned)((NM + 255) / 256)), blk, 0, stream>>>(V1, Bm, 1.f / 120.f, NM);
    {
        const float f1[4] = {1.f / 24.f, 1.f / 6.f, 0.5f, 1.f};
        float* pc = V1; float* pn = Vt;
        for (int j = 3; j >= 0; --j) {
            gemm(false, Am, 0, N, pc, Bm, 0, GM, f1[3 - j], pn, 0, GM, N, GM, N, h, 0);
            float* t = pc; pc = pn; pn = t;
        }
    }
    scale_copy_k<<<dim3((unsigned)((NM + 255) / 256)), blk, 0, stream>>>(V2, Bm, 1.f / 720.f, NM);
    {
        const float f2[4] = {1.f / 120.f, 1.f / 24.f, 1.f / 6.f, 0.5f};
        float* pc = V2; float* pn = Vt;
        for (int j = 3; j >= 0; --j) {
            gemm(false, Am, 0, N, pc, Bm, 0, GM, f2[3 - j], pn, 0, GM, N, GM, N, h, 0);
            float* t = pc; pc = pn; pn = t;
        }
    }
    g1g2_k<<<dim3((unsigned)((NM + 255) / 256)), blk, 0, stream>>>(G1, G2, V1, V2, h, NM);
    gemm(true, u, 0, GM, G1, nullptr, 0, 0, 0.f, Yout, (long)N, N, GT - 1, N, GM, 1.f, 0);
    gemm(true, u, GM, GM, G2, Yout, (long)N, N, 1.f, Yout, (long)N, N, GT - 1, N, GM, 1.f, 0);
    copy_rows_k<<<dim3(4, 1), blk, 0, stream>>>(Yout, 0, 0, y0, 0, 0, N);
    for (int s = 2; s <= SCH; ++s) {
        int Mr = (GT - 1 - s) / SCH + 1;
        gemm(true, Yout, (long)(s - 1) * N, (long)SCH * N, Eyy,
             Yout, (long)s * N, (long)SCH * N, 1.f,
             Yout, (long)s * N, (long)SCH * N, Mr, N, N, 1.f, 0);
    }
    copy_rows_k<<<dim3(4, 1), blk, 0, stream>>>(Z, 0, 0, y0, 0, 0, N);
    copy_rows_k<<<dim3(4, CCH - 1), blk, 0, stream>>>(Z, (long)N, (long)N,
                                                      Yout, (long)SCH * N, (long)SCH * N, N);
    gemm(false, Eyy, 0, N, Eyy, nullptr, 0, 0, 0.f, T1, 0, N, N, N, N, 1.f, 0);
    gemm(false, T1, 0, N, T1, nullptr, 0, 0, 0.f, T2, 0, N, N, N, N, 1.f, 0);
    gemm(false, T2, 0, N, T2, nullptr, 0, 0, 0.f, T1, 0, N, N, N, N, 1.f, 0);
    {
        float* Mc = T1; float* Mo = T2;
        float* Zc = Z;  float* Zn = Zt;
        for (int p = 0; p < 10; ++p) {
            int o = 1 << p;
            gemm(true, Zc, 0, N, Mc, Zc, (long)o * N, N, 1.f,
                 Zn, (long)o * N, N, CCH - o, N, N, 1.f, 0);
            copy_rows_k<<<dim3(4, o), blk, 0, stream>>>(Zn, 0, N, Zc, 0, N, N);
            if (p < 9) {
                gemm(false, Mc, 0, N, Mc, nullptr, 0, 0, 0.f, Mo, 0, N, N, N, N, 1.f, 0);
                float* t = Mc; Mc = Mo; Mo = t;
            }
            float* t = Zc; Zc = Zn; Zn = t;
        }
        copy_rows_k<<<dim3(4, CCH), blk, 0, stream>>>(Yout, 0, (long)SCH * N, Zc, 0, N, N);
        float* Q = Zc; float* Qt = Zn;
        for (int s = 1; s <= SCH - 1; ++s) {
            gemm(true, Q, 0, N, Eyy, nullptr, 0, 0, 0.f, Qt, 0, N, CCH, N, N, 1.f, 0);
            int Mr = (GT - 1 - s) / SCH + 1;
            add_rows_k<<<dim3(4, Mr), blk, 0, stream>>>(Yout, (long)s * N, (long)SCH * N, Qt, N);
            float* t = Q; Q = Qt; Qt = t;
        }
    }
}

// ---------------------------------------------------------------------------
extern "C" void kernel_launch(void* const* d_in, const int* in_sizes, int n_in,
                              void* d_out, int out_size, void* d_ws, size_t ws_size,
                              hipStream_t stream)
{
    (void)in_sizes; (void)n_in; (void)out_size;
    const size_t NEED = 46ull * 1024 * 1024;
    if (ws_size < NEED) { fallback_launch(d_in, d_out, d_ws, stream); return; }

    const float* y0 = (const float*)d_in[1];
    const float* u  = (const float*)d_in[2];
    const float* Am = (const float*)d_in[3];
    const float* Bm = (const float*)d_in[4];
    float* Yout = (float*)d_out;
    char* w = (char*)d_ws;
    const float h = 0.01f;
    const size_t MB = 1024 * 1024;
    const long P1M = 1 << 20;                  // plane limb offset (1024x1024)

    // ws regions (44 MB), time-phased:
    // R0 [0,16MB): early T1/T2/EyyT fp32 -> PU planes -> Zc/Zn fp32 + PZ1/PZ2
    float* T1   = (float*)(w);
    float* T2   = (float*)(w + 4 * MB);
    float* EyyT = (float*)(w + 8 * MB);
    unsigned short* PU  = (unsigned short*)(w);
    float* Zc0 = (float*)(w);
    float* Zn0 = (float*)(w + 4 * MB);
    unsigned short* PZ1 = (unsigned short*)(w + 8 * MB);
    unsigned short* PZ2 = (unsigned short*)(w + 12 * MB);
    unsigned short* PY1 = (unsigned short*)(w + 16 * MB);
    unsigned short* PY2 = (unsigned short*)(w + 20 * MB);
    unsigned short* PA  = (unsigned short*)(w + 24 * MB);  // -> PW later
    unsigned short* PW  = PA;
    unsigned short* PE  = (unsigned short*)(w + 28 * MB);
    unsigned short* PWT = (unsigned short*)(w + 32 * MB);
    unsigned short* PG  = (unsigned short*)(w + 36 * MB);
    float* BmT = (float*)(w + 36 * MB);        // dead before PG written
    float* Wf  = (float*)(w + 40 * MB);

    dim3 blk(256);
    dim3 tgrid(32, 32);

    auto G64 = [&](const unsigned short* Ap, long asz, int alda, int aldsh,
                   const unsigned short* Bp,
                   const float* Cin, long cb, long ldc, float beta,
                   float* Outp, long ob, long ldo,
                   unsigned short* Pp, long psz, int prowoff, int pmode,
                   int M, float alpha, int add_id) {
        dim3 grid((M + 63) / 64, 16);
        gemm_pp<64><<<grid, blk, 0, stream>>>(Ap, asz, alda, aldsh, Bp, P1M,
            Cin, cb, ldc, beta, Outp, ob, ldo, Pp, psz, 0, prowoff, pmode, M, alpha, add_id);
    };

    // 1. planes(Am)
    split_pl_k<<<dim3(4096), blk, 0, stream>>>(Am, PA, P1M, 10, 1.f, (long)1 << 20);

    // 2. expm in transposed space: seed T^T = I + (h/5)A^T (fp32 + planes)
    tr_scale_pl<<<tgrid, blk, 0, stream>>>(T1, Am, 1024, 1024, h / 5.f, 1, PY1, P1M);
    // chain k=4..1: out = (h/k)*(P^T @ A^T) + I
    G64(PY1, P1M, 1024, 10, PA, nullptr, 0, 0, 0.f, T2, 0, 1024, PY2, P1M, 0, 1, 1024, h / 4.f, 1);
    G64(PY2, P1M, 1024, 10, PA, nullptr, 0, 0, 0.f, T1, 0, 1024, PY1, P1M, 0, 1, 1024, h / 3.f, 1);
    G64(PY1, P1M, 1024, 10, PA, nullptr, 0, 0, 0.f, T2, 0, 1024, PY2, P1M, 0, 1, 1024, h / 2.f, 1);
    G64(PY2, P1M, 1024, 10, PA, nullptr, 0, 0, 0.f, EyyT, 0, 1024, PWT, P1M, 0, 1, 1024, h, 1);
    // 3. planes(E) from E^T
    tsp_k<<<tgrid, blk, 0, stream>>>(EyyT, nullptr, PE);

    // 4. B^T fp32 + phi-chain seeds (planes only)
    tr_scale_pl<<<dim3(16, 32), blk, 0, stream>>>(BmT, Bm, 512, 1024, 1.f, 0, nullptr, 0);
    const long PVS = (long)512 * 1024;         // V-plane limb offset
    unsigned short* PV1c = PY1;                // 2MB set inside PY1
    unsigned short* PV2c = PY1 + (1 << 20);
    unsigned short* PV1n = PY2;
    unsigned short* PV2n = PY2 + (1 << 20);
    split_pl_k<<<dim3(2048), blk, 0, stream>>>(BmT, PV1c, PVS, 10, 1.f / 120.f, PVS);
    split_pl_k<<<dim3(2048), blk, 0, stream>>>(BmT, PV2c, PVS, 10, 1.f / 720.f, PVS);
    // phi chains (transposed space, M=512): V^T <- h*(V^T@A^T) + f*B^T
    float* v1f[2] = {T1, T1 + (512 * 1024)};
    float* v2f[2] = {T2, T2 + (512 * 1024)};
    {
        const float f1[4] = {1.f / 24.f, 1.f / 6.f, 0.5f, 1.f};
        const float f2[4] = {1.f / 120.f, 1.f / 24.f, 1.f / 6.f, 0.5f};
        for (int j = 0; j < 4; ++j) {
            G64(PV1c, PVS, 1024, 10, PA, BmT, 0, 1024, f1[j],
                v1f[j & 1], 0, 1024, PV1n, PVS, 0, 1, 512, h, 0);
            G64(PV2c, PVS, 1024, 10, PA, BmT, 0, 1024, f2[j],
                v2f[j & 1], 0, 1024, PV2n, PVS, 0, 1, 512, h, 0);
            unsigned short* t = PV1c; PV1c = PV1n; PV1n = t;
            t = PV2c; PV2c = PV2n; PV2n = t;
        }
    }
    // 5. planes(Gcat) from final V1^T (v1f[1]), V2^T (v2f[1])
    gtsp_k<<<dim3(16, 32, 2), blk, 0, stream>>>(v1f[1], v2f[1], PG, h);

    // 6. planes(u) — concat trick: A row t spans u rows t, t+1 via lda=512
    split_pl_k<<<dim3(16384), blk, 0, stream>>>(u, PU, (long)1 << 22, 9, 1.f, (long)1 << 22);

    // 7. c-staging: Yout[t] = [u_{t-1}|u_t] @ Gcat^T, t=1..8191 (+ planes of rows==1 mod 8)
    {
        dim3 grid((GT - 1 + 127) / 128, 8);
        gemm_pp<128><<<grid, blk, 0, stream>>>(PU, (long)1 << 22, 512, 9, PG, P1M,
            nullptr, 0, 0, 0.f, Yout, 1024, 1024, PY1, P1M, 1, 0, 1, GT - 1, 1.f, 0);
    }
    copy_rows_k<<<dim3(4, 1), blk, 0, stream>>>(Yout, 0, 0, y0, 0, 0, 1024);

    // 8. phase 1: within-chunk scan, in place; planes chained through epilogues
    {
        unsigned short* pc = PY1; unsigned short* pn = PY2;
        for (int s = 2; s <= SCH; ++s) {
            int M = (s <= 7) ? 1024 : 1023;
            unsigned short* pout = (s <= 7) ? pn : PZ1;
            int prowoff = (s <= 7) ? 0 : 1;
            G64(pc, P1M, 1024, 10, PE,
                Yout, (long)s * 1024, 8192, 1.f,
                Yout, (long)s * 1024, 8192,
                pout, P1M, prowoff, 1, M, 1.f, 0);
            unsigned short* t = pc; pc = pn; pn = t;
        }
    }

    // 9. phase 2 init: Z fp32 + plane row 0 (y0)
    split_pl_k<<<dim3(4), blk, 0, stream>>>(y0, PZ1, P1M, 10, 1.f, 1024);
    copy_rows_k<<<dim3(4, 1), blk, 0, stream>>>(Zc0, 0, 0, y0, 0, 0, 1024);
    copy_rows_k<<<dim3(4, CCH - 1), blk, 0, stream>>>(Zc0, 1024, 1024,
                                                      Yout, (long)SCH * 1024, (long)SCH * 1024, 1024);
    // squarings E -> E^2 -> E^4 -> E^8 (A/B planes; tsp rebuilds PW/PWT from fp32)
    G64(PE, P1M, 1024, 10, PWT, nullptr, 0, 0, 0.f, Wf, 0, 1024, nullptr, 0, 0, 0, 1024, 1.f, 0);
    tsp_k<<<tgrid, blk, 0, stream>>>(Wf, PW, PWT);
    G64(PW, P1M, 1024, 10, PWT, nullptr, 0, 0, 0.f, Wf, 0, 1024, nullptr, 0, 0, 0, 1024, 1.f, 0);
    tsp_k<<<tgrid, blk, 0, stream>>>(Wf, PW, PWT);
    G64(PW, P1M, 1024, 10, PWT, nullptr, 0, 0, 0.f, Wf, 0, 1024, nullptr, 0, 0, 0, 1024, 1.f, 0);
    tsp_k<<<tgrid, blk, 0, stream>>>(Wf, PW, PWT);

    // 10. doubling: Zn[i] = Zc[i] + Zc[i-o] @ W^T ; W <- W^2
    {
        float* Zc = Zc0; float* Zn = Zn0;
        unsigned short* PZc = PZ1; unsigned short* PZn = PZ2;
        for (int p = 0; p < 10; ++p) {
            int o = 1 << p;
            G64(PZc, P1M, 1024, 10, PW,
                Zc, (long)o * 1024, 1024, 1.f,
                Zn, (long)o * 1024, 1024,
                PZn, P1M, o, 1, 1024 - o, 1.f, 0);
            copy_rows_k<<<dim3(4, o), blk, 0, stream>>>(Zn, 0, 1024, Zc, 0, 1024, 1024);
            copy_rows_k<<<dim3(2, o), blk, 0, stream>>>((float*)PZn, 0, 512, (float*)PZc, 0, 512, 512);
            copy_rows_k<<<dim3(2, o), blk, 0, stream>>>((float*)(PZn + P1M), 0, 512,
                                                        (float*)(PZc + P1M), 0, 512, 512);
            if (p < 9) {
                G64(PW, P1M, 1024, 10, PWT, nullptr, 0, 0, 0.f, Wf, 0, 1024, nullptr, 0, 0, 0, 1024, 1.f, 0);
                tsp_k<<<tgrid, blk, 0, stream>>>(Wf, PW, PWT);
            }
            float* t = Zc; Zc = Zn; Zn = t;
            unsigned short* pt = PZc; PZc = PZn; PZn = pt;
        }
        // 11. phase 3: boundary rows exact, then y_{8i+s} += E^s z_i (s=1..7)
        copy_rows_k<<<dim3(4, CCH), blk, 0, stream>>>(Yout, 0, (long)SCH * 1024, Zc, 0, 1024, 1024);
        unsigned short* PQc = PZc; unsigned short* PQn = PY1;
        for (int s = 1; s <= SCH - 1; ++s) {
            G64(PQc, P1M, 1024, 10, PE,
                Yout, (long)s * 1024, 8192, 1.f,
                Yout, (long)s * 1024, 8192,
                (s < 7) ? PQn : nullptr, P1M, 0, 2, 1024, 1.f, 0);
            PQc = PQn;
            PQn = (PQn == PY1) ? PY2 : PY1;
        }
    }
}

// Round 6
// 1017.695 us; speedup vs baseline: 1.5142x; 1.5142x over previous
//
#include <hip/hip_runtime.h>

// Problem constants (fixed in the reference file)
#define GT 8192      // time steps
#define GN 1024      // state dim
#define GM 512       // input dim
#define CCH 1024     // scan chunks
#define SCH 8        // steps per chunk

typedef __attribute__((ext_vector_type(8))) short bf16x8;
typedef __attribute__((ext_vector_type(4))) float f32x4;

__device__ __forceinline__ unsigned short f2bf(float x) {   // RNE fp32->bf16
    unsigned int u = __float_as_uint(x);
    u += 0x7FFF + ((u >> 16) & 1);
    return (unsigned short)(u >> 16);
}
__device__ __forceinline__ float bf2f(unsigned short b) {
    return __uint_as_float(((unsigned int)b) << 16);
}
__device__ __forceinline__ void split2(float x, unsigned short& h0, unsigned short& h1) {
    h0 = f2bf(x);
    h1 = f2bf(x - bf2f(h0));
}
__device__ __forceinline__ void split3(float x, unsigned short& s0,
                                       unsigned short& s1, unsigned short& s2) {
    s0 = f2bf(x); float r = x - bf2f(s0);
    s1 = f2bf(r); r -= bf2f(s1);
    s2 = f2bf(r);
}
// storage swizzle: XOR bits 3-4 of the element index with (row>>1)&3.
// Involution (bits >= sh+1 unaffected by the XOR). sh = log2(row length).
__device__ __forceinline__ long swz(long e, int sh) {
    return e ^ (((e >> (sh + 1)) & 3) << 3);
}
// async 16B global->LDS (dest wave-uniform base; HW scatters lane*16; src per-lane)
__device__ __forceinline__ void gl16(const unsigned short* g, unsigned short* l) {
    __builtin_amdgcn_global_load_lds(
        (const __attribute__((address_space(1))) unsigned int*)g,
        (__attribute__((address_space(3))) unsigned int*)l, 16, 0, 0);
}

// ---------------------------------------------------------------------------
// Plane x plane GEMM, double-buffered single-barrier pipeline.
// Out = alpha * A2limb @ B2limb^T (+ Cin term) (+I).
// A planes: element (r,k) stored at swz(r*alda + k, aldsh); limb1 at +apsz.
// B planes: [1024][1024], sh=10, limb1 at +bpsz. K=1024, N=1024 fixed.
// 3 limb products (a0b0, a0b1, a1b0) -> ~fp32 precision.
// Row mapping: trow = (gr < segN) ? gr + zoff : gr; row skipped if the mapped
// row crosses segN. Cin/Out/plane rows all use trow; A staging uses gr.
// Cin: fp32 (Cf) or 2-limb planes (Cp); coefficient beta (trow<bsplit) / betaB.
// Pout: 2-limb plane emission; pmode 1 = final v, 2 = pure alpha*acc;
//       pstep8: emit only when (trow&7)==0 at plane row trow>>3.
// ---------------------------------------------------------------------------
template <int BM>
__global__ __launch_bounds__(256) void gemm_pp(
    const unsigned short* __restrict__ Ap, long apsz, int alda, int aldsh,
    const unsigned short* __restrict__ Bp, long bpsz,
    const float* __restrict__ Cf, long cfb, long cfld,
    const unsigned short* __restrict__ Cp, long cpsz, int cmask,
    float beta, float betaB, int bsplit,
    float* __restrict__ Of, long ofb, long ofld,
    unsigned short* __restrict__ Pout, long ppsz, int pstep8, int pmode,
    int segN, int zoff,
    int M, float alpha, int add_id)
{
    constexpr int MT = BM / 32;            // 16-tiles per wave dim
    constexpr int CPL = BM / 16;           // 1KB staging chunks per (op,limb)
    __shared__ __align__(16) unsigned short At[2][2][BM][32];  // [buf][limb][row][k]
    __shared__ __align__(16) unsigned short Bt[2][2][BM][32];

    const int tid = threadIdx.x;
    const int lane = tid & 63;
    const int w = tid >> 6;                // 4 waves, 2x2
    const int wr = (w >> 1) * (BM / 2);
    const int wc = (w & 1) * (BM / 2);
    const int l16 = lane & 15, koff = lane >> 4;
    const int row0 = blockIdx.x * BM;
    const int col0 = blockIdx.y * BM;
    const int lr4 = lane >> 2;             // row within 16-row chunk
    const int lg = lane & 3;               // physical 16B granule

    f32x4 acc[MT][MT] = {};

    auto stage = [&](int bsel, int k0) {
        #pragma unroll
        for (int ci = 0; ci < CPL; ++ci) {
            const int c = w * CPL + ci;
            const int op = c / (2 * CPL);
            const int limb = (c / CPL) & 1;
            const int rb = (c % CPL) * 16;
            const int lr = rb + lr4;
            const int q = lg ^ ((lr >> 1) & 3);      // logical granule wanted
            long e; int sh;
            if (op == 0) { e = (long)(row0 + lr) * alda + k0 + (q << 3); sh = aldsh; }
            else         { e = (long)(col0 + lr) * 1024 + k0 + (q << 3); sh = 10; }
            long f = swz(e, sh);
            const unsigned short* g =
                (op == 0 ? Ap + (limb ? apsz : 0) : Bp + (limb ? bpsz : 0)) + f;
            unsigned short* l = (op == 0 ? &At[bsel][limb][rb][0]
                                         : &Bt[bsel][limb][rb][0]);
            gl16(g, l);
        }
    };

    stage(0, 0);
    __syncthreads();
    int cur = 0;
    for (int k0 = 0; k0 < 1024; k0 += 32) {
        if (k0 + 32 < 1024) stage(cur ^ 1, k0 + 32);   // loads fly under MFMA

        bf16x8 a0[MT], a1[MT], b0[MT], b1[MT];
        #pragma unroll
        for (int mi = 0; mi < MT; ++mi) {
            int lr = wr + mi * 16 + l16;
            int off = (koff ^ ((lr >> 1) & 3)) << 3;
            a0[mi] = *(const bf16x8*)&At[cur][0][lr][off];
            a1[mi] = *(const bf16x8*)&At[cur][1][lr][off];
        }
        #pragma unroll
        for (int ni = 0; ni < MT; ++ni) {
            int lr = wc + ni * 16 + l16;
            int off = (koff ^ ((lr >> 1) & 3)) << 3;
            b0[ni] = *(const bf16x8*)&Bt[cur][0][lr][off];
            b1[ni] = *(const bf16x8*)&Bt[cur][1][lr][off];
        }
        #pragma unroll
        for (int mi = 0; mi < MT; ++mi)
            #pragma unroll
            for (int ni = 0; ni < MT; ++ni) {
                f32x4 cc = acc[mi][ni];
                cc = __builtin_amdgcn_mfma_f32_16x16x32_bf16(a0[mi], b0[ni], cc, 0, 0, 0);
                cc = __builtin_amdgcn_mfma_f32_16x16x32_bf16(a0[mi], b1[ni], cc, 0, 0, 0);
                cc = __builtin_amdgcn_mfma_f32_16x16x32_bf16(a1[mi], b0[ni], cc, 0, 0, 0);
                acc[mi][ni] = cc;
            }
        __syncthreads();   // drains this iter's stage (vmcnt0) + syncs LDS reuse
        cur ^= 1;
    }

    // epilogue
    #pragma unroll
    for (int mi = 0; mi < MT; ++mi) {
        #pragma unroll
        for (int r = 0; r < 4; ++r) {
            const int gr = row0 + wr + mi * 16 + koff * 4 + r;
            if (gr >= M) continue;
            const int trow = (gr < segN) ? gr + zoff : gr;
            if (gr < segN && trow >= segN) continue;
            #pragma unroll
            for (int ni = 0; ni < MT; ++ni) {
                const int gc = col0 + wc + ni * 16 + l16;
                float vp = alpha * acc[mi][ni][r];
                float v = vp;
                float bb = (trow < bsplit) ? beta : betaB;
                if (bb != 0.f) {
                    int crow = trow & cmask;
                    if (Cf) v += bb * Cf[cfb + (long)crow * cfld + gc];
                    else if (Cp) {
                        long f = swz((long)crow * 1024 + gc, 10);
                        v += bb * (bf2f(Cp[f]) + bf2f(Cp[cpsz + f]));
                    }
                }
                if (add_id && gr == gc) v += 1.f;
                if (Of) Of[ofb + (long)trow * ofld + gc] = v;
                if (Pout && (!pstep8 || (trow & 7) == 0)) {
                    int prow = pstep8 ? (trow >> 3) : trow;
                    long f = swz((long)prow * 1024 + gc, 10);
                    float pv = (pmode == 2) ? vp : v;
                    unsigned short h0 = f2bf(pv);
                    Pout[f] = h0;
                    Pout[ppsz + f] = f2bf(pv - bf2f(h0));
                }
            }
        }
    }
}

// ---- X (cnt fp32, rows of length 2^ldsh) -> swizzled 2-limb planes ----
__global__ void split_pl_k(const float* __restrict__ X, unsigned short* __restrict__ P,
                           long psz, int ldsh, float s, long cnt)
{
    long i = (long)blockIdx.x * 256 + threadIdx.x;
    if (i >= cnt) return;
    float v = s * X[i];
    long f = swz(i, ldsh);
    unsigned short h0 = f2bf(v);
    P[f] = h0;
    P[psz + f] = f2bf(v - bf2f(h0));
}

// ---- planes of s*in^T (+I): out R x 1024, in is 1024 x R fp32 (lda R) ----
__global__ void trsp_k(const float* __restrict__ in, int R, float s, int add_id,
                       unsigned short* __restrict__ P, long psz, int roff)
{
    __shared__ float t[32][33];
    const int tx = threadIdx.x & 31, ty4 = threadIdx.x >> 5;
    const int r0 = blockIdx.x * 32, c0 = blockIdx.y * 32;   // out-row/out-col tiles
    #pragma unroll
    for (int i = 0; i < 4; ++i)
        t[ty4 * 4 + i][tx] = in[(long)(c0 + ty4 * 4 + i) * R + r0 + tx];
    __syncthreads();
    #pragma unroll
    for (int i = 0; i < 4; ++i) {
        int r = r0 + ty4 * 4 + i, c = c0 + tx;
        float v = s * t[tx][ty4 * 4 + i];
        if (add_id && r == c) v += 1.f;
        long f = swz((long)(r + roff) * 1024 + c, 10);
        unsigned short h0 = f2bf(v);
        P[f] = h0;
        P[psz + f] = f2bf(v - bf2f(h0));
    }
}

// ---- planes(X) from planes(X^T): OUT[c][r] = IN[irow0+r][c] ----
__global__ void tspp_k(const unsigned short* __restrict__ IN, long ipsz, long irow0,
                       unsigned short* __restrict__ OUT, long opsz)
{
    __shared__ float t[32][33];
    const int tx = threadIdx.x & 31, ty4 = threadIdx.x >> 5;
    const int r0 = blockIdx.x * 32, c0 = blockIdx.y * 32;
    #pragma unroll
    for (int i = 0; i < 4; ++i) {
        long f = swz((irow0 + r0 + ty4 * 4 + i) * 1024 + c0 + tx, 10);
        t[ty4 * 4 + i][tx] = bf2f(IN[f]) + bf2f(IN[ipsz + f]);
    }
    __syncthreads();
    #pragma unroll
    for (int i = 0; i < 4; ++i) {
        int orow = c0 + ty4 * 4 + i;
        long f = swz((long)orow * 1024 + r0 + tx, 10);
        float v = t[tx][ty4 * 4 + i];
        unsigned short h0 = f2bf(v);
        OUT[f] = h0;
        OUT[opsz + f] = f2bf(v - bf2f(h0));
    }
}

// ---- Gcat planes from stacked [V1^T; V2^T] planes ----
__global__ void gtspp_k(const unsigned short* __restrict__ PV, long vpsz,
                        unsigned short* __restrict__ PG, long gpsz, float h)
{
    __shared__ float t[32][33];
    const int tx = threadIdx.x & 31, ty4 = threadIdx.x >> 5;
    const int k0 = blockIdx.x * 32, n0 = blockIdx.y * 32, z = blockIdx.z;
    #pragma unroll
    for (int i = 0; i < 4; ++i) {
        int k = k0 + ty4 * 4 + i, n = n0 + tx;
        long f2 = swz((long)(512 + k) * 1024 + n, 10);
        float v2 = bf2f(PV[f2]) + bf2f(PV[vpsz + f2]);
        float v;
        if (z == 0) {
            long f1 = swz((long)k * 1024 + n, 10);
            v = h * (bf2f(PV[f1]) + bf2f(PV[vpsz + f1]) - v2);
        } else v = h * v2;
        t[ty4 * 4 + i][tx] = v;
    }
    __syncthreads();
    #pragma unroll
    for (int i = 0; i < 4; ++i) {
        int n = n0 + ty4 * 4 + i, kk = z * 512 + k0 + tx;
        long f = swz((long)n * 1024 + kk, 10);
        float v = t[tx][ty4 * 4 + i];
        unsigned short h0 = f2bf(v);
        PG[f] = h0;
        PG[gpsz + f] = f2bf(v - bf2f(h0));
    }
}

// ---- Yout[8r] = reconstruct(P row r) ----
__global__ void cprows_pl(float* __restrict__ Y, const unsigned short* __restrict__ P,
                          long psz)
{
    int r = blockIdx.y;
    int c = blockIdx.x * 256 + threadIdx.x;
    long f = swz((long)r * 1024 + c, 10);
    Y[(long)r * 8192 + c] = bf2f(P[f]) + bf2f(P[psz + f]);
}

// dst[db + r*ds + c] = src[sb + r*ss + c]
__global__ void copy_rows_k(float* __restrict__ dst, long db, long ds,
                            const float* __restrict__ src, long sb, long ss, int ncols)
{
    int r = blockIdx.y;
    int c = blockIdx.x * 256 + threadIdx.x;
    if (c < ncols) dst[db + (long)r * ds + c] = src[sb + (long)r * ss + c];
}

// dst[db + r*ds + c] += src[r*ncols + c]
__global__ void add_rows_k(float* __restrict__ dst, long db, long ds,
                           const float* __restrict__ src, int ncols)
{
    int r = blockIdx.y;
    int c = blockIdx.x * 256 + threadIdx.x;
    if (c < ncols) dst[db + (long)r * ds + c] += src[(long)r * ncols + c];
}

__global__ void scale_add_id_k(float* __restrict__ dst, const float* __restrict__ src,
                               float s, int n)
{
    int r = blockIdx.y;
    int c = blockIdx.x * 256 + threadIdx.x;
    if (c < n) dst[(long)r * n + c] = s * src[(long)r * n + c] + ((r == c) ? 1.f : 0.f);
}

__global__ void scale_copy_k(float* __restrict__ dst, const float* __restrict__ src,
                             float s, long cnt)
{
    long i = (long)blockIdx.x * 256 + threadIdx.x;
    if (i < cnt) dst[i] = s * src[i];
}

__global__ void g1g2_k(float* __restrict__ g1, float* __restrict__ g2,
                       const float* __restrict__ v1, const float* __restrict__ v2,
                       float h, long cnt)
{
    long i = (long)blockIdx.x * 256 + threadIdx.x;
    if (i < cnt) {
        float a = v1[i], b = v2[i];
        g1[i] = h * (a - b);
        g2[i] = h * b;
    }
}

// ---------------------------------------------------------------------------
// FALLBACK (round-3, 3-limb, 30 MB ws) — only if ws_size < 46 MB.
// ---------------------------------------------------------------------------
template <int BM, int BN, bool TRANSB>
__global__ __launch_bounds__(256) void gemm_mfma(
    const float* __restrict__ A, long ab, long lda,
    const float* __restrict__ B,
    const float* __restrict__ Cin, long cb, long ldc, float beta,
    float* __restrict__ Out, long ob, long ldo,
    int M, int Nn, int K, float alpha, int add_id)
{
    constexpr int LDT = 40;
    __shared__ unsigned short At[3][BM][LDT];
    __shared__ unsigned short Bt[3][BN][LDT];
    const int tid = threadIdx.x;
    const int lane = tid & 63;
    const int wid = tid >> 6;
    const int row0 = blockIdx.x * BM;
    const int col0 = blockIdx.y * BN;
    constexpr int MR = BM / 32;
    constexpr int NR = BN / 32;
    const int wrow = (wid >> 1) * (BM / 2);
    const int wcol = (wid & 1) * (BN / 2);
    const int l16 = lane & 15;
    const int koff = lane >> 4;
    f32x4 acc[MR][NR] = {};

    for (int k0 = 0; k0 < K; k0 += 32) {
        #pragma unroll
        for (int i = 0; i < BM / 32; ++i) {
            int r = i * 32 + (tid >> 3);
            int kl = (tid & 7) * 4;
            int gr = row0 + r;
            float4 v = make_float4(0.f, 0.f, 0.f, 0.f);
            if (gr < M) v = *(const float4*)&A[ab + (long)gr * lda + (k0 + kl)];
            unsigned short h0[4], h1[4], h2[4];
            split3(v.x, h0[0], h1[0], h2[0]);
            split3(v.y, h0[1], h1[1], h2[1]);
            split3(v.z, h0[2], h1[2], h2[2]);
            split3(v.w, h0[3], h1[3], h2[3]);
            *(ushort4*)&At[0][r][kl] = make_ushort4(h0[0], h0[1], h0[2], h0[3]);
            *(ushort4*)&At[1][r][kl] = make_ushort4(h1[0], h1[1], h1[2], h1[3]);
            *(ushort4*)&At[2][r][kl] = make_ushort4(h2[0], h2[1], h2[2], h2[3]);
        }
        if (TRANSB) {
            #pragma unroll
            for (int i = 0; i < BN / 32; ++i) {
                int r = i * 32 + (tid >> 3);
                int kl = (tid & 7) * 4;
                float4 v = *(const float4*)&B[(long)(col0 + r) * K + (k0 + kl)];
                unsigned short h0[4], h1[4], h2[4];
                split3(v.x, h0[0], h1[0], h2[0]);
                split3(v.y, h0[1], h1[1], h2[1]);
                split3(v.z, h0[2], h1[2], h2[2]);
                split3(v.w, h0[3], h1[3], h2[3]);
                *(ushort4*)&Bt[0][r][kl] = make_ushort4(h0[0], h0[1], h0[2], h0[3]);
                *(ushort4*)&Bt[1][r][kl] = make_ushort4(h1[0], h1[1], h1[2], h1[3]);
                *(ushort4*)&Bt[2][r][kl] = make_ushort4(h2[0], h2[1], h2[2], h2[3]);
            }
        } else {
            constexpr int TPK = BN / 4;
            #pragma unroll
            for (int i = 0; i < BN / 32; ++i) {
                int kl = i * (256 / TPK) + tid / TPK;
                int nl = (tid % TPK) * 4;
                float4 v = *(const float4*)&B[(long)(k0 + kl) * Nn + (col0 + nl)];
                unsigned short s0, s1, s2;
                split3(v.x, s0, s1, s2);
                Bt[0][nl + 0][kl] = s0; Bt[1][nl + 0][kl] = s1; Bt[2][nl + 0][kl] = s2;
                split3(v.y, s0, s1, s2);
                Bt[0][nl + 1][kl] = s0; Bt[1][nl + 1][kl] = s1; Bt[2][nl + 1][kl] = s2;
                split3(v.z, s0, s1, s2);
                Bt[0][nl + 2][kl] = s0; Bt[1][nl + 2][kl] = s1; Bt[2][nl + 2][kl] = s2;
                split3(v.w, s0, s1, s2);
                Bt[0][nl + 3][kl] = s0; Bt[1][nl + 3][kl] = s1; Bt[2][nl + 3][kl] = s2;
            }
        }
        __syncthreads();
        bf16x8 bf[NR][3];
        #pragma unroll
        for (int nr = 0; nr < NR; ++nr) {
            int brow = wcol + nr * 16 + l16;
            #pragma unroll
            for (int s = 0; s < 3; ++s)
                bf[nr][s] = *(const bf16x8*)&Bt[s][brow][koff * 8];
        }
        #pragma unroll
        for (int mr = 0; mr < MR; ++mr) {
            int arow = wrow + mr * 16 + l16;
            bf16x8 a0 = *(const bf16x8*)&At[0][arow][koff * 8];
            bf16x8 a1 = *(const bf16x8*)&At[1][arow][koff * 8];
            bf16x8 a2 = *(const bf16x8*)&At[2][arow][koff * 8];
            #pragma unroll
            for (int nr = 0; nr < NR; ++nr) {
                f32x4 c = acc[mr][nr];
                c = __builtin_amdgcn_mfma_f32_16x16x32_bf16(a0, bf[nr][0], c, 0, 0, 0);
                c = __builtin_amdgcn_mfma_f32_16x16x32_bf16(a0, bf[nr][1], c, 0, 0, 0);
                c = __builtin_amdgcn_mfma_f32_16x16x32_bf16(a1, bf[nr][0], c, 0, 0, 0);
                c = __builtin_amdgcn_mfma_f32_16x16x32_bf16(a0, bf[nr][2], c, 0, 0, 0);
                c = __builtin_amdgcn_mfma_f32_16x16x32_bf16(a1, bf[nr][1], c, 0, 0, 0);
                c = __builtin_amdgcn_mfma_f32_16x16x32_bf16(a2, bf[nr][0], c, 0, 0, 0);
                acc[mr][nr] = c;
            }
        }
        __syncthreads();
    }
    #pragma unroll
    for (int mr = 0; mr < MR; ++mr) {
        #pragma unroll
        for (int r = 0; r < 4; ++r) {
            int gr = row0 + wrow + mr * 16 + koff * 4 + r;
            if (gr >= M) continue;
            #pragma unroll
            for (int nr = 0; nr < NR; ++nr) {
                int gc = col0 + wcol + nr * 16 + l16;
                float v = alpha * acc[mr][nr][r];
                if (Cin) v += beta * Cin[cb + (long)gr * ldc + gc];
                if (add_id && gr == gc) v += 1.f;
                Out[ob + (long)gr * ldo + gc] = v;
            }
        }
    }
}

static void fallback_launch(void* const* d_in, void* d_out, void* d_ws,
                            hipStream_t stream)
{
    const float* y0 = (const float*)d_in[1];
    const float* u  = (const float*)d_in[2];
    const float* Am = (const float*)d_in[3];
    const float* Bm = (const float*)d_in[4];
    float* Yout = (float*)d_out;
    float* w = (float*)d_ws;
    const float h = 0.01f;
    const int N = GN;

    float* Eyy = w;
    float* T1  = Eyy + (long)N * N;
    float* T2  = T1  + (long)N * N;
    float* V1  = T2  + (long)N * N;
    float* Vt  = V1  + (long)N * GM;
    float* V2  = Vt  + (long)N * GM;
    float* G1  = V2  + (long)N * GM;
    float* G2  = G1  + (long)N * GM;
    float* Z   = G2  + (long)N * GM;
    float* Zt  = Z   + (long)CCH * N;
    dim3 blk(256);

    auto gemm = [&](bool transb, const float* A, long ab, long lda,
                    const float* B, const float* Cin, long cb, long ldc, float beta,
                    float* Out, long ob, long ldo,
                    int M, int Nn, int K, float alpha, int add_id) {
        if (M > 1536 && (Nn % 128) == 0) {
            dim3 grid((M + 127) / 128, Nn / 128);
            if (transb)
                gemm_mfma<128, 128, true><<<grid, blk, 0, stream>>>(A, ab, lda, B, Cin, cb, ldc, beta, Out, ob, ldo, M, Nn, K, alpha, add_id);
            else
                gemm_mfma<128, 128, false><<<grid, blk, 0, stream>>>(A, ab, lda, B, Cin, cb, ldc, beta, Out, ob, ldo, M, Nn, K, alpha, add_id);
        } else {
            dim3 grid((M + 63) / 64, Nn / 64);
            if (transb)
                gemm_mfma<64, 64, true><<<grid, blk, 0, stream>>>(A, ab, lda, B, Cin, cb, ldc, beta, Out, ob, ldo, M, Nn, K, alpha, add_id);
            else
                gemm_mfma<64, 64, false><<<grid, blk, 0, stream>>>(A, ab, lda, B, Cin, cb, ldc, beta, Out, ob, ldo, M, Nn, K, alpha, add_id);
        }
    };

    scale_add_id_k<<<dim3(4, N), blk, 0, stream>>>(T1, Am, h / 5.f, N);
    {
        float* pc = T1; float* pn = T2;
        for (int k = 4; k >= 1; --k) {
            float* out = (k == 1) ? Eyy : pn;
            gemm(false, Am, 0, N, pc, nullptr, 0, 0, 0.f, out, 0, N, N, N, N, h / (float)k, 1);
            pn = pc; pc = out;
        }
    }
    const long NM = (long)N * GM;
    scale_copy_k<<<dim3((unsigned)((NM + 255) / 256)), blk, 0, stream>>>(V1, Bm, 1.f / 120.f, NM);
    {
        const float f1[4] = {1.f / 24.f, 1.f / 6.f, 0.5f, 1.f};
        float* pc = V1; float* pn = Vt;
        for (int j = 3; j >= 0; --j) {
            gemm(false, Am, 0, N, pc, Bm, 0, GM, f1[3 - j], pn, 0, GM, N, GM, N, h, 0);
            float* t = pc; pc = pn; pn = t;
        }
    }
    scale_copy_k<<<dim3((unsigned)((NM + 255) / 256)), blk, 0, stream>>>(V2, Bm, 1.f / 720.f, NM);
    {
        const float f2[4] = {1.f / 120.f, 1.f / 24.f, 1.f / 6.f, 0.5f};
        float* pc = V2; float* pn = Vt;
        for (int j = 3; j >= 0; --j) {
            gemm(false, Am, 0, N, pc, Bm, 0, GM, f2[3 - j], pn, 0, GM, N, GM, N, h, 0);
            float* t = pc; pc = pn; pn = t;
        }
    }
    g1g2_k<<<dim3((unsigned)((NM + 255) / 256)), blk, 0, stream>>>(G1, G2, V1, V2, h, NM);
    gemm(true, u, 0, GM, G1, nullptr, 0, 0, 0.f, Yout, (long)N, N, GT - 1, N, GM, 1.f, 0);
    gemm(true, u, GM, GM, G2, Yout, (long)N, N, 1.f, Yout, (long)N, N, GT - 1, N, GM, 1.f, 0);
    copy_rows_k<<<dim3(4, 1), blk, 0, stream>>>(Yout, 0, 0, y0, 0, 0, N);
    for (int s = 2; s <= SCH; ++s) {
        int Mr = (GT - 1 - s) / SCH + 1;
        gemm(true, Yout, (long)(s - 1) * N, (long)SCH * N, Eyy,
             Yout, (long)s * N, (long)SCH * N, 1.f,
             Yout, (long)s * N, (long)SCH * N, Mr, N, N, 1.f, 0);
    }
    copy_rows_k<<<dim3(4, 1), blk, 0, stream>>>(Z, 0, 0, y0, 0, 0, N);
    copy_rows_k<<<dim3(4, CCH - 1), blk, 0, stream>>>(Z, (long)N, (long)N,
                                                      Yout, (long)SCH * N, (long)SCH * N, N);
    gemm(false, Eyy, 0, N, Eyy, nullptr, 0, 0, 0.f, T1, 0, N, N, N, N, 1.f, 0);
    gemm(false, T1, 0, N, T1, nullptr, 0, 0, 0.f, T2, 0, N, N, N, N, 1.f, 0);
    gemm(false, T2, 0, N, T2, nullptr, 0, 0, 0.f, T1, 0, N, N, N, N, 1.f, 0);
    {
        float* Mc = T1; float* Mo = T2;
        float* Zc = Z;  float* Zn = Zt;
        for (int p = 0; p < 10; ++p) {
            int o = 1 << p;
            gemm(true, Zc, 0, N, Mc, Zc, (long)o * N, N, 1.f,
                 Zn, (long)o * N, N, CCH - o, N, N, 1.f, 0);
            copy_rows_k<<<dim3(4, o), blk, 0, stream>>>(Zn, 0, N, Zc, 0, N, N);
            if (p < 9) {
                gemm(false, Mc, 0, N, Mc, nullptr, 0, 0, 0.f, Mo, 0, N, N, N, N, 1.f, 0);
                float* t = Mc; Mc = Mo; Mo = t;
            }
            float* t = Zc; Zc = Zn; Zn = t;
        }
        copy_rows_k<<<dim3(4, CCH), blk, 0, stream>>>(Yout, 0, (long)SCH * N, Zc, 0, N, N);
        float* Q = Zc; float* Qt = Zn;
        for (int s = 1; s <= SCH - 1; ++s) {
            gemm(true, Q, 0, N, Eyy, nullptr, 0, 0, 0.f, Qt, 0, N, CCH, N, N, 1.f, 0);
            int Mr = (GT - 1 - s) / SCH + 1;
            add_rows_k<<<dim3(4, Mr), blk, 0, stream>>>(Yout, (long)s * N, (long)SCH * N, Qt, N);
            float* t = Q; Q = Qt; Qt = t;
        }
    }
}

// ---------------------------------------------------------------------------
extern "C" void kernel_launch(void* const* d_in, const int* in_sizes, int n_in,
                              void* d_out, int out_size, void* d_ws, size_t ws_size,
                              hipStream_t stream)
{
    (void)in_sizes; (void)n_in; (void)out_size;
    const size_t NEED = 46ull * 1024 * 1024;
    if (ws_size < NEED) { fallback_launch(d_in, d_out, d_ws, stream); return; }

    const float* y0 = (const float*)d_in[1];
    const float* u  = (const float*)d_in[2];
    const float* Am = (const float*)d_in[3];
    const float* Bm = (const float*)d_in[4];
    float* Yout = (float*)d_out;
    char* w = (char*)d_ws;
    const float h = 0.01f;
    const size_t MB = 1024 * 1024;
    const long P1M = 1 << 20;                  // 1024x1024 plane limb stride
    const long P2M = 1 << 21;                  // 2048x1024 (PZW)
    const long PUS = 1 << 22;                  // 8192x512  (PU)
    const long PBS = 1 << 19;                  // 512x1024  (PBT)
    const int  BIG = 1 << 30;

    // ws layout (42 MB, time-phased):
    unsigned short* PZW1 = (unsigned short*)(w);            // [0,8)   (= PU limb0)
    unsigned short* PZW2 = (unsigned short*)(w + 8 * MB);   // [8,16)  (= PU limb1)
    unsigned short* PU   = (unsigned short*)(w);            // [0,16)  c-staging only
    unsigned short* PET  = (unsigned short*)(w + 16 * MB);  // planes(E^T)
    unsigned short* PE   = (unsigned short*)(w + 20 * MB);  // planes(E)
    unsigned short* PG   = (unsigned short*)(w + 24 * MB);  // planes(Gcat)
    unsigned short* PY1  = (unsigned short*)(w + 28 * MB);  // ping
    unsigned short* PY2  = (unsigned short*)(w + 32 * MB);  // pong
    unsigned short* PA   = (unsigned short*)(w + 36 * MB);  // planes(A) -> later PW
    unsigned short* PW   = PA;
    unsigned short* PBT  = (unsigned short*)(w + 40 * MB);  // planes(B^T)

    dim3 blk(256);

    // ---- 1. planes(Am) ----
    split_pl_k<<<dim3(4096), blk, 0, stream>>>(Am, PA, P1M, 10, 1.f, (long)1 << 20);

    // ---- 2. expm (transposed space): seed planes(I + (h/5)A^T), Horner k=4..1 ----
    trsp_k<<<dim3(32, 32), blk, 0, stream>>>(Am, 1024, h / 5.f, 1, PY1, P1M, 0);
    {
        const float al[4] = {h / 4.f, h / 3.f, h / 2.f, h};
        unsigned short* pc = PY1; unsigned short* pn = PY2;
        for (int k = 0; k < 4; ++k) {
            unsigned short* pout = (k == 3) ? PET : pn;
            gemm_pp<64><<<dim3(16, 16), blk, 0, stream>>>(
                pc, P1M, 1024, 10, PA, P1M,
                nullptr, 0, 0, nullptr, 0, -1, 0.f, 0.f, BIG,
                nullptr, 0, 0, pout, P1M, 0, 1, BIG, 0, 1024, al[k], 1);
            unsigned short* t = pc; pc = pn; pn = t;
        }
    }
    tspp_k<<<dim3(32, 32), blk, 0, stream>>>(PET, P1M, 0, PE, P1M);

    // ---- 3. phi chains, stacked [V1^T; V2^T] (M=1024) ----
    trsp_k<<<dim3(16, 32), blk, 0, stream>>>(Bm, 512, 1.f / 120.f, 0, PY1, P1M, 0);
    trsp_k<<<dim3(16, 32), blk, 0, stream>>>(Bm, 512, 1.f / 720.f, 0, PY1, P1M, 512);
    trsp_k<<<dim3(16, 32), blk, 0, stream>>>(Bm, 512, 1.f, 0, PBT, PBS, 0);
    {
        const float f1[4] = {1.f / 24.f, 1.f / 6.f, 0.5f, 1.f};
        const float f2[4] = {1.f / 120.f, 1.f / 24.f, 1.f / 6.f, 0.5f};
        unsigned short* pc = PY1; unsigned short* pn = PY2;
        for (int j = 0; j < 4; ++j) {
            gemm_pp<64><<<dim3(16, 16), blk, 0, stream>>>(
                pc, P1M, 1024, 10, PA, P1M,
                nullptr, 0, 0, PBT, PBS, 511, f1[j], f2[j], 512,
                nullptr, 0, 0, pn, P1M, 0, 1, BIG, 0, 1024, h, 0);
            unsigned short* t = pc; pc = pn; pn = t;
        }  // final in PY1
    }
    gtspp_k<<<dim3(16, 32, 2), blk, 0, stream>>>(PY1, P1M, PG, P1M, h);

    // ---- 4. planes(u) (concat trick: c-staging A row t spans u rows t,t+1) ----
    split_pl_k<<<dim3(16384), blk, 0, stream>>>(u, PU, PUS, 9, 1.f, PUS);

    // ---- 5. c-staging: Yout[t] = [u_{t-1}|u_t] @ Gcat^T + planes of rows {8i+1} ----
    gemm_pp<128><<<dim3(64, 8), blk, 0, stream>>>(
        PU, PUS, 512, 9, PG, P1M,
        nullptr, 0, 0, nullptr, 0, -1, 0.f, 0.f, BIG,
        Yout, 1024, 1024, PY1, P1M, 1, 1, BIG, 0, GT - 1, 1.f, 0);

    // ---- 6. phase 1: within-chunk scan (A chained through plane emissions) ----
    {
        unsigned short* pc = PY1; unsigned short* pn = PY2;
        for (int s = 2; s <= 7; ++s) {
            gemm_pp<64><<<dim3(16, 16), blk, 0, stream>>>(
                pc, P1M, 1024, 10, PE, P1M,
                Yout, (long)s * 1024, 8192, nullptr, 0, -1, 1.f, 0.f, BIG,
                Yout, (long)s * 1024, 8192, pn, P1M, 0, 1, BIG, 0, 1024, 1.f, 0);
            unsigned short* t = pc; pc = pn; pn = t;
        }
        // s=8 -> boundary rows {8(i+1)}; plane row i+1 via zoff=1 (trow shift)
        gemm_pp<64><<<dim3(16, 16), blk, 0, stream>>>(
            pc, P1M, 1024, 10, PE, P1M,
            Yout, 0, 8192, nullptr, 0, -1, 1.f, 0.f, BIG,
            Yout, 0, 8192, PZW1, P2M, 0, 1, BIG, 1, 1023, 1.f, 0);
    }
    // z_0 = y0 -> PZW1 plane row 0
    split_pl_k<<<dim3(4), blk, 0, stream>>>(y0, PZW1, P2M, 10, 1.f, 1024);

    // ---- 7. pre-squarings E->E^2->E^4->E^8 (W^T planes; B = planes(W)) ----
    gemm_pp<64><<<dim3(16, 16), blk, 0, stream>>>(        // E^2,T
        PET, P1M, 1024, 10, PE, P1M,
        nullptr, 0, 0, nullptr, 0, -1, 0.f, 0.f, BIG,
        nullptr, 0, 0, PY1, P1M, 0, 1, BIG, 0, 1024, 1.f, 0);
    tspp_k<<<dim3(32, 32), blk, 0, stream>>>(PY1, P1M, 0, PW, P1M);
    gemm_pp<64><<<dim3(16, 16), blk, 0, stream>>>(        // E^4,T
        PY1, P1M, 1024, 10, PW, P1M,
        nullptr, 0, 0, nullptr, 0, -1, 0.f, 0.f, BIG,
        nullptr, 0, 0, PY2, P1M, 0, 1, BIG, 0, 1024, 1.f, 0);
    tspp_k<<<dim3(32, 32), blk, 0, stream>>>(PY2, P1M, 0, PW, P1M);
    gemm_pp<64><<<dim3(16, 16), blk, 0, stream>>>(        // E^8,T -> PZW1 rows 1024..
        PY2, P1M, 1024, 10, PW, P1M,
        nullptr, 0, 0, nullptr, 0, -1, 0.f, 0.f, BIG,
        nullptr, 0, 0, PZW1, P2M, 0, 1, BIG, 1024, 1024, 1.f, 0);
    tspp_k<<<dim3(32, 32), blk, 0, stream>>>(PZW1, P2M, 1024, PW, P1M);

    // ---- 8. fused doubling: [Zn; Wnext^T] = [Zc[i-o]@W^T + Zc[i]; W^T@W^T] ----
    {
        unsigned short* PZc = PZW1; unsigned short* PZn = PZW2;
        for (int p = 0; p < 10; ++p) {
            int o = 1 << p;
            int Mr = (p == 9) ? 1024 : 2048;
            gemm_pp<64><<<dim3((Mr + 63) / 64, 16), blk, 0, stream>>>(
                PZc, P2M, 1024, 10, PW, P1M,
                nullptr, 0, 0, PZc, P2M, -1, 1.f, 0.f, 1024,
                nullptr, 0, 0, PZn, P2M, 0, 1, 1024, o, Mr, 1.f, 0);
            // unchanged prefix rows [0,o): copy both plane limbs (rows of 512 floats)
            copy_rows_k<<<dim3(2, o), blk, 0, stream>>>(
                (float*)PZn, 0, 512, (float*)PZc, 0, 512, 512);
            copy_rows_k<<<dim3(2, o), blk, 0, stream>>>(
                (float*)PZn + (1 << 20), 0, 512, (float*)PZc + (1 << 20), 0, 512, 512);
            if (p < 9)
                tspp_k<<<dim3(32, 32), blk, 0, stream>>>(PZn, P2M, 1024, PW, P1M);
            unsigned short* t = PZc; PZc = PZn; PZn = t;
        }  // 10 swaps -> final Z planes back in PZW1
    }

    // ---- 9. phase 3: boundary rows exact, then y_{8i+s} += E^s z_i, s=1..7 ----
    cprows_pl<<<dim3(4, 1024), blk, 0, stream>>>(Yout, PZW1, P2M);
    copy_rows_k<<<dim3(4, 1), blk, 0, stream>>>(Yout, 0, 0, y0, 0, 0, 1024);
    {
        const unsigned short* pc = PZW1; long apsz = P2M;
        unsigned short* pn = PY1;
        for (int s = 1; s <= 7; ++s) {
            gemm_pp<64><<<dim3(16, 16), blk, 0, stream>>>(
                pc, apsz, 1024, 10, PE, P1M,
                Yout, (long)s * 1024, 8192, nullptr, 0, -1, 1.f, 0.f, BIG,
                Yout, (long)s * 1024, 8192,
                (s < 7) ? pn : nullptr, P1M, 0, 2, BIG, 0, 1024, 1.f, 0);
            pc = pn; apsz = P1M;
            pn = (pn == PY1) ? PY2 : PY1;
        }
    }
}

// Round 7
// 886.327 us; speedup vs baseline: 1.7387x; 1.1482x over previous
//
#include <hip/hip_runtime.h>

// Problem constants (fixed in the reference file)
#define GT 8192      // time steps
#define GN 1024      // state dim
#define GM 512       // input dim
#define CCH 1024     // scan chunks
#define SCH 8        // steps per chunk

typedef __attribute__((ext_vector_type(8))) short bf16x8;
typedef __attribute__((ext_vector_type(4))) float f32x4;

__device__ __forceinline__ unsigned short f2bf(float x) {   // RNE fp32->bf16
    unsigned int u = __float_as_uint(x);
    u += 0x7FFF + ((u >> 16) & 1);
    return (unsigned short)(u >> 16);
}
__device__ __forceinline__ float bf2f(unsigned short b) {
    return __uint_as_float(((unsigned int)b) << 16);
}
__device__ __forceinline__ void split2(float x, unsigned short& h0, unsigned short& h1) {
    h0 = f2bf(x);
    h1 = f2bf(x - bf2f(h0));
}
__device__ __forceinline__ void split3(float x, unsigned short& s0,
                                       unsigned short& s1, unsigned short& s2) {
    s0 = f2bf(x); float r = x - bf2f(s0);
    s1 = f2bf(r); r -= bf2f(s1);
    s2 = f2bf(r);
}
// storage swizzle: XOR element bits 3-4 with (row>>1)&3 (row = e>>sh).
// Involution; keeps LDS reads 2-way-max bank aliased (free).
__device__ __forceinline__ long swz(long e, int sh) {
    return e ^ (((e >> (sh + 1)) & 3) << 3);
}
// async 16B global->LDS (dest wave-uniform base; HW scatters lane*16; src per-lane)
__device__ __forceinline__ void gl16(const unsigned short* g, unsigned short* l) {
    __builtin_amdgcn_global_load_lds(
        (const __attribute__((address_space(1))) unsigned int*)g,
        (__attribute__((address_space(3))) unsigned int*)l, 16, 0, 0);
}

// ---------------------------------------------------------------------------
// Plane x plane GEMM, double-buffered, KH 32-k halves per barrier step.
// Out = aa * A2limb @ B2limb^T (+ bb * Cin) (+I),  K = 1024, N = 1024.
// A planes: element (r,k) at swz(r*alda + k, aldsh); limb1 at +apsz.
// B planes: [1024][1024], sh=10, limb1 at +bpsz.
// 3 limb products (a0b0, a0b1, a1b0) -> ~fp32 precision.
// Row mapping: trow = (gr < segN) ? gr + zoff : gr; skipped if crossing segN.
// aa = trow<asplit ? alpha : alphaB.
// bb = trow<bzero ? 0 : (trow<bsplit ? beta : betaB); Cin row = trow & cmask;
// Cin from fp32 (Cf) or 2-limb planes (Cp).
// Pout: plane emission (pmode 1: final v, 2: pure aa*acc); pstep8: only rows
// with trow%8==0 at plane row trow>>3.
// ---------------------------------------------------------------------------
template <int BM, int KH>
__global__ __launch_bounds__(256) void gemm_pp(
    const unsigned short* __restrict__ Ap, long apsz, int alda, int aldsh,
    const unsigned short* __restrict__ Bp, long bpsz,
    const float* __restrict__ Cf, long cfb, long cfld,
    const unsigned short* __restrict__ Cp, long cpsz, int cmask,
    int bzero, int bsplit, float beta, float betaB,
    float* __restrict__ Of, long ofb, long ofld,
    unsigned short* __restrict__ Pout, long ppsz, int pstep8, int pmode,
    int segN, int zoff,
    int M, float alpha, float alphaB, int asplit, int add_id)
{
    constexpr int MT = BM / 32;            // 16-tiles per wave dim
    constexpr int CPL = BM / 16;           // 1KB chunks per (op,limb,kk)
    __shared__ __align__(16) unsigned short At[2][KH][2][BM][32];
    __shared__ __align__(16) unsigned short Bt[2][KH][2][BM][32];

    const int tid = threadIdx.x;
    const int lane = tid & 63;
    const int w = tid >> 6;                // 4 waves, 2x2
    const int wr = (w >> 1) * (BM / 2);
    const int wc = (w & 1) * (BM / 2);
    const int l16 = lane & 15, koff = lane >> 4;
    const int row0 = blockIdx.x * BM;
    const int col0 = blockIdx.y * BM;
    const int lr4 = lane >> 2;             // row within 16-row chunk
    const int lg = lane & 3;               // physical 16B granule

    f32x4 acc[MT][MT] = {};

    auto stage = [&](int bsel, int k0) {
        #pragma unroll
        for (int ci = 0; ci < KH * CPL; ++ci) {
            const int c = w * (KH * CPL) + ci;
            const int op = c / (2 * KH * CPL);
            const int limb = (c / (KH * CPL)) & 1;
            const int kk = (c / CPL) % KH;
            const int rb = (c % CPL) * 16;
            const int lr = rb + lr4;
            const int q = lg ^ ((lr >> 1) & 3);      // logical granule wanted
            long e; int sh;
            if (op == 0) { e = (long)(row0 + lr) * alda + k0 + kk * 32 + (q << 3); sh = aldsh; }
            else         { e = (long)(col0 + lr) * 1024 + k0 + kk * 32 + (q << 3); sh = 10; }
            long f = swz(e, sh);
            const unsigned short* g =
                (op == 0 ? Ap + (limb ? apsz : 0) : Bp + (limb ? bpsz : 0)) + f;
            unsigned short* l = (op == 0 ? &At[bsel][kk][limb][rb][0]
                                         : &Bt[bsel][kk][limb][rb][0]);
            gl16(g, l);
        }
    };

    stage(0, 0);
    __syncthreads();
    int cur = 0;
    for (int k0 = 0; k0 < 1024; k0 += KH * 32) {
        if (k0 + KH * 32 < 1024) stage(cur ^ 1, k0 + KH * 32);  // fly under MFMA

        #pragma unroll
        for (int kk = 0; kk < KH; ++kk) {
            bf16x8 a0[MT], a1[MT], b0[MT], b1[MT];
            #pragma unroll
            for (int mi = 0; mi < MT; ++mi) {
                int lr = wr + mi * 16 + l16;
                int off = (koff ^ ((lr >> 1) & 3)) << 3;
                a0[mi] = *(const bf16x8*)&At[cur][kk][0][lr][off];
                a1[mi] = *(const bf16x8*)&At[cur][kk][1][lr][off];
            }
            #pragma unroll
            for (int ni = 0; ni < MT; ++ni) {
                int lr = wc + ni * 16 + l16;
                int off = (koff ^ ((lr >> 1) & 3)) << 3;
                b0[ni] = *(const bf16x8*)&Bt[cur][kk][0][lr][off];
                b1[ni] = *(const bf16x8*)&Bt[cur][kk][1][lr][off];
            }
            #pragma unroll
            for (int mi = 0; mi < MT; ++mi)
                #pragma unroll
                for (int ni = 0; ni < MT; ++ni) {
                    f32x4 cc = acc[mi][ni];
                    cc = __builtin_amdgcn_mfma_f32_16x16x32_bf16(a0[mi], b0[ni], cc, 0, 0, 0);
                    cc = __builtin_amdgcn_mfma_f32_16x16x32_bf16(a0[mi], b1[ni], cc, 0, 0, 0);
                    cc = __builtin_amdgcn_mfma_f32_16x16x32_bf16(a1[mi], b0[ni], cc, 0, 0, 0);
                    acc[mi][ni] = cc;
                }
        }
        __syncthreads();   // drains this iter's stage + syncs LDS reuse
        cur ^= 1;
    }

    // epilogue
    #pragma unroll
    for (int mi = 0; mi < MT; ++mi) {
        #pragma unroll
        for (int r = 0; r < 4; ++r) {
            const int gr = row0 + wr + mi * 16 + koff * 4 + r;
            if (gr >= M) continue;
            const int trow = (gr < segN) ? gr + zoff : gr;
            if (gr < segN && trow >= segN) continue;
            const float aa = (trow < asplit) ? alpha : alphaB;
            const float bb = (trow < bzero) ? 0.f : ((trow < bsplit) ? beta : betaB);
            #pragma unroll
            for (int ni = 0; ni < MT; ++ni) {
                const int gc = col0 + wc + ni * 16 + l16;
                float vp = aa * acc[mi][ni][r];
                float v = vp;
                if (bb != 0.f) {
                    int crow = trow & cmask;
                    if (Cf) v += bb * Cf[cfb + (long)crow * cfld + gc];
                    else if (Cp) {
                        long f = swz((long)crow * 1024 + gc, 10);
                        v += bb * (bf2f(Cp[f]) + bf2f(Cp[cpsz + f]));
                    }
                }
                if (add_id && gr == gc) v += 1.f;
                if (Of) Of[ofb + (long)trow * ofld + gc] = v;
                if (Pout && (!pstep8 || (trow & 7) == 0)) {
                    int prow = pstep8 ? (trow >> 3) : trow;
                    long f = swz((long)prow * 1024 + gc, 10);
                    float pv = (pmode == 2) ? vp : v;
                    unsigned short h0 = f2bf(pv);
                    Pout[f] = h0;
                    Pout[ppsz + f] = f2bf(pv - bf2f(h0));
                }
            }
        }
    }
}

// ---- X (cnt fp32, rows of length 2^ldsh) -> swizzled 2-limb planes ----
__global__ void split_pl_k(const float* __restrict__ X, unsigned short* __restrict__ P,
                           long psz, int ldsh, float s, long cnt)
{
    long i = (long)blockIdx.x * 256 + threadIdx.x;
    if (i >= cnt) return;
    float v = s * X[i];
    long f = swz(i, ldsh);
    unsigned short h0 = f2bf(v);
    P[f] = h0;
    P[psz + f] = f2bf(v - bf2f(h0));
}

// ---- planes of s*in^T (+I): out rows (roff+)0..R-1, in is 1024 x R fp32 ----
__global__ void trsp_k(const float* __restrict__ in, int R, float s, int add_id,
                       unsigned short* __restrict__ P, long psz, int roff)
{
    __shared__ float t[32][33];
    const int tx = threadIdx.x & 31, ty4 = threadIdx.x >> 5;
    const int r0 = blockIdx.x * 32, c0 = blockIdx.y * 32;
    #pragma unroll
    for (int i = 0; i < 4; ++i)
        t[ty4 * 4 + i][tx] = in[(long)(c0 + ty4 * 4 + i) * R + r0 + tx];
    __syncthreads();
    #pragma unroll
    for (int i = 0; i < 4; ++i) {
        int r = r0 + ty4 * 4 + i, c = c0 + tx;
        float v = s * t[tx][ty4 * 4 + i];
        if (add_id && r == c) v += 1.f;
        long f = swz((long)(r + roff) * 1024 + c, 10);
        unsigned short h0 = f2bf(v);
        P[f] = h0;
        P[psz + f] = f2bf(v - bf2f(h0));
    }
}

// ---- planes(X) from planes(X^T): OUT[c][r] = IN[irow0+r][c] ----
__global__ void tspp_k(const unsigned short* __restrict__ IN, long ipsz, long irow0,
                       unsigned short* __restrict__ OUT, long opsz)
{
    __shared__ float t[32][33];
    const int tx = threadIdx.x & 31, ty4 = threadIdx.x >> 5;
    const int r0 = blockIdx.x * 32, c0 = blockIdx.y * 32;
    #pragma unroll
    for (int i = 0; i < 4; ++i) {
        long f = swz((irow0 + r0 + ty4 * 4 + i) * 1024 + c0 + tx, 10);
        t[ty4 * 4 + i][tx] = bf2f(IN[f]) + bf2f(IN[ipsz + f]);
    }
    __syncthreads();
    #pragma unroll
    for (int i = 0; i < 4; ++i) {
        int orow = c0 + ty4 * 4 + i;
        long f = swz((long)orow * 1024 + r0 + tx, 10);
        float v = t[tx][ty4 * 4 + i];
        unsigned short h0 = f2bf(v);
        OUT[f] = h0;
        OUT[opsz + f] = f2bf(v - bf2f(h0));
    }
}

// ---- Gcat planes from stacked [V1^T; V2^T] planes ----
__global__ void gtspp_k(const unsigned short* __restrict__ PV, long vpsz,
                        unsigned short* __restrict__ PG, long gpsz, float h)
{
    __shared__ float t[32][33];
    const int tx = threadIdx.x & 31, ty4 = threadIdx.x >> 5;
    const int k0 = blockIdx.x * 32, n0 = blockIdx.y * 32, z = blockIdx.z;
    #pragma unroll
    for (int i = 0; i < 4; ++i) {
        int k = k0 + ty4 * 4 + i, n = n0 + tx;
        long f2 = swz((long)(512 + k) * 1024 + n, 10);
        float v2 = bf2f(PV[f2]) + bf2f(PV[vpsz + f2]);
        float v;
        if (z == 0) {
            long f1 = swz((long)k * 1024 + n, 10);
            v = h * (bf2f(PV[f1]) + bf2f(PV[vpsz + f1]) - v2);
        } else v = h * v2;
        t[ty4 * 4 + i][tx] = v;
    }
    __syncthreads();
    #pragma unroll
    for (int i = 0; i < 4; ++i) {
        int n = n0 + ty4 * 4 + i, kk = z * 512 + k0 + tx;
        long f = swz((long)n * 1024 + kk, 10);
        float v = t[tx][ty4 * 4 + i];
        unsigned short h0 = f2bf(v);
        PG[f] = h0;
        PG[gpsz + f] = f2bf(v - bf2f(h0));
    }
}

// ---- Yout[8r] = reconstruct(P row r) ----
__global__ void cprows_pl(float* __restrict__ Y, const unsigned short* __restrict__ P,
                          long psz)
{
    int r = blockIdx.y;
    int c = blockIdx.x * 256 + threadIdx.x;
    long f = swz((long)r * 1024 + c, 10);
    Y[(long)r * 8192 + c] = bf2f(P[f]) + bf2f(P[psz + f]);
}

// dst[db + r*ds + c] = src[sb + r*ss + c]
__global__ void copy_rows_k(float* __restrict__ dst, long db, long ds,
                            const float* __restrict__ src, long sb, long ss, int ncols)
{
    int r = blockIdx.y;
    int c = blockIdx.x * 256 + threadIdx.x;
    if (c < ncols) dst[db + (long)r * ds + c] = src[sb + (long)r * ss + c];
}

// dst[db + r*ds + c] += src[r*ncols + c]
__global__ void add_rows_k(float* __restrict__ dst, long db, long ds,
                           const float* __restrict__ src, int ncols)
{
    int r = blockIdx.y;
    int c = blockIdx.x * 256 + threadIdx.x;
    if (c < ncols) dst[db + (long)r * ds + c] += src[(long)r * ncols + c];
}

__global__ void scale_add_id_k(float* __restrict__ dst, const float* __restrict__ src,
                               float s, int n)
{
    int r = blockIdx.y;
    int c = blockIdx.x * 256 + threadIdx.x;
    if (c < n) dst[(long)r * n + c] = s * src[(long)r * n + c] + ((r == c) ? 1.f : 0.f);
}

__global__ void scale_copy_k(float* __restrict__ dst, const float* __restrict__ src,
                             float s, long cnt)
{
    long i = (long)blockIdx.x * 256 + threadIdx.x;
    if (i < cnt) dst[i] = s * src[i];
}

__global__ void g1g2_k(float* __restrict__ g1, float* __restrict__ g2,
                       const float* __restrict__ v1, const float* __restrict__ v2,
                       float h, long cnt)
{
    long i = (long)blockIdx.x * 256 + threadIdx.x;
    if (i < cnt) {
        float a = v1[i], b = v2[i];
        g1[i] = h * (a - b);
        g2[i] = h * b;
    }
}

// ---------------------------------------------------------------------------
// FALLBACK (round-3, 3-limb, 30 MB ws) — only if ws_size < 46 MB.
// ---------------------------------------------------------------------------
template <int BM, int BN, bool TRANSB>
__global__ __launch_bounds__(256) void gemm_mfma(
    const float* __restrict__ A, long ab, long lda,
    const float* __restrict__ B,
    const float* __restrict__ Cin, long cb, long ldc, float beta,
    float* __restrict__ Out, long ob, long ldo,
    int M, int Nn, int K, float alpha, int add_id)
{
    constexpr int LDT = 40;
    __shared__ unsigned short At[3][BM][LDT];
    __shared__ unsigned short Bt[3][BN][LDT];
    const int tid = threadIdx.x;
    const int lane = tid & 63;
    const int wid = tid >> 6;
    const int row0 = blockIdx.x * BM;
    const int col0 = blockIdx.y * BN;
    constexpr int MR = BM / 32;
    constexpr int NR = BN / 32;
    const int wrow = (wid >> 1) * (BM / 2);
    const int wcol = (wid & 1) * (BN / 2);
    const int l16 = lane & 15;
    const int koff = lane >> 4;
    f32x4 acc[MR][NR] = {};

    for (int k0 = 0; k0 < K; k0 += 32) {
        #pragma unroll
        for (int i = 0; i < BM / 32; ++i) {
            int r = i * 32 + (tid >> 3);
            int kl = (tid & 7) * 4;
            int gr = row0 + r;
            float4 v = make_float4(0.f, 0.f, 0.f, 0.f);
            if (gr < M) v = *(const float4*)&A[ab + (long)gr * lda + (k0 + kl)];
            unsigned short h0[4], h1[4], h2[4];
            split3(v.x, h0[0], h1[0], h2[0]);
            split3(v.y, h0[1], h1[1], h2[1]);
            split3(v.z, h0[2], h1[2], h2[2]);
            split3(v.w, h0[3], h1[3], h2[3]);
            *(ushort4*)&At[0][r][kl] = make_ushort4(h0[0], h0[1], h0[2], h0[3]);
            *(ushort4*)&At[1][r][kl] = make_ushort4(h1[0], h1[1], h1[2], h1[3]);
            *(ushort4*)&At[2][r][kl] = make_ushort4(h2[0], h2[1], h2[2], h2[3]);
        }
        if (TRANSB) {
            #pragma unroll
            for (int i = 0; i < BN / 32; ++i) {
                int r = i * 32 + (tid >> 3);
                int kl = (tid & 7) * 4;
                float4 v = *(const float4*)&B[(long)(col0 + r) * K + (k0 + kl)];
                unsigned short h0[4], h1[4], h2[4];
                split3(v.x, h0[0], h1[0], h2[0]);
                split3(v.y, h0[1], h1[1], h2[1]);
                split3(v.z, h0[2], h1[2], h2[2]);
                split3(v.w, h0[3], h1[3], h2[3]);
                *(ushort4*)&Bt[0][r][kl] = make_ushort4(h0[0], h0[1], h0[2], h0[3]);
                *(ushort4*)&Bt[1][r][kl] = make_ushort4(h1[0], h1[1], h1[2], h1[3]);
                *(ushort4*)&Bt[2][r][kl] = make_ushort4(h2[0], h2[1], h2[2], h2[3]);
            }
        } else {
            constexpr int TPK = BN / 4;
            #pragma unroll
            for (int i = 0; i < BN / 32; ++i) {
                int kl = i * (256 / TPK) + tid / TPK;
                int nl = (tid % TPK) * 4;
                float4 v = *(const float4*)&B[(long)(k0 + kl) * Nn + (col0 + nl)];
                unsigned short s0, s1, s2;
                split3(v.x, s0, s1, s2);
                Bt[0][nl + 0][kl] = s0; Bt[1][nl + 0][kl] = s1; Bt[2][nl + 0][kl] = s2;
                split3(v.y, s0, s1, s2);
                Bt[0][nl + 1][kl] = s0; Bt[1][nl + 1][kl] = s1; Bt[2][nl + 1][kl] = s2;
                split3(v.z, s0, s1, s2);
                Bt[0][nl + 2][kl] = s0; Bt[1][nl + 2][kl] = s1; Bt[2][nl + 2][kl] = s2;
                split3(v.w, s0, s1, s2);
                Bt[0][nl + 3][kl] = s0; Bt[1][nl + 3][kl] = s1; Bt[2][nl + 3][kl] = s2;
            }
        }
        __syncthreads();
        bf16x8 bf[NR][3];
        #pragma unroll
        for (int nr = 0; nr < NR; ++nr) {
            int brow = wcol + nr * 16 + l16;
            #pragma unroll
            for (int s = 0; s < 3; ++s)
                bf[nr][s] = *(const bf16x8*)&Bt[s][brow][koff * 8];
        }
        #pragma unroll
        for (int mr = 0; mr < MR; ++mr) {
            int arow = wrow + mr * 16 + l16;
            bf16x8 a0 = *(const bf16x8*)&At[0][arow][koff * 8];
            bf16x8 a1 = *(const bf16x8*)&At[1][arow][koff * 8];
            bf16x8 a2 = *(const bf16x8*)&At[2][arow][koff * 8];
            #pragma unroll
            for (int nr = 0; nr < NR; ++nr) {
                f32x4 c = acc[mr][nr];
                c = __builtin_amdgcn_mfma_f32_16x16x32_bf16(a0, bf[nr][0], c, 0, 0, 0);
                c = __builtin_amdgcn_mfma_f32_16x16x32_bf16(a0, bf[nr][1], c, 0, 0, 0);
                c = __builtin_amdgcn_mfma_f32_16x16x32_bf16(a1, bf[nr][0], c, 0, 0, 0);
                c = __builtin_amdgcn_mfma_f32_16x16x32_bf16(a0, bf[nr][2], c, 0, 0, 0);
                c = __builtin_amdgcn_mfma_f32_16x16x32_bf16(a1, bf[nr][1], c, 0, 0, 0);
                c = __builtin_amdgcn_mfma_f32_16x16x32_bf16(a2, bf[nr][0], c, 0, 0, 0);
                acc[mr][nr] = c;
            }
        }
        __syncthreads();
    }
    #pragma unroll
    for (int mr = 0; mr < MR; ++mr) {
        #pragma unroll
        for (int r = 0; r < 4; ++r) {
            int gr = row0 + wrow + mr * 16 + koff * 4 + r;
            if (gr >= M) continue;
            #pragma unroll
            for (int nr = 0; nr < NR; ++nr) {
                int gc = col0 + wcol + nr * 16 + l16;
                float v = alpha * acc[mr][nr][r];
                if (Cin) v += beta * Cin[cb + (long)gr * ldc + gc];
                if (add_id && gr == gc) v += 1.f;
                Out[ob + (long)gr * ldo + gc] = v;
            }
        }
    }
}

static void fallback_launch(void* const* d_in, void* d_out, void* d_ws,
                            hipStream_t stream)
{
    const float* y0 = (const float*)d_in[1];
    const float* u  = (const float*)d_in[2];
    const float* Am = (const float*)d_in[3];
    const float* Bm = (const float*)d_in[4];
    float* Yout = (float*)d_out;
    float* w = (float*)d_ws;
    const float h = 0.01f;
    const int N = GN;

    float* Eyy = w;
    float* T1  = Eyy + (long)N * N;
    float* T2  = T1  + (long)N * N;
    float* V1  = T2  + (long)N * N;
    float* Vt  = V1  + (long)N * GM;
    float* V2  = Vt  + (long)N * GM;
    float* G1  = V2  + (long)N * GM;
    float* G2  = G1  + (long)N * GM;
    float* Z   = G2  + (long)N * GM;
    float* Zt  = Z   + (long)CCH * N;
    dim3 blk(256);

    auto gemm = [&](bool transb, const float* A, long ab, long lda,
                    const float* B, const float* Cin, long cb, long ldc, float beta,
                    float* Out, long ob, long ldo,
                    int M, int Nn, int K, float alpha, int add_id) {
        if (M > 1536 && (Nn % 128) == 0) {
            dim3 grid((M + 127) / 128, Nn / 128);
            if (transb)
                gemm_mfma<128, 128, true><<<grid, blk, 0, stream>>>(A, ab, lda, B, Cin, cb, ldc, beta, Out, ob, ldo, M, Nn, K, alpha, add_id);
            else
                gemm_mfma<128, 128, false><<<grid, blk, 0, stream>>>(A, ab, lda, B, Cin, cb, ldc, beta, Out, ob, ldo, M, Nn, K, alpha, add_id);
        } else {
            dim3 grid((M + 63) / 64, Nn / 64);
            if (transb)
                gemm_mfma<64, 64, true><<<grid, blk, 0, stream>>>(A, ab, lda, B, Cin, cb, ldc, beta, Out, ob, ldo, M, Nn, K, alpha, add_id);
            else
                gemm_mfma<64, 64, false><<<grid, blk, 0, stream>>>(A, ab, lda, B, Cin, cb, ldc, beta, Out, ob, ldo, M, Nn, K, alpha, add_id);
        }
    };

    scale_add_id_k<<<dim3(4, N), blk, 0, stream>>>(T1, Am, h / 5.f, N);
    {
        float* pc = T1; float* pn = T2;
        for (int k = 4; k >= 1; --k) {
            float* out = (k == 1) ? Eyy : pn;
            gemm(false, Am, 0, N, pc, nullptr, 0, 0, 0.f, out, 0, N, N, N, N, h / (float)k, 1);
            pn = pc; pc = out;
        }
    }
    const long NM = (long)N * GM;
    scale_copy_k<<<dim3((unsigned)((NM + 255) / 256)), blk, 0, stream>>>(V1, Bm, 1.f / 120.f, NM);
    {
        const float f1[4] = {1.f / 24.f, 1.f / 6.f, 0.5f, 1.f};
        float* pc = V1; float* pn = Vt;
        for (int j = 3; j >= 0; --j) {
            gemm(false, Am, 0, N, pc, Bm, 0, GM, f1[3 - j], pn, 0, GM, N, GM, N, h, 0);
            float* t = pc; pc = pn; pn = t;
        }
    }
    scale_copy_k<<<dim3((unsigned)((NM + 255) / 256)), blk, 0, stream>>>(V2, Bm, 1.f / 720.f, NM);
    {
        const float f2[4] = {1.f / 120.f, 1.f / 24.f, 1.f / 6.f, 0.5f};
        float* pc = V2; float* pn = Vt;
        for (int j = 3; j >= 0; --j) {
            gemm(false, Am, 0, N, pc, Bm, 0, GM, f2[3 - j], pn, 0, GM, N, GM, N, h, 0);
            float* t = pc; pc = pn; pn = t;
        }
    }
    g1g2_k<<<dim3((unsigned)((NM + 255) / 256)), blk, 0, stream>>>(G1, G2, V1, V2, h, NM);
    gemm(true, u, 0, GM, G1, nullptr, 0, 0, 0.f, Yout, (long)N, N, GT - 1, N, GM, 1.f, 0);
    gemm(true, u, GM, GM, G2, Yout, (long)N, N, 1.f, Yout, (long)N, N, GT - 1, N, GM, 1.f, 0);
    copy_rows_k<<<dim3(4, 1), blk, 0, stream>>>(Yout, 0, 0, y0, 0, 0, N);
    for (int s = 2; s <= SCH; ++s) {
        int Mr = (GT - 1 - s) / SCH + 1;
        gemm(true, Yout, (long)(s - 1) * N, (long)SCH * N, Eyy,
             Yout, (long)s * N, (long)SCH * N, 1.f,
             Yout, (long)s * N, (long)SCH * N, Mr, N, N, 1.f, 0);
    }
    copy_rows_k<<<dim3(4, 1), blk, 0, stream>>>(Z, 0, 0, y0, 0, 0, N);
    copy_rows_k<<<dim3(4, CCH - 1), blk, 0, stream>>>(Z, (long)N, (long)N,
                                                      Yout, (long)SCH * N, (long)SCH * N, N);
    gemm(false, Eyy, 0, N, Eyy, nullptr, 0, 0, 0.f, T1, 0, N, N, N, N, 1.f, 0);
    gemm(false, T1, 0, N, T1, nullptr, 0, 0, 0.f, T2, 0, N, N, N, N, 1.f, 0);
    gemm(false, T2, 0, N, T2, nullptr, 0, 0, 0.f, T1, 0, N, N, N, N, 1.f, 0);
    {
        float* Mc = T1; float* Mo = T2;
        float* Zc = Z;  float* Zn = Zt;
        for (int p = 0; p < 10; ++p) {
            int o = 1 << p;
            gemm(true, Zc, 0, N, Mc, Zc, (long)o * N, N, 1.f,
                 Zn, (long)o * N, N, CCH - o, N, N, 1.f, 0);
            copy_rows_k<<<dim3(4, o), blk, 0, stream>>>(Zn, 0, N, Zc, 0, N, N);
            if (p < 9) {
                gemm(false, Mc, 0, N, Mc, nullptr, 0, 0, 0.f, Mo, 0, N, N, N, N, 1.f, 0);
                float* t = Mc; Mc = Mo; Mo = t;
            }
            float* t = Zc; Zc = Zn; Zn = t;
        }
        copy_rows_k<<<dim3(4, CCH), blk, 0, stream>>>(Yout, 0, (long)SCH * N, Zc, 0, N, N);
        float* Q = Zc; float* Qt = Zn;
        for (int s = 1; s <= SCH - 1; ++s) {
            gemm(true, Q, 0, N, Eyy, nullptr, 0, 0, 0.f, Qt, 0, N, CCH, N, N, 1.f, 0);
            int Mr = (GT - 1 - s) / SCH + 1;
            add_rows_k<<<dim3(4, Mr), blk, 0, stream>>>(Yout, (long)s * N, (long)SCH * N, Qt, N);
            float* t = Q; Q = Qt; Qt = t;
        }
    }
}

// ---------------------------------------------------------------------------
extern "C" void kernel_launch(void* const* d_in, const int* in_sizes, int n_in,
                              void* d_out, int out_size, void* d_ws, size_t ws_size,
                              hipStream_t stream)
{
    (void)in_sizes; (void)n_in; (void)out_size;
    const size_t NEED = 46ull * 1024 * 1024;
    if (ws_size < NEED) { fallback_launch(d_in, d_out, d_ws, stream); return; }

    const float* y0 = (const float*)d_in[1];
    const float* u  = (const float*)d_in[2];
    const float* Am = (const float*)d_in[3];
    const float* Bm = (const float*)d_in[4];
    float* Yout = (float*)d_out;
    char* w = (char*)d_ws;
    const float h = 0.01f;
    const size_t MB = 1024 * 1024;
    const long P1M = 1 << 20;                  // 1024x1024 plane limb stride
    const long P2M = 1 << 21;                  // 2048x1024 plane limb stride
    const long PUS = 1 << 22;                  // 8192x512  (PU)
    const long PBS = 1 << 19;                  // 512x1024  (PBT)
    const int  BIG = 1 << 30;

    // ws layout (46 MB, time-phased):
    unsigned short* PU   = (unsigned short*)(w);            // [0,16) c-staging only
    unsigned short* PZW1 = (unsigned short*)(w);            // [0,8)  after PU dead
    unsigned short* PZW2 = (unsigned short*)(w + 8 * MB);   // [8,16)
    unsigned short* CH1  = (unsigned short*)(w + 16 * MB);  // [16,24) chain ping
    unsigned short* CH2  = (unsigned short*)(w + 24 * MB);  // [24,32) chain pong
    unsigned short* PY1  = (unsigned short*)(w + 24 * MB);  // reuse CH2 low
    unsigned short* PY2  = (unsigned short*)(w + 28 * MB);  // reuse CH2 high
    unsigned short* PE   = (unsigned short*)(w + 32 * MB);  // planes(E)
    unsigned short* PG   = (unsigned short*)(w + 36 * MB);  // planes(Gcat)
    unsigned short* PA   = (unsigned short*)(w + 40 * MB);  // planes(A) -> later PW
    unsigned short* PW   = PA;
    unsigned short* PBT  = (unsigned short*)(w + 44 * MB);  // planes(B^T), 2MB

    dim3 blk(256);

    // ---- 1. planes(Am) ----
    split_pl_k<<<dim3(4096), blk, 0, stream>>>(Am, PA, P1M, 10, 1.f, (long)1 << 20);

    // ---- 2. seeds for fused expm+phi chain (stacked 2048 rows in CH1) ----
    trsp_k<<<dim3(32, 32), blk, 0, stream>>>(Am, 1024, h / 5.f, 1, CH1, P2M, 0);
    trsp_k<<<dim3(16, 32), blk, 0, stream>>>(Bm, 512, 1.f / 120.f, 0, CH1, P2M, 1024);
    trsp_k<<<dim3(16, 32), blk, 0, stream>>>(Bm, 512, 1.f / 720.f, 0, CH1, P2M, 1536);
    trsp_k<<<dim3(16, 32), blk, 0, stream>>>(Bm, 512, 1.f, 0, PBT, PBS, 0);

    // ---- 3. fused chain x4: rows 0-1023 expm Horner, rows 1024-2047 phi chains.
    // P := al[j]*(P@A^T) + I ; V1 := h*(V1@A^T) + f1[j]*B^T ; V2 likewise f2.
    {
        const float alE[4] = {h / 4.f, h / 3.f, h / 2.f, h};
        const float f1[4] = {1.f / 24.f, 1.f / 6.f, 0.5f, 1.f};
        const float f2[4] = {1.f / 120.f, 1.f / 24.f, 1.f / 6.f, 0.5f};
        unsigned short* cc = CH1; unsigned short* cn = CH2;
        for (int j = 0; j < 4; ++j) {
            gemm_pp<64, 2><<<dim3(32, 16), blk, 0, stream>>>(
                cc, P2M, 1024, 10, PA, P1M,
                nullptr, 0, 0, PBT, PBS, 511,
                1024, 1536, f1[j], f2[j],
                nullptr, 0, 0, cn, P2M, 0, 1,
                BIG, 0, 2048, alE[j], h, 1024, 1);
            unsigned short* t = cc; cc = cn; cn = t;
        }  // 4 swaps -> final in CH1 (rows 0-1023 = E^T, 1024+ = [V1^T;V2^T])
    }
    tspp_k<<<dim3(32, 32), blk, 0, stream>>>(CH1, P2M, 0, PE, P1M);
    gtspp_k<<<dim3(16, 32, 2), blk, 0, stream>>>(CH1 + (1 << 20), P2M, PG, P1M, h);

    // ---- 4. planes(u) (concat trick: c-staging A row t spans u rows t,t+1) ----
    split_pl_k<<<dim3(16384), blk, 0, stream>>>(u, PU, PUS, 9, 1.f, PUS);

    // ---- 5. c-staging: Yout[t] = [u_{t-1}|u_t] @ Gcat^T (+ planes of rows 8i+1) ----
    gemm_pp<128, 1><<<dim3(64, 8), blk, 0, stream>>>(
        PU, PUS, 512, 9, PG, P1M,
        nullptr, 0, 0, nullptr, 0, -1,
        0, BIG, 0.f, 0.f,
        Yout, 1024, 1024, PY1, P1M, 1, 1,
        BIG, 0, GT - 1, 1.f, 1.f, BIG, 0);
    copy_rows_k<<<dim3(4, 1), blk, 0, stream>>>(Yout, 0, 0, y0, 0, 0, 1024);

    // ---- 6. phase 1: within-chunk scan, in place; planes chained ----
    {
        unsigned short* pc = PY1; unsigned short* pn = PY2;
        for (int s = 2; s <= 7; ++s) {
            gemm_pp<64, 2><<<dim3(16, 16), blk, 0, stream>>>(
                pc, P1M, 1024, 10, PE, P1M,
                Yout, (long)s * 1024, 8192, nullptr, 0, -1,
                0, BIG, 1.f, 0.f,
                Yout, (long)s * 1024, 8192, pn, P1M, 0, 1,
                BIG, 0, 1024, 1.f, 1.f, BIG, 0);
            unsigned short* t = pc; pc = pn; pn = t;
        }
        // s=8 -> boundary rows 8(i+1), plane row i+1 via zoff=1
        gemm_pp<64, 2><<<dim3(16, 16), blk, 0, stream>>>(
            pc, P1M, 1024, 10, PE, P1M,
            Yout, 0, 8192, nullptr, 0, -1,
            0, BIG, 1.f, 0.f,
            Yout, 0, 8192, PZW1, P2M, 0, 1,
            BIG, 1, 1023, 1.f, 1.f, BIG, 0);
    }
    // z_0 = y0 -> PZW1 plane row 0
    split_pl_k<<<dim3(4), blk, 0, stream>>>(y0, PZW1, P2M, 10, 1.f, 1024);

    // ---- 7. pre-squarings E->E^2->E^4->E^8 (B = planes(W)) ----
    gemm_pp<64, 2><<<dim3(16, 16), blk, 0, stream>>>(      // E^2,T
        CH1, P2M, 1024, 10, PE, P1M,
        nullptr, 0, 0, nullptr, 0, -1, 0, BIG, 0.f, 0.f,
        nullptr, 0, 0, PY1, P1M, 0, 1,
        BIG, 0, 1024, 1.f, 1.f, BIG, 0);
    tspp_k<<<dim3(32, 32), blk, 0, stream>>>(PY1, P1M, 0, PW, P1M);
    gemm_pp<64, 2><<<dim3(16, 16), blk, 0, stream>>>(      // E^4,T
        PY1, P1M, 1024, 10, PW, P1M,
        nullptr, 0, 0, nullptr, 0, -1, 0, BIG, 0.f, 0.f,
        nullptr, 0, 0, PY2, P1M, 0, 1,
        BIG, 0, 1024, 1.f, 1.f, BIG, 0);
    tspp_k<<<dim3(32, 32), blk, 0, stream>>>(PY2, P1M, 0, PW, P1M);
    gemm_pp<64, 2><<<dim3(16, 16), blk, 0, stream>>>(      // E^8,T -> PZW1 rows 1024+
        PY2, P1M, 1024, 10, PW, P1M,
        nullptr, 0, 0, nullptr, 0, -1, 0, BIG, 0.f, 0.f,
        nullptr, 0, 0, PZW1, P2M, 0, 1,
        BIG, 1024, 1024, 1.f, 1.f, BIG, 0);
    tspp_k<<<dim3(32, 32), blk, 0, stream>>>(PZW1, P2M, 1024, PW, P1M);

    // ---- 8. fused doubling: [Zn; Wnext^T] = [Zc[i-o]@W^T + Zc[i]; W^T@W^T] ----
    {
        unsigned short* PZc = PZW1; unsigned short* PZn = PZW2;
        for (int p = 0; p < 10; ++p) {
            int o = 1 << p;
            int Mr = (p == 9) ? 1024 : 2048;
            gemm_pp<64, 2><<<dim3(Mr / 64, 16), blk, 0, stream>>>(
                PZc, P2M, 1024, 10, PW, P1M,
                nullptr, 0, 0, PZc, P2M, -1,
                0, 1024, 1.f, 0.f,
                nullptr, 0, 0, PZn, P2M, 0, 1,
                1024, o, Mr, 1.f, 1.f, BIG, 0);
            // unchanged prefix rows [0,o): copy both plane limbs
            copy_rows_k<<<dim3(2, o), blk, 0, stream>>>(
                (float*)PZn, 0, 512, (float*)PZc, 0, 512, 512);
            copy_rows_k<<<dim3(2, o), blk, 0, stream>>>(
                (float*)PZn + (1 << 20), 0, 512, (float*)PZc + (1 << 20), 0, 512, 512);
            if (p < 9)
                tspp_k<<<dim3(32, 32), blk, 0, stream>>>(PZn, P2M, 1024, PW, P1M);
            unsigned short* t = PZc; PZc = PZn; PZn = t;
        }  // 10 swaps -> final Z planes back in PZW1
    }

    // ---- 9. phase 3: boundary rows exact, then y_{8i+s} += E^s z_i, s=1..7 ----
    cprows_pl<<<dim3(4, 1024), blk, 0, stream>>>(Yout, PZW1, P2M);
    copy_rows_k<<<dim3(4, 1), blk, 0, stream>>>(Yout, 0, 0, y0, 0, 0, 1024);
    {
        const unsigned short* pc = PZW1; long apsz = P2M;
        unsigned short* pn = PY1;
        for (int s = 1; s <= 7; ++s) {
            gemm_pp<64, 2><<<dim3(16, 16), blk, 0, stream>>>(
                pc, apsz, 1024, 10, PE, P1M,
                Yout, (long)s * 1024, 8192, nullptr, 0, -1,
                0, BIG, 1.f, 0.f,
                Yout, (long)s * 1024, 8192,
                (s < 7) ? pn : nullptr, P1M, 0, 2,
                BIG, 0, 1024, 1.f, 1.f, BIG, 0);
            pc = pn; apsz = P1M;
            pn = (pn == PY1) ? PY2 : PY1;
        }
    }
}

// Round 8
// 871.206 us; speedup vs baseline: 1.7688x; 1.0174x over previous
//
#include <hip/hip_runtime.h>

// Problem constants (fixed in the reference file)
#define GT 8192      // time steps
#define GN 1024      // state dim
#define GM 512       // input dim
#define CCH 1024     // scan chunks
#define SCH 8        // steps per chunk

typedef __attribute__((ext_vector_type(8))) short bf16x8;
typedef __attribute__((ext_vector_type(4))) float f32x4;

__device__ __forceinline__ unsigned short f2bf(float x) {   // RNE fp32->bf16
    unsigned int u = __float_as_uint(x);
    u += 0x7FFF + ((u >> 16) & 1);
    return (unsigned short)(u >> 16);
}
__device__ __forceinline__ float bf2f(unsigned short b) {
    return __uint_as_float(((unsigned int)b) << 16);
}
__device__ __forceinline__ void split2(float x, unsigned short& h0, unsigned short& h1) {
    h0 = f2bf(x);
    h1 = f2bf(x - bf2f(h0));
}
__device__ __forceinline__ void split3(float x, unsigned short& s0,
                                       unsigned short& s1, unsigned short& s2) {
    s0 = f2bf(x); float r = x - bf2f(s0);
    s1 = f2bf(r); r -= bf2f(s1);
    s2 = f2bf(r);
}
// storage swizzle: XOR element bits 3-4 with (row>>1)&3 (row = e>>sh).
// Involution; LDS reads land 2-way-max bank aliased (free).
__device__ __forceinline__ long swz(long e, int sh) {
    return e ^ (((e >> (sh + 1)) & 3) << 3);
}
// async 16B global->LDS (dest wave-uniform base; HW scatters lane*16; src per-lane)
__device__ __forceinline__ void gl16(const unsigned short* g, unsigned short* l) {
    __builtin_amdgcn_global_load_lds(
        (const __attribute__((address_space(1))) unsigned int*)g,
        (__attribute__((address_space(3))) unsigned int*)l, 16, 0, 0);
}

// ---------------------------------------------------------------------------
// Plane x plane GEMM; 512 threads = 8 waves; waves 0-3 / 4-7 K-split the 64-k
// step (kk=0/1); f32 LDS reduce at the end. Double-buffered staging.
// Out = aa * A2limb @ B2limb^T (+ bb * Cin) (+I),  K = 1024, N = 1024.
// A planes: element (r,k) at swz(r*alda + k, aldsh); limb1 at +apsz.
// B planes: [1024][1024], sh=10, limb1 at +bpsz.
// 3 limb products (a0b0, a0b1, a1b0) -> ~fp32 precision.
// Row mapping (segment 1): trow = (gr < segN) ? gr + zoff : gr; skip if crossing.
// aa = trow<asplit ? alpha : alphaB;
// bb = trow<bzero ? 0 : (trow<bsplit ? beta : betaB); Cin row = trow & cmask.
// Pout: plane emission (pmode 1: final v, 2: pure aa*acc); pstep8: only rows
// with trow%8==0 at plane row trow>>3.
// DUAL-GEMM: blocks with row0 >= seg2 instead compute a pure product
// Ap2 @ Bp2^T (A row = gr - seg2, standard 1024-lda planes, limb1 at +apsz2)
// and emit planes to Pout2 at row (gr - seg2 + p2off), limb stride ppsz2.
// ---------------------------------------------------------------------------
template <int BM>
__global__ __launch_bounds__(512) void gemm_pp(
    const unsigned short* __restrict__ Ap, long apsz, int alda, int aldsh,
    const unsigned short* __restrict__ Bp, long bpsz,
    const float* __restrict__ Cf, long cfb, long cfld,
    const unsigned short* __restrict__ Cp, long cpsz, int cmask,
    int bzero, int bsplit, float beta, float betaB,
    float* __restrict__ Of, long ofb, long ofld,
    unsigned short* __restrict__ Pout, long ppsz, int pstep8, int pmode,
    int segN, int zoff,
    int M, float alpha, float alphaB, int asplit, int add_id,
    const unsigned short* __restrict__ Ap2, long apsz2,
    const unsigned short* __restrict__ Bp2,
    unsigned short* __restrict__ Pout2, long ppsz2, int p2off, int seg2)
{
    constexpr int MT = BM / 32;            // 16-tiles per wave dim
    __shared__ __align__(16) unsigned short At[2][2][2][BM][32]; // [buf][kk][limb][row][k]
    __shared__ __align__(16) unsigned short Bt[2][2][2][BM][32];

    const int tid = threadIdx.x;
    const int lane = tid & 63;
    const int w = tid >> 6;                // 8 waves
    const int ksub = w >> 2;               // K-split group
    const int quad = w & 3;                // 2x2 output quads
    const int wr = (quad >> 1) * (BM / 2);
    const int wc = (quad & 1) * (BM / 2);
    const int l16 = lane & 15, koff = lane >> 4;
    const int row0 = blockIdx.x * BM;
    const int col0 = blockIdx.y * BM;
    const int lr4 = lane >> 2;             // row within 16-row chunk
    const int lg = lane & 3;               // physical 16B granule
    const bool s2 = (row0 >= seg2);

    f32x4 acc[MT][MT] = {};

    auto stage = [&](int bsel, int k0) {
        #pragma unroll
        for (int ci = 0; ci < BM / 16; ++ci) {
            const int c = w * (BM / 16) + ci;
            const int op = c / (BM / 4);
            const int rem = c % (BM / 4);
            const int limb = rem / (BM / 8);
            const int rem2 = rem % (BM / 8);
            const int kk = rem2 / (BM / 16);
            const int rb = (rem2 % (BM / 16)) * 16;
            const int lr = rb + lr4;
            const int q = lg ^ ((lr >> 1) & 3);      // logical granule wanted
            long e; int sh; const unsigned short* base;
            if (op == 0) {
                if (!s2) {
                    e = (long)(row0 + lr) * alda + k0 + kk * 32 + (q << 3); sh = aldsh;
                    base = Ap + (limb ? apsz : 0);
                } else {
                    e = (long)(row0 - seg2 + lr) * 1024 + k0 + kk * 32 + (q << 3); sh = 10;
                    base = Ap2 + (limb ? apsz2 : 0);
                }
            } else {
                e = (long)(col0 + lr) * 1024 + k0 + kk * 32 + (q << 3); sh = 10;
                base = (s2 ? Bp2 : Bp) + (limb ? bpsz : 0);
            }
            long f = swz(e, sh);
            unsigned short* l = (op == 0 ? &At[bsel][kk][limb][rb][0]
                                         : &Bt[bsel][kk][limb][rb][0]);
            gl16(base + f, l);
        }
    };

    stage(0, 0);
    __syncthreads();
    int cur = 0;
    for (int k0 = 0; k0 < 1024; k0 += 64) {
        if (k0 + 64 < 1024) stage(cur ^ 1, k0 + 64);   // next tile flies under MFMA

        bf16x8 a0[MT], a1[MT], b0[MT], b1[MT];
        #pragma unroll
        for (int mi = 0; mi < MT; ++mi) {
            int lr = wr + mi * 16 + l16;
            int off = (koff ^ ((lr >> 1) & 3)) << 3;
            a0[mi] = *(const bf16x8*)&At[cur][ksub][0][lr][off];
            a1[mi] = *(const bf16x8*)&At[cur][ksub][1][lr][off];
        }
        #pragma unroll
        for (int ni = 0; ni < MT; ++ni) {
            int lr = wc + ni * 16 + l16;
            int off = (koff ^ ((lr >> 1) & 3)) << 3;
            b0[ni] = *(const bf16x8*)&Bt[cur][ksub][0][lr][off];
            b1[ni] = *(const bf16x8*)&Bt[cur][ksub][1][lr][off];
        }
        #pragma unroll
        for (int mi = 0; mi < MT; ++mi)
            #pragma unroll
            for (int ni = 0; ni < MT; ++ni) {
                f32x4 cc = acc[mi][ni];
                cc = __builtin_amdgcn_mfma_f32_16x16x32_bf16(a0[mi], b0[ni], cc, 0, 0, 0);
                cc = __builtin_amdgcn_mfma_f32_16x16x32_bf16(a0[mi], b1[ni], cc, 0, 0, 0);
                cc = __builtin_amdgcn_mfma_f32_16x16x32_bf16(a1[mi], b0[ni], cc, 0, 0, 0);
                acc[mi][ni] = cc;
            }
        __syncthreads();   // drains this iter's stage + syncs LDS reuse
        cur ^= 1;
    }

    // ---- cross-ksub reduce (alias At as f32 scratch; sized exactly) ----
    float* red = (float*)&At[0][0][0][0][0];
    if (ksub == 1) {
        #pragma unroll
        for (int mi = 0; mi < MT; ++mi)
            #pragma unroll
            for (int ni = 0; ni < MT; ++ni)
                *(f32x4*)&red[(((quad * MT + mi) * MT + ni) * 64 + lane) * 4] = acc[mi][ni];
    }
    __syncthreads();
    if (ksub != 0) return;
    #pragma unroll
    for (int mi = 0; mi < MT; ++mi)
        #pragma unroll
        for (int ni = 0; ni < MT; ++ni) {
            f32x4 o = *(const f32x4*)&red[(((quad * MT + mi) * MT + ni) * 64 + lane) * 4];
            acc[mi][ni][0] += o[0]; acc[mi][ni][1] += o[1];
            acc[mi][ni][2] += o[2]; acc[mi][ni][3] += o[3];
        }

    if (s2) {                              // pure product -> planes(Pout2)
        #pragma unroll
        for (int mi = 0; mi < MT; ++mi)
            #pragma unroll
            for (int r = 0; r < 4; ++r) {
                const int gr = row0 + wr + mi * 16 + koff * 4 + r;
                if (gr >= M) continue;
                const int prow = gr - seg2 + p2off;
                #pragma unroll
                for (int ni = 0; ni < MT; ++ni) {
                    const int gc = col0 + wc + ni * 16 + l16;
                    float pv = acc[mi][ni][r];
                    long f = swz((long)prow * 1024 + gc, 10);
                    unsigned short h0 = f2bf(pv);
                    Pout2[f] = h0;
                    Pout2[ppsz2 + f] = f2bf(pv - bf2f(h0));
                }
            }
        return;
    }

    #pragma unroll
    for (int mi = 0; mi < MT; ++mi) {
        #pragma unroll
        for (int r = 0; r < 4; ++r) {
            const int gr = row0 + wr + mi * 16 + koff * 4 + r;
            if (gr >= M) continue;
            const int trow = (gr < segN) ? gr + zoff : gr;
            if (gr < segN && trow >= segN) continue;
            const float aa = (trow < asplit) ? alpha : alphaB;
            const float bb = (trow < bzero) ? 0.f : ((trow < bsplit) ? beta : betaB);
            #pragma unroll
            for (int ni = 0; ni < MT; ++ni) {
                const int gc = col0 + wc + ni * 16 + l16;
                float vp = aa * acc[mi][ni][r];
                float v = vp;
                if (bb != 0.f) {
                    int crow = trow & cmask;
                    if (Cf) v += bb * Cf[cfb + (long)crow * cfld + gc];
                    else if (Cp) {
                        long f = swz((long)crow * 1024 + gc, 10);
                        v += bb * (bf2f(Cp[f]) + bf2f(Cp[cpsz + f]));
                    }
                }
                if (add_id && gr == gc) v += 1.f;
                if (Of) Of[ofb + (long)trow * ofld + gc] = v;
                if (Pout && (!pstep8 || (trow & 7) == 0)) {
                    int prow = pstep8 ? (trow >> 3) : trow;
                    long f = swz((long)prow * 1024 + gc, 10);
                    float pv = (pmode == 2) ? vp : v;
                    unsigned short h0 = f2bf(pv);
                    Pout[f] = h0;
                    Pout[ppsz + f] = f2bf(pv - bf2f(h0));
                }
            }
        }
    }
}

// ---- X (cnt fp32, rows of length 2^ldsh) -> swizzled 2-limb planes ----
__global__ void split_pl_k(const float* __restrict__ X, unsigned short* __restrict__ P,
                           long psz, int ldsh, float s, long cnt)
{
    long i = (long)blockIdx.x * 256 + threadIdx.x;
    if (i >= cnt) return;
    float v = s * X[i];
    long f = swz(i, ldsh);
    unsigned short h0 = f2bf(v);
    P[f] = h0;
    P[psz + f] = f2bf(v - bf2f(h0));
}

// ---- planes of s*in^T (+I): out rows (roff+)0..R-1, in is 1024 x R fp32 ----
__global__ void trsp_k(const float* __restrict__ in, int R, float s, int add_id,
                       unsigned short* __restrict__ P, long psz, int roff)
{
    __shared__ float t[32][33];
    const int tx = threadIdx.x & 31, ty4 = threadIdx.x >> 5;
    const int r0 = blockIdx.x * 32, c0 = blockIdx.y * 32;
    #pragma unroll
    for (int i = 0; i < 4; ++i)
        t[ty4 * 4 + i][tx] = in[(long)(c0 + ty4 * 4 + i) * R + r0 + tx];
    __syncthreads();
    #pragma unroll
    for (int i = 0; i < 4; ++i) {
        int r = r0 + ty4 * 4 + i, c = c0 + tx;
        float v = s * t[tx][ty4 * 4 + i];
        if (add_id && r == c) v += 1.f;
        long f = swz((long)(r + roff) * 1024 + c, 10);
        unsigned short h0 = f2bf(v);
        P[f] = h0;
        P[psz + f] = f2bf(v - bf2f(h0));
    }
}

// ---- planes(X) from planes(X^T): OUT[c][r] = IN[irow0+r][c] ----
__global__ void tspp_k(const unsigned short* __restrict__ IN, long ipsz, long irow0,
                       unsigned short* __restrict__ OUT, long opsz)
{
    __shared__ float t[32][33];
    const int tx = threadIdx.x & 31, ty4 = threadIdx.x >> 5;
    const int r0 = blockIdx.x * 32, c0 = blockIdx.y * 32;
    #pragma unroll
    for (int i = 0; i < 4; ++i) {
        long f = swz((irow0 + r0 + ty4 * 4 + i) * 1024 + c0 + tx, 10);
        t[ty4 * 4 + i][tx] = bf2f(IN[f]) + bf2f(IN[ipsz + f]);
    }
    __syncthreads();
    #pragma unroll
    for (int i = 0; i < 4; ++i) {
        int orow = c0 + ty4 * 4 + i;
        long f = swz((long)orow * 1024 + r0 + tx, 10);
        float v = t[tx][ty4 * 4 + i];
        unsigned short h0 = f2bf(v);
        OUT[f] = h0;
        OUT[opsz + f] = f2bf(v - bf2f(h0));
    }
}

// ---- Gcat planes from stacked [V1^T; V2^T] planes ----
__global__ void gtspp_k(const unsigned short* __restrict__ PV, long vpsz,
                        unsigned short* __restrict__ PG, long gpsz, float h)
{
    __shared__ float t[32][33];
    const int tx = threadIdx.x & 31, ty4 = threadIdx.x >> 5;
    const int k0 = blockIdx.x * 32, n0 = blockIdx.y * 32, z = blockIdx.z;
    #pragma unroll
    for (int i = 0; i < 4; ++i) {
        int k = k0 + ty4 * 4 + i, n = n0 + tx;
        long f2 = swz((long)(512 + k) * 1024 + n, 10);
        float v2 = bf2f(PV[f2]) + bf2f(PV[vpsz + f2]);
        float v;
        if (z == 0) {
            long f1 = swz((long)k * 1024 + n, 10);
            v = h * (bf2f(PV[f1]) + bf2f(PV[vpsz + f1]) - v2);
        } else v = h * v2;
        t[ty4 * 4 + i][tx] = v;
    }
    __syncthreads();
    #pragma unroll
    for (int i = 0; i < 4; ++i) {
        int n = n0 + ty4 * 4 + i, kk = z * 512 + k0 + tx;
        long f = swz((long)n * 1024 + kk, 10);
        float v = t[tx][ty4 * 4 + i];
        unsigned short h0 = f2bf(v);
        PG[f] = h0;
        PG[gpsz + f] = f2bf(v - bf2f(h0));
    }
}

// ---- Yout[8r] = reconstruct(P row r) ----
__global__ void cprows_pl(float* __restrict__ Y, const unsigned short* __restrict__ P,
                          long psz)
{
    int r = blockIdx.y;
    int c = blockIdx.x * 256 + threadIdx.x;
    long f = swz((long)r * 1024 + c, 10);
    Y[(long)r * 8192 + c] = bf2f(P[f]) + bf2f(P[psz + f]);
}

// dst[db + r*ds + c] = src[sb + r*ss + c]
__global__ void copy_rows_k(float* __restrict__ dst, long db, long ds,
                            const float* __restrict__ src, long sb, long ss, int ncols)
{
    int r = blockIdx.y;
    int c = blockIdx.x * 256 + threadIdx.x;
    if (c < ncols) dst[db + (long)r * ds + c] = src[sb + (long)r * ss + c];
}

// dst[db + r*ds + c] += src[r*ncols + c]
__global__ void add_rows_k(float* __restrict__ dst, long db, long ds,
                           const float* __restrict__ src, int ncols)
{
    int r = blockIdx.y;
    int c = blockIdx.x * 256 + threadIdx.x;
    if (c < ncols) dst[db + (long)r * ds + c] += src[(long)r * ncols + c];
}

__global__ void scale_add_id_k(float* __restrict__ dst, const float* __restrict__ src,
                               float s, int n)
{
    int r = blockIdx.y;
    int c = blockIdx.x * 256 + threadIdx.x;
    if (c < n) dst[(long)r * n + c] = s * src[(long)r * n + c] + ((r == c) ? 1.f : 0.f);
}

__global__ void scale_copy_k(float* __restrict__ dst, const float* __restrict__ src,
                             float s, long cnt)
{
    long i = (long)blockIdx.x * 256 + threadIdx.x;
    if (i < cnt) dst[i] = s * src[i];
}

__global__ void g1g2_k(float* __restrict__ g1, float* __restrict__ g2,
                       const float* __restrict__ v1, const float* __restrict__ v2,
                       float h, long cnt)
{
    long i = (long)blockIdx.x * 256 + threadIdx.x;
    if (i < cnt) {
        float a = v1[i], b = v2[i];
        g1[i] = h * (a - b);
        g2[i] = h * b;
    }
}

// ---------------------------------------------------------------------------
// FALLBACK (round-3, 3-limb, 30 MB ws) — only if ws_size < 46 MB.
// ---------------------------------------------------------------------------
template <int BM, int BN, bool TRANSB>
__global__ __launch_bounds__(256) void gemm_mfma(
    const float* __restrict__ A, long ab, long lda,
    const float* __restrict__ B,
    const float* __restrict__ Cin, long cb, long ldc, float beta,
    float* __restrict__ Out, long ob, long ldo,
    int M, int Nn, int K, float alpha, int add_id)
{
    constexpr int LDT = 40;
    __shared__ unsigned short At[3][BM][LDT];
    __shared__ unsigned short Bt[3][BN][LDT];
    const int tid = threadIdx.x;
    const int lane = tid & 63;
    const int wid = tid >> 6;
    const int row0 = blockIdx.x * BM;
    const int col0 = blockIdx.y * BN;
    constexpr int MR = BM / 32;
    constexpr int NR = BN / 32;
    const int wrow = (wid >> 1) * (BM / 2);
    const int wcol = (wid & 1) * (BN / 2);
    const int l16 = lane & 15;
    const int koff = lane >> 4;
    f32x4 acc[MR][NR] = {};

    for (int k0 = 0; k0 < K; k0 += 32) {
        #pragma unroll
        for (int i = 0; i < BM / 32; ++i) {
            int r = i * 32 + (tid >> 3);
            int kl = (tid & 7) * 4;
            int gr = row0 + r;
            float4 v = make_float4(0.f, 0.f, 0.f, 0.f);
            if (gr < M) v = *(const float4*)&A[ab + (long)gr * lda + (k0 + kl)];
            unsigned short h0[4], h1[4], h2[4];
            split3(v.x, h0[0], h1[0], h2[0]);
            split3(v.y, h0[1], h1[1], h2[1]);
            split3(v.z, h0[2], h1[2], h2[2]);
            split3(v.w, h0[3], h1[3], h2[3]);
            *(ushort4*)&At[0][r][kl] = make_ushort4(h0[0], h0[1], h0[2], h0[3]);
            *(ushort4*)&At[1][r][kl] = make_ushort4(h1[0], h1[1], h1[2], h1[3]);
            *(ushort4*)&At[2][r][kl] = make_ushort4(h2[0], h2[1], h2[2], h2[3]);
        }
        if (TRANSB) {
            #pragma unroll
            for (int i = 0; i < BN / 32; ++i) {
                int r = i * 32 + (tid >> 3);
                int kl = (tid & 7) * 4;
                float4 v = *(const float4*)&B[(long)(col0 + r) * K + (k0 + kl)];
                unsigned short h0[4], h1[4], h2[4];
                split3(v.x, h0[0], h1[0], h2[0]);
                split3(v.y, h0[1], h1[1], h2[1]);
                split3(v.z, h0[2], h1[2], h2[2]);
                split3(v.w, h0[3], h1[3], h2[3]);
                *(ushort4*)&Bt[0][r][kl] = make_ushort4(h0[0], h0[1], h0[2], h0[3]);
                *(ushort4*)&Bt[1][r][kl] = make_ushort4(h1[0], h1[1], h1[2], h1[3]);
                *(ushort4*)&Bt[2][r][kl] = make_ushort4(h2[0], h2[1], h2[2], h2[3]);
            }
        } else {
            constexpr int TPK = BN / 4;
            #pragma unroll
            for (int i = 0; i < BN / 32; ++i) {
                int kl = i * (256 / TPK) + tid / TPK;
                int nl = (tid % TPK) * 4;
                float4 v = *(const float4*)&B[(long)(k0 + kl) * Nn + (col0 + nl)];
                unsigned short s0, s1, s2;
                split3(v.x, s0, s1, s2);
                Bt[0][nl + 0][kl] = s0; Bt[1][nl + 0][kl] = s1; Bt[2][nl + 0][kl] = s2;
                split3(v.y, s0, s1, s2);
                Bt[0][nl + 1][kl] = s0; Bt[1][nl + 1][kl] = s1; Bt[2][nl + 1][kl] = s2;
                split3(v.z, s0, s1, s2);
                Bt[0][nl + 2][kl] = s0; Bt[1][nl + 2][kl] = s1; Bt[2][nl + 2][kl] = s2;
                split3(v.w, s0, s1, s2);
                Bt[0][nl + 3][kl] = s0; Bt[1][nl + 3][kl] = s1; Bt[2][nl + 3][kl] = s2;
            }
        }
        __syncthreads();
        bf16x8 bf[NR][3];
        #pragma unroll
        for (int nr = 0; nr < NR; ++nr) {
            int brow = wcol + nr * 16 + l16;
            #pragma unroll
            for (int s = 0; s < 3; ++s)
                bf[nr][s] = *(const bf16x8*)&Bt[s][brow][koff * 8];
        }
        #pragma unroll
        for (int mr = 0; mr < MR; ++mr) {
            int arow = wrow + mr * 16 + l16;
            bf16x8 a0 = *(const bf16x8*)&At[0][arow][koff * 8];
            bf16x8 a1 = *(const bf16x8*)&At[1][arow][koff * 8];
            bf16x8 a2 = *(const bf16x8*)&At[2][arow][koff * 8];
            #pragma unroll
            for (int nr = 0; nr < NR; ++nr) {
                f32x4 c = acc[mr][nr];
                c = __builtin_amdgcn_mfma_f32_16x16x32_bf16(a0, bf[nr][0], c, 0, 0, 0);
                c = __builtin_amdgcn_mfma_f32_16x16x32_bf16(a0, bf[nr][1], c, 0, 0, 0);
                c = __builtin_amdgcn_mfma_f32_16x16x32_bf16(a1, bf[nr][0], c, 0, 0, 0);
                c = __builtin_amdgcn_mfma_f32_16x16x32_bf16(a0, bf[nr][2], c, 0, 0, 0);
                c = __builtin_amdgcn_mfma_f32_16x16x32_bf16(a1, bf[nr][1], c, 0, 0, 0);
                c = __builtin_amdgcn_mfma_f32_16x16x32_bf16(a2, bf[nr][0], c, 0, 0, 0);
                acc[mr][nr] = c;
            }
        }
        __syncthreads();
    }
    #pragma unroll
    for (int mr = 0; mr < MR; ++mr) {
        #pragma unroll
        for (int r = 0; r < 4; ++r) {
            int gr = row0 + wrow + mr * 16 + koff * 4 + r;
            if (gr >= M) continue;
            #pragma unroll
            for (int nr = 0; nr < NR; ++nr) {
                int gc = col0 + wcol + nr * 16 + l16;
                float v = alpha * acc[mr][nr][r];
                if (Cin) v += beta * Cin[cb + (long)gr * ldc + gc];
                if (add_id && gr == gc) v += 1.f;
                Out[ob + (long)gr * ldo + gc] = v;
            }
        }
    }
}

static void fallback_launch(void* const* d_in, void* d_out, void* d_ws,
                            hipStream_t stream)
{
    const float* y0 = (const float*)d_in[1];
    const float* u  = (const float*)d_in[2];
    const float* Am = (const float*)d_in[3];
    const float* Bm = (const float*)d_in[4];
    float* Yout = (float*)d_out;
    float* w = (float*)d_ws;
    const float h = 0.01f;
    const int N = GN;

    float* Eyy = w;
    float* T1  = Eyy + (long)N * N;
    float* T2  = T1  + (long)N * N;
    float* V1  = T2  + (long)N * N;
    float* Vt  = V1  + (long)N * GM;
    float* V2  = Vt  + (long)N * GM;
    float* G1  = V2  + (long)N * GM;
    float* G2  = G1  + (long)N * GM;
    float* Z   = G2  + (long)N * GM;
    float* Zt  = Z   + (long)CCH * N;
    dim3 blk(256);

    auto gemm = [&](bool transb, const float* A, long ab, long lda,
                    const float* B, const float* Cin, long cb, long ldc, float beta,
                    float* Out, long ob, long ldo,
                    int M, int Nn, int K, float alpha, int add_id) {
        if (M > 1536 && (Nn % 128) == 0) {
            dim3 grid((M + 127) / 128, Nn / 128);
            if (transb)
                gemm_mfma<128, 128, true><<<grid, blk, 0, stream>>>(A, ab, lda, B, Cin, cb, ldc, beta, Out, ob, ldo, M, Nn, K, alpha, add_id);
            else
                gemm_mfma<128, 128, false><<<grid, blk, 0, stream>>>(A, ab, lda, B, Cin, cb, ldc, beta, Out, ob, ldo, M, Nn, K, alpha, add_id);
        } else {
            dim3 grid((M + 63) / 64, Nn / 64);
            if (transb)
                gemm_mfma<64, 64, true><<<grid, blk, 0, stream>>>(A, ab, lda, B, Cin, cb, ldc, beta, Out, ob, ldo, M, Nn, K, alpha, add_id);
            else
                gemm_mfma<64, 64, false><<<grid, blk, 0, stream>>>(A, ab, lda, B, Cin, cb, ldc, beta, Out, ob, ldo, M, Nn, K, alpha, add_id);
        }
    };

    scale_add_id_k<<<dim3(4, N), blk, 0, stream>>>(T1, Am, h / 5.f, N);
    {
        float* pc = T1; float* pn = T2;
        for (int k = 4; k >= 1; --k) {
            float* out = (k == 1) ? Eyy : pn;
            gemm(false, Am, 0, N, pc, nullptr, 0, 0, 0.f, out, 0, N, N, N, N, h / (float)k, 1);
            pn = pc; pc = out;
        }
    }
    const long NM = (long)N * GM;
    scale_copy_k<<<dim3((unsigned)((NM + 255) / 256)), blk, 0, stream>>>(V1, Bm, 1.f / 120.f, NM);
    {
        const float f1[4] = {1.f / 24.f, 1.f / 6.f, 0.5f, 1.f};
        float* pc = V1; float* pn = Vt;
        for (int j = 3; j >= 0; --j) {
            gemm(false, Am, 0, N, pc, Bm, 0, GM, f1[3 - j], pn, 0, GM, N, GM, N, h, 0);
            float* t = pc; pc = pn; pn = t;
        }
    }
    scale_copy_k<<<dim3((unsigned)((NM + 255) / 256)), blk, 0, stream>>>(V2, Bm, 1.f / 720.f, NM);
    {
        const float f2[4] = {1.f / 120.f, 1.f / 24.f, 1.f / 6.f, 0.5f};
        float* pc = V2; float* pn = Vt;
        for (int j = 3; j >= 0; --j) {
            gemm(false, Am, 0, N, pc, Bm, 0, GM, f2[3 - j], pn, 0, GM, N, GM, N, h, 0);
            float* t = pc; pc = pn; pn = t;
        }
    }
    g1g2_k<<<dim3((unsigned)((NM + 255) / 256)), blk, 0, stream>>>(G1, G2, V1, V2, h, NM);
    gemm(true, u, 0, GM, G1, nullptr, 0, 0, 0.f, Yout, (long)N, N, GT - 1, N, GM, 1.f, 0);
    gemm(true, u, GM, GM, G2, Yout, (long)N, N, 1.f, Yout, (long)N, N, GT - 1, N, GM, 1.f, 0);
    copy_rows_k<<<dim3(4, 1), blk, 0, stream>>>(Yout, 0, 0, y0, 0, 0, N);
    for (int s = 2; s <= SCH; ++s) {
        int Mr = (GT - 1 - s) / SCH + 1;
        gemm(true, Yout, (long)(s - 1) * N, (long)SCH * N, Eyy,
             Yout, (long)s * N, (long)SCH * N, 1.f,
             Yout, (long)s * N, (long)SCH * N, Mr, N, N, 1.f, 0);
    }
    copy_rows_k<<<dim3(4, 1), blk, 0, stream>>>(Z, 0, 0, y0, 0, 0, N);
    copy_rows_k<<<dim3(4, CCH - 1), blk, 0, stream>>>(Z, (long)N, (long)N,
                                                      Yout, (long)SCH * N, (long)SCH * N, N);
    gemm(false, Eyy, 0, N, Eyy, nullptr, 0, 0, 0.f, T1, 0, N, N, N, N, 1.f, 0);
    gemm(false, T1, 0, N, T1, nullptr, 0, 0, 0.f, T2, 0, N, N, N, N, 1.f, 0);
    gemm(false, T2, 0, N, T2, nullptr, 0, 0, 0.f, T1, 0, N, N, N, N, 1.f, 0);
    {
        float* Mc = T1; float* Mo = T2;
        float* Zc = Z;  float* Zn = Zt;
        for (int p = 0; p < 10; ++p) {
            int o = 1 << p;
            gemm(true, Zc, 0, N, Mc, Zc, (long)o * N, N, 1.f,
                 Zn, (long)o * N, N, CCH - o, N, N, 1.f, 0);
            copy_rows_k<<<dim3(4, o), blk, 0, stream>>>(Zn, 0, N, Zc, 0, N, N);
            if (p < 9) {
                gemm(false, Mc, 0, N, Mc, nullptr, 0, 0, 0.f, Mo, 0, N, N, N, N, 1.f, 0);
                float* t = Mc; Mc = Mo; Mo = t;
            }
            float* t = Zc; Zc = Zn; Zn = t;
        }
        copy_rows_k<<<dim3(4, CCH), blk, 0, stream>>>(Yout, 0, (long)SCH * N, Zc, 0, N, N);
        float* Q = Zc; float* Qt = Zn;
        for (int s = 1; s <= SCH - 1; ++s) {
            gemm(true, Q, 0, N, Eyy, nullptr, 0, 0, 0.f, Qt, 0, N, CCH, N, N, 1.f, 0);
            int Mr = (GT - 1 - s) / SCH + 1;
            add_rows_k<<<dim3(4, Mr), blk, 0, stream>>>(Yout, (long)s * N, (long)SCH * N, Qt, N);
            float* t = Q; Q = Qt; Qt = t;
        }
    }
}

// ---------------------------------------------------------------------------
extern "C" void kernel_launch(void* const* d_in, const int* in_sizes, int n_in,
                              void* d_out, int out_size, void* d_ws, size_t ws_size,
                              hipStream_t stream)
{
    (void)in_sizes; (void)n_in; (void)out_size;
    const size_t NEED = 46ull * 1024 * 1024;
    if (ws_size < NEED) { fallback_launch(d_in, d_out, d_ws, stream); return; }

    const float* y0 = (const float*)d_in[1];
    const float* u  = (const float*)d_in[2];
    const float* Am = (const float*)d_in[3];
    const float* Bm = (const float*)d_in[4];
    float* Yout = (float*)d_out;
    char* w = (char*)d_ws;
    const float h = 0.01f;
    const size_t MB = 1024 * 1024;
    const long P1M = 1 << 20;                  // 1024x1024 plane limb stride
    const long P2M = 1 << 21;                  // 2048x1024 plane limb stride
    const long PUS = 1 << 22;                  // 8192x512  (PU)
    const long PBS = 1 << 19;                  // 512x1024  (PBT)
    const int  BIG = 1 << 30;

    // ws layout (46 MB, time-phased):
    unsigned short* PU   = (unsigned short*)(w);            // [0,16) c-staging only
    unsigned short* PZW1 = (unsigned short*)(w);            // [0,8)  after PU dead
    unsigned short* PZW2 = (unsigned short*)(w + 8 * MB);   // [8,16)
    unsigned short* CH1  = (unsigned short*)(w + 16 * MB);  // [16,24) chain ping
    unsigned short* SQa  = (unsigned short*)(w + 18 * MB);  // V-row区 reuse: limb1 at +P2M
    unsigned short* CH2  = (unsigned short*)(w + 24 * MB);  // [24,32) chain pong
    unsigned short* PY1  = (unsigned short*)(w + 24 * MB);  // reuse CH2 low
    unsigned short* PY2  = (unsigned short*)(w + 28 * MB);  // reuse CH2 high
    unsigned short* PE   = (unsigned short*)(w + 32 * MB);  // planes(E)
    unsigned short* PG   = (unsigned short*)(w + 36 * MB);  // planes(Gcat) -> later SQb
    unsigned short* SQb  = PG;
    unsigned short* PA   = (unsigned short*)(w + 40 * MB);  // planes(A) -> later PW
    unsigned short* PW   = PA;
    unsigned short* PBT  = (unsigned short*)(w + 44 * MB);  // planes(B^T), 2MB

    dim3 blk(256), blk5(512);

    // ---- 1. planes(Am) ----
    split_pl_k<<<dim3(4096), blk, 0, stream>>>(Am, PA, P1M, 10, 1.f, (long)1 << 20);

    // ---- 2. seeds for fused expm+phi chain (stacked 2048 rows in CH1) ----
    trsp_k<<<dim3(32, 32), blk, 0, stream>>>(Am, 1024, h / 5.f, 1, CH1, P2M, 0);
    trsp_k<<<dim3(16, 32), blk, 0, stream>>>(Bm, 512, 1.f / 120.f, 0, CH1, P2M, 1024);
    trsp_k<<<dim3(16, 32), blk, 0, stream>>>(Bm, 512, 1.f / 720.f, 0, CH1, P2M, 1536);
    trsp_k<<<dim3(16, 32), blk, 0, stream>>>(Bm, 512, 1.f, 0, PBT, PBS, 0);

    // ---- 3. fused chain x4: rows 0-1023 expm Horner, rows 1024-2047 phi chains ----
    {
        const float alE[4] = {h / 4.f, h / 3.f, h / 2.f, h};
        const float f1[4] = {1.f / 24.f, 1.f / 6.f, 0.5f, 1.f};
        const float f2[4] = {1.f / 120.f, 1.f / 24.f, 1.f / 6.f, 0.5f};
        unsigned short* cc = CH1; unsigned short* cn = CH2;
        for (int j = 0; j < 4; ++j) {
            gemm_pp<64><<<dim3(32, 16), blk5, 0, stream>>>(
                cc, P2M, 1024, 10, PA, P1M,
                nullptr, 0, 0, PBT, PBS, 511,
                1024, 1536, f1[j], f2[j],
                nullptr, 0, 0, cn, P2M, 0, 1,
                BIG, 0, 2048, alE[j], h, 1024, 1,
                nullptr, 0, nullptr, nullptr, 0, 0, BIG);
            unsigned short* t = cc; cc = cn; cn = t;
        }  // 4 swaps -> final in CH1 (rows 0-1023 = E^T, 1024+ = [V1^T;V2^T])
    }
    tspp_k<<<dim3(32, 32), blk, 0, stream>>>(CH1, P2M, 0, PE, P1M);
    gtspp_k<<<dim3(16, 32, 2), blk, 0, stream>>>(CH1 + (1 << 20), P2M, PG, P1M, h);

    // ---- 4. planes(u) ----
    split_pl_k<<<dim3(16384), blk, 0, stream>>>(u, PU, PUS, 9, 1.f, PUS);

    // ---- 5. c-staging: Yout[t] = [u_{t-1}|u_t] @ Gcat^T (+ planes of rows 8i+1) ----
    gemm_pp<128><<<dim3(64, 8), blk5, 0, stream>>>(
        PU, PUS, 512, 9, PG, P1M,
        nullptr, 0, 0, nullptr, 0, -1,
        0, BIG, 0.f, 0.f,
        Yout, 1024, 1024, PY1, P1M, 1, 1,
        BIG, 0, GT - 1, 1.f, 1.f, BIG, 0,
        nullptr, 0, nullptr, nullptr, 0, 0, BIG);
    copy_rows_k<<<dim3(4, 1), blk, 0, stream>>>(Yout, 0, 0, y0, 0, 0, 1024);

    // ---- 6. phase 1 fused with E-squarings (seg2 = rows 1024+) ----
    // F1: s=2 | E^2,T = E^T @ planes(E) -> SQa (limb stride P2M: [18,20)+[22,24))
    gemm_pp<64><<<dim3(32, 16), blk5, 0, stream>>>(
        PY1, P1M, 1024, 10, PE, P1M,
        Yout, 2 * 1024, 8192, nullptr, 0, -1,
        0, BIG, 1.f, 0.f,
        Yout, 2 * 1024, 8192, PY2, P1M, 0, 1,
        BIG, 0, 2048, 1.f, 1.f, BIG, 0,
        CH1, P2M, PE, SQa, P2M, 0, 1024);
    tspp_k<<<dim3(32, 32), blk, 0, stream>>>(SQa, P2M, 0, PW, P1M);
    // F2: s=3 | E^4,T = E^2,T @ planes(E^2) -> SQb
    gemm_pp<64><<<dim3(32, 16), blk5, 0, stream>>>(
        PY2, P1M, 1024, 10, PE, P1M,
        Yout, 3 * 1024, 8192, nullptr, 0, -1,
        0, BIG, 1.f, 0.f,
        Yout, 3 * 1024, 8192, PY1, P1M, 0, 1,
        BIG, 0, 2048, 1.f, 1.f, BIG, 0,
        SQa, P2M, PW, SQb, P1M, 0, 1024);
    tspp_k<<<dim3(32, 32), blk, 0, stream>>>(SQb, P1M, 0, PW, P1M);
    // F3: s=4 | E^8,T = E^4,T @ planes(E^4) -> PZW1 rows 1024+
    gemm_pp<64><<<dim3(32, 16), blk5, 0, stream>>>(
        PY1, P1M, 1024, 10, PE, P1M,
        Yout, 4 * 1024, 8192, nullptr, 0, -1,
        0, BIG, 1.f, 0.f,
        Yout, 4 * 1024, 8192, PY2, P1M, 0, 1,
        BIG, 0, 2048, 1.f, 1.f, BIG, 0,
        SQb, P1M, PW, PZW1, P2M, 1024, 1024);
    tspp_k<<<dim3(32, 32), blk, 0, stream>>>(PZW1, P2M, 1024, PW, P1M);
    // s = 5..7 solo
    {
        unsigned short* pc = PY2; unsigned short* pn = PY1;
        for (int s = 5; s <= 7; ++s) {
            gemm_pp<64><<<dim3(16, 16), blk5, 0, stream>>>(
                pc, P1M, 1024, 10, PE, P1M,
                Yout, (long)s * 1024, 8192, nullptr, 0, -1,
                0, BIG, 1.f, 0.f,
                Yout, (long)s * 1024, 8192, pn, P1M, 0, 1,
                BIG, 0, 1024, 1.f, 1.f, BIG, 0,
                nullptr, 0, nullptr, nullptr, 0, 0, BIG);
            unsigned short* t = pc; pc = pn; pn = t;
        }
        // s=8 -> boundary rows 8(i+1), plane row i+1 via zoff=1 (pc == PY1 here)
        gemm_pp<64><<<dim3(16, 16), blk5, 0, stream>>>(
            pc, P1M, 1024, 10, PE, P1M,
            Yout, 0, 8192, nullptr, 0, -1,
            0, BIG, 1.f, 0.f,
            Yout, 0, 8192, PZW1, P2M, 0, 1,
            BIG, 1, 1023, 1.f, 1.f, BIG, 0,
            nullptr, 0, nullptr, nullptr, 0, 0, BIG);
    }
    // z_0 = y0 -> PZW1 plane row 0
    split_pl_k<<<dim3(4), blk, 0, stream>>>(y0, PZW1, P2M, 10, 1.f, 1024);

    // ---- 7. fused doubling: [Zn; Wnext^T] = [Zc[i-o]@W^T + Zc[i]; W^T@W^T] ----
    {
        unsigned short* PZc = PZW1; unsigned short* PZn = PZW2;
        for (int p = 0; p < 10; ++p) {
            int o = 1 << p;
            int Mr = (p == 9) ? 1024 : 2048;
            gemm_pp<64><<<dim3(Mr / 64, 16), blk5, 0, stream>>>(
                PZc, P2M, 1024, 10, PW, P1M,
                nullptr, 0, 0, PZc, P2M, -1,
                0, 1024, 1.f, 0.f,
                nullptr, 0, 0, PZn, P2M, 0, 1,
                1024, o, Mr, 1.f, 1.f, BIG, 0,
                nullptr, 0, nullptr, nullptr, 0, 0, BIG);
            // unchanged prefix rows [0,o): copy both plane limbs
            copy_rows_k<<<dim3(2, o), blk, 0, stream>>>(
                (float*)PZn, 0, 512, (float*)PZc, 0, 512, 512);
            copy_rows_k<<<dim3(2, o), blk, 0, stream>>>(
                (float*)PZn + (1 << 20), 0, 512, (float*)PZc + (1 << 20), 0, 512, 512);
            if (p < 9)
                tspp_k<<<dim3(32, 32), blk, 0, stream>>>(PZn, P2M, 1024, PW, P1M);
            unsigned short* t = PZc; PZc = PZn; PZn = t;
        }  // 10 swaps -> final Z planes back in PZW1
    }

    // ---- 8. phase 3: boundary rows exact, then y_{8i+s} += E^s z_i, s=1..7 ----
    cprows_pl<<<dim3(4, 1024), blk, 0, stream>>>(Yout, PZW1, P2M);
    copy_rows_k<<<dim3(4, 1), blk, 0, stream>>>(Yout, 0, 0, y0, 0, 0, 1024);
    {
        const unsigned short* pc = PZW1; long apsz = P2M;
        unsigned short* pn = PY1;
        for (int s = 1; s <= 7; ++s) {
            gemm_pp<64><<<dim3(16, 16), blk5, 0, stream>>>(
                pc, apsz, 1024, 10, PE, P1M,
                Yout, (long)s * 1024, 8192, nullptr, 0, -1,
                0, BIG, 1.f, 0.f,
                Yout, (long)s * 1024, 8192,
                (s < 7) ? pn : nullptr, P1M, 0, 2,
                BIG, 0, 1024, 1.f, 1.f, BIG, 0,
                nullptr, 0, nullptr, nullptr, 0, 0, BIG);
            pc = pn; apsz = P1M;
            pn = (pn == PY1) ? PY2 : PY1;
        }
    }
}

// Round 9
// 808.490 us; speedup vs baseline: 1.9060x; 1.0776x over previous
//
#include <hip/hip_runtime.h>

// Problem constants (fixed in the reference file)
#define GT 8192      // time steps
#define GN 1024      // state dim
#define GM 512       // input dim
#define CCH 1024     // scan chunks
#define SCH 8        // steps per chunk

typedef __attribute__((ext_vector_type(8))) short bf16x8;
typedef __attribute__((ext_vector_type(4))) float f32x4;

__device__ __forceinline__ unsigned short f2bf(float x) {   // RNE fp32->bf16
    unsigned int u = __float_as_uint(x);
    u += 0x7FFF + ((u >> 16) & 1);
    return (unsigned short)(u >> 16);
}
__device__ __forceinline__ float bf2f(unsigned short b) {
    return __uint_as_float(((unsigned int)b) << 16);
}
__device__ __forceinline__ void split2(float x, unsigned short& h0, unsigned short& h1) {
    h0 = f2bf(x);
    h1 = f2bf(x - bf2f(h0));
}
__device__ __forceinline__ void split3(float x, unsigned short& s0,
                                       unsigned short& s1, unsigned short& s2) {
    s0 = f2bf(x); float r = x - bf2f(s0);
    s1 = f2bf(r); r -= bf2f(s1);
    s2 = f2bf(r);
}
// storage swizzle: XOR element bits 3-4 with (row>>1)&3 (row = e>>sh). Involution.
__device__ __forceinline__ long swz(long e, int sh) {
    return e ^ (((e >> (sh + 1)) & 3) << 3);
}
// async 16B global->LDS (dest wave-uniform base; HW scatters lane*16; src per-lane)
__device__ __forceinline__ void gl16(const unsigned short* g, unsigned short* l) {
    __builtin_amdgcn_global_load_lds(
        (const __attribute__((address_space(1))) unsigned int*)g,
        (__attribute__((address_space(3))) unsigned int*)l, 16, 0, 0);
}

// ---------------------------------------------------------------------------
// Plane x plane GEMM; 512 threads = 8 waves = (2 x WN quads) x KS k-groups.
// KS=2: waves 0-3 / 4-7 split the 64-k step; f32 LDS reduce at end.
// KS=1: 8 output quads, 32-k steps, no reduce.
// Out = aa * A @ B^T (+ bb*Cin) (+I), K=1024, N=1024, 2-limb bf16 planes,
// 3 limb products. A element (r,k) at swz(r*alda+k, aldsh), limb1 +apsz.
// A row shift: rows ar < ashiftN stage from (ar - ashift) clamped >= 0.
// trow = (gr<segN)? gr+zoff : gr (skip on segment cross).
// aa = trow<asplit? alpha:alphaB; bb = trow<bzero? 0 : (trow<bsplit? beta:betaB).
// Cin: fp32 Cf or planes Cp at row trow&cmask. Of optional fp32 out.
// Pout: plane emission (pmode 1: v, 2: aa*acc); pstep8 -> rows trow%8==0 only.
// DUAL (Ap2 set): blocks row0>=seg2 compute Ap2@Bp2^T pure (A row gr-seg2),
//   planes -> Pout2 row gr-seg2+p2off (stride ppsz2).
// TRANSPOSE (PoutT set, BM==64): blocks row0>=tposeN also emit the transposed
//   tile as planes to PoutT (stride 1M): PoutT[col0+i][row0-tposeN+j].
// ---------------------------------------------------------------------------
template <int BM, int WN, int KS>
__global__ __launch_bounds__(512) void gemm_pp(
    const unsigned short* __restrict__ Ap, long apsz, int alda, int aldsh,
    int ashift, int ashiftN,
    const unsigned short* __restrict__ Bp, long bpsz,
    const float* __restrict__ Cf, long cfb, long cfld,
    const unsigned short* __restrict__ Cp, long cpsz, int cmask,
    int bzero, int bsplit, float beta, float betaB,
    float* __restrict__ Of, long ofb, long ofld,
    unsigned short* __restrict__ Pout, long ppsz, int pstep8, int pmode,
    int segN, int zoff,
    int M, float alpha, float alphaB, int asplit, int add_id,
    const unsigned short* __restrict__ Ap2, long apsz2,
    const unsigned short* __restrict__ Bp2,
    unsigned short* __restrict__ Pout2, long ppsz2, int p2off, int seg2,
    unsigned short* __restrict__ PoutT, int tposeN)
{
    constexpr int NQ = 2 * WN;             // output quads
    constexpr int MTM = BM / 32;           // 16-tiles in M per wave
    constexpr int MTN = BM / (WN * 16);    // 16-tiles in N per wave
    constexpr int CPW = KS * BM / 32;      // staging chunks per wave
    __shared__ __align__(16) unsigned short At[2][KS][2][BM][32];
    __shared__ __align__(16) unsigned short Bt[2][KS][2][BM][32];

    const int tid = threadIdx.x;
    const int lane = tid & 63;
    const int w = tid >> 6;
    const int ksub = w / NQ;
    const int quad = w % NQ;
    const int wr = (quad / WN) * (BM / 2);
    const int wc = (quad % WN) * (BM / WN);
    const int l16 = lane & 15, koff = lane >> 4;
    const int row0 = blockIdx.x * BM;
    const int col0 = blockIdx.y * BM;
    const int lr4 = lane >> 2;
    const int lg = lane & 3;
    const bool s2 = (Ap2 != nullptr) && (row0 >= seg2);
    const bool lead = (KS == 1) || (ksub == 0);

    f32x4 acc[MTM][MTN] = {};

    auto stage = [&](int bsel, int k0) {
        #pragma unroll
        for (int ci = 0; ci < CPW; ++ci) {
            const int c = w * CPW + ci;
            const int op = c / (KS * BM / 8);
            const int rem = c % (KS * BM / 8);
            const int limb = rem / (KS * BM / 16);
            const int rem2 = rem % (KS * BM / 16);
            const int kk = rem2 / (BM / 16);
            const int rb = (rem2 % (BM / 16)) * 16;
            const int lr = rb + lr4;
            const int q = lg ^ ((lr >> 1) & 3);
            long e; int sh; const unsigned short* base;
            if (op == 0) {
                if (!s2) {
                    int ar = row0 + lr;
                    if (ar < ashiftN) { ar -= ashift; if (ar < 0) ar = 0; }
                    e = (long)ar * alda + k0 + kk * 32 + (q << 3); sh = aldsh;
                    base = Ap + (limb ? apsz : 0);
                } else {
                    e = (long)(row0 - seg2 + lr) * 1024 + k0 + kk * 32 + (q << 3); sh = 10;
                    base = Ap2 + (limb ? apsz2 : 0);
                }
            } else {
                e = (long)(col0 + lr) * 1024 + k0 + kk * 32 + (q << 3); sh = 10;
                base = (s2 ? Bp2 : Bp) + (limb ? bpsz : 0);
            }
            long f = swz(e, sh);
            unsigned short* l = (op == 0 ? &At[bsel][kk][limb][rb][0]
                                         : &Bt[bsel][kk][limb][rb][0]);
            gl16(base + f, l);
        }
    };

    stage(0, 0);
    __syncthreads();
    int cur = 0;
    for (int k0 = 0; k0 < 1024; k0 += KS * 32) {
        if (k0 + KS * 32 < 1024) stage(cur ^ 1, k0 + KS * 32);

        const int kk = ksub;
        bf16x8 a0[MTM], a1[MTM], b0[MTN], b1[MTN];
        #pragma unroll
        for (int mi = 0; mi < MTM; ++mi) {
            int lr = wr + mi * 16 + l16;
            int off = (koff ^ ((lr >> 1) & 3)) << 3;
            a0[mi] = *(const bf16x8*)&At[cur][kk][0][lr][off];
            a1[mi] = *(const bf16x8*)&At[cur][kk][1][lr][off];
        }
        #pragma unroll
        for (int ni = 0; ni < MTN; ++ni) {
            int lr = wc + ni * 16 + l16;
            int off = (koff ^ ((lr >> 1) & 3)) << 3;
            b0[ni] = *(const bf16x8*)&Bt[cur][kk][0][lr][off];
            b1[ni] = *(const bf16x8*)&Bt[cur][kk][1][lr][off];
        }
        #pragma unroll
        for (int mi = 0; mi < MTM; ++mi)
            #pragma unroll
            for (int ni = 0; ni < MTN; ++ni) {
                f32x4 cc = acc[mi][ni];
                cc = __builtin_amdgcn_mfma_f32_16x16x32_bf16(a0[mi], b0[ni], cc, 0, 0, 0);
                cc = __builtin_amdgcn_mfma_f32_16x16x32_bf16(a0[mi], b1[ni], cc, 0, 0, 0);
                cc = __builtin_amdgcn_mfma_f32_16x16x32_bf16(a1[mi], b0[ni], cc, 0, 0, 0);
                acc[mi][ni] = cc;
            }
        __syncthreads();
        cur ^= 1;
    }

    if (KS == 2) {   // cross-ksub reduce (alias At as f32 scratch)
        float* red = (float*)&At[0][0][0][0][0];
        if (ksub == 1) {
            #pragma unroll
            for (int mi = 0; mi < MTM; ++mi)
                #pragma unroll
                for (int ni = 0; ni < MTN; ++ni)
                    *(f32x4*)&red[(((quad * MTM + mi) * MTN + ni) * 64 + lane) * 4] =
                        acc[mi][ni];
        }
        __syncthreads();
        if (ksub == 0) {
            #pragma unroll
            for (int mi = 0; mi < MTM; ++mi)
                #pragma unroll
                for (int ni = 0; ni < MTN; ++ni) {
                    f32x4 o = *(const f32x4*)
                        &red[(((quad * MTM + mi) * MTN + ni) * 64 + lane) * 4];
                    acc[mi][ni][0] += o[0]; acc[mi][ni][1] += o[1];
                    acc[mi][ni][2] += o[2]; acc[mi][ni][3] += o[3];
                }
        }
    }

    const bool tp = (PoutT != nullptr) && (row0 >= tposeN);
    float* T = (float*)&Bt[0][0][0][0][0];   // 64x65 f32 = 16.6KB, Bt dead

    if (s2) {                               // dual: pure product -> Pout2 planes
        if (lead) {
            #pragma unroll
            for (int mi = 0; mi < MTM; ++mi)
                #pragma unroll
                for (int r = 0; r < 4; ++r) {
                    const int gr = row0 + wr + mi * 16 + koff * 4 + r;
                    if (gr >= M) continue;
                    const int prow = gr - seg2 + p2off;
                    #pragma unroll
                    for (int ni = 0; ni < MTN; ++ni) {
                        const int gc = col0 + wc + ni * 16 + l16;
                        float pv = acc[mi][ni][r];
                        long f = swz((long)prow * 1024 + gc, 10);
                        unsigned short h0 = f2bf(pv);
                        Pout2[f] = h0;
                        Pout2[ppsz2 + f] = f2bf(pv - bf2f(h0));
                        if (tp) T[(wr + mi * 16 + koff * 4 + r) * 65 + gc - col0] = pv;
                    }
                }
        }
    } else {
        if (lead) {
            #pragma unroll
            for (int mi = 0; mi < MTM; ++mi) {
                #pragma unroll
                for (int r = 0; r < 4; ++r) {
                    const int gr = row0 + wr + mi * 16 + koff * 4 + r;
                    if (gr >= M) continue;
                    const int trow = (gr < segN) ? gr + zoff : gr;
                    if (gr < segN && trow >= segN) continue;
                    const float aa = (trow < asplit) ? alpha : alphaB;
                    const float bb = (trow < bzero) ? 0.f
                                    : ((trow < bsplit) ? beta : betaB);
                    #pragma unroll
                    for (int ni = 0; ni < MTN; ++ni) {
                        const int gc = col0 + wc + ni * 16 + l16;
                        float vp = aa * acc[mi][ni][r];
                        float v = vp;
                        if (bb != 0.f) {
                            int crow = trow & cmask;
                            if (Cf) v += bb * Cf[cfb + (long)crow * cfld + gc];
                            else if (Cp) {
                                long f = swz((long)crow * 1024 + gc, 10);
                                v += bb * (bf2f(Cp[f]) + bf2f(Cp[cpsz + f]));
                            }
                        }
                        if (add_id && gr == gc) v += 1.f;
                        if (Of) Of[ofb + (long)trow * ofld + gc] = v;
                        if (Pout && (!pstep8 || (trow & 7) == 0)) {
                            int prow = pstep8 ? (trow >> 3) : trow;
                            long f = swz((long)prow * 1024 + gc, 10);
                            float pv = (pmode == 2) ? vp : v;
                            unsigned short h0 = f2bf(pv);
                            Pout[f] = h0;
                            Pout[ppsz + f] = f2bf(pv - bf2f(h0));
                        }
                        if (tp) T[(wr + mi * 16 + koff * 4 + r) * 65 + gc - col0] = v;
                    }
                }
            }
        }
    }

    if (BM == 64 && tp) {                   // transposed plane emission
        __syncthreads();
        if (tid < 256) {
            const int i = tid >> 2;
            const int jb = (tid & 3) * 16;
            const int prow = col0 + i;
            #pragma unroll
            for (int e2 = 0; e2 < 16; ++e2) {
                int j = jb + e2;
                float v = T[j * 65 + i];
                long f = swz((long)prow * 1024 + (row0 - tposeN + j), 10);
                unsigned short h0 = f2bf(v);
                PoutT[f] = h0;
                PoutT[(long)(1 << 20) + f] = f2bf(v - bf2f(h0));
            }
        }
    }
}

// ---- X (cnt fp32, rows of length 2^ldsh) -> swizzled 2-limb planes ----
__global__ void split_pl_k(const float* __restrict__ X, unsigned short* __restrict__ P,
                           long psz, int ldsh, float s, long cnt)
{
    long i = (long)blockIdx.x * 256 + threadIdx.x;
    if (i >= cnt) return;
    float v = s * X[i];
    long f = swz(i, ldsh);
    unsigned short h0 = f2bf(v);
    P[f] = h0;
    P[psz + f] = f2bf(v - bf2f(h0));
}

// ---- planes of s*in^T (+I): out rows (roff+)0..R-1, in is 1024 x R fp32 ----
__global__ void trsp_k(const float* __restrict__ in, int R, float s, int add_id,
                       unsigned short* __restrict__ P, long psz, int roff)
{
    __shared__ float t[32][33];
    const int tx = threadIdx.x & 31, ty4 = threadIdx.x >> 5;
    const int r0 = blockIdx.x * 32, c0 = blockIdx.y * 32;
    #pragma unroll
    for (int i = 0; i < 4; ++i)
        t[ty4 * 4 + i][tx] = in[(long)(c0 + ty4 * 4 + i) * R + r0 + tx];
    __syncthreads();
    #pragma unroll
    for (int i = 0; i < 4; ++i) {
        int r = r0 + ty4 * 4 + i, c = c0 + tx;
        float v = s * t[tx][ty4 * 4 + i];
        if (add_id && r == c) v += 1.f;
        long f = swz((long)(r + roff) * 1024 + c, 10);
        unsigned short h0 = f2bf(v);
        P[f] = h0;
        P[psz + f] = f2bf(v - bf2f(h0));
    }
}

// ---- planes(X) from planes(X^T): OUT[c][r] = IN[irow0+r][c] ----
__global__ void tspp_k(const unsigned short* __restrict__ IN, long ipsz, long irow0,
                       unsigned short* __restrict__ OUT, long opsz)
{
    __shared__ float t[32][33];
    const int tx = threadIdx.x & 31, ty4 = threadIdx.x >> 5;
    const int r0 = blockIdx.x * 32, c0 = blockIdx.y * 32;
    #pragma unroll
    for (int i = 0; i < 4; ++i) {
        long f = swz((irow0 + r0 + ty4 * 4 + i) * 1024 + c0 + tx, 10);
        t[ty4 * 4 + i][tx] = bf2f(IN[f]) + bf2f(IN[ipsz + f]);
    }
    __syncthreads();
    #pragma unroll
    for (int i = 0; i < 4; ++i) {
        int orow = c0 + ty4 * 4 + i;
        long f = swz((long)orow * 1024 + r0 + tx, 10);
        float v = t[tx][ty4 * 4 + i];
        unsigned short h0 = f2bf(v);
        OUT[f] = h0;
        OUT[opsz + f] = f2bf(v - bf2f(h0));
    }
}

// ---- Gcat planes from stacked [V1^T; V2^T] planes ----
__global__ void gtspp_k(const unsigned short* __restrict__ PV, long vpsz,
                        unsigned short* __restrict__ PG, long gpsz, float h)
{
    __shared__ float t[32][33];
    const int tx = threadIdx.x & 31, ty4 = threadIdx.x >> 5;
    const int k0 = blockIdx.x * 32, n0 = blockIdx.y * 32, z = blockIdx.z;
    #pragma unroll
    for (int i = 0; i < 4; ++i) {
        int k = k0 + ty4 * 4 + i, n = n0 + tx;
        long f2 = swz((long)(512 + k) * 1024 + n, 10);
        float v2 = bf2f(PV[f2]) + bf2f(PV[vpsz + f2]);
        float v;
        if (z == 0) {
            long f1 = swz((long)k * 1024 + n, 10);
            v = h * (bf2f(PV[f1]) + bf2f(PV[vpsz + f1]) - v2);
        } else v = h * v2;
        t[ty4 * 4 + i][tx] = v;
    }
    __syncthreads();
    #pragma unroll
    for (int i = 0; i < 4; ++i) {
        int n = n0 + ty4 * 4 + i, kk = z * 512 + k0 + tx;
        long f = swz((long)n * 1024 + kk, 10);
        float v = t[tx][ty4 * 4 + i];
        unsigned short h0 = f2bf(v);
        PG[f] = h0;
        PG[gpsz + f] = f2bf(v - bf2f(h0));
    }
}

// dst[db + r*ds + c] = src[sb + r*ss + c]
__global__ void copy_rows_k(float* __restrict__ dst, long db, long ds,
                            const float* __restrict__ src, long sb, long ss, int ncols)
{
    int r = blockIdx.y;
    int c = blockIdx.x * 256 + threadIdx.x;
    if (c < ncols) dst[db + (long)r * ds + c] = src[sb + (long)r * ss + c];
}

// dst[db + r*ds + c] += src[r*ncols + c]
__global__ void add_rows_k(float* __restrict__ dst, long db, long ds,
                           const float* __restrict__ src, int ncols)
{
    int r = blockIdx.y;
    int c = blockIdx.x * 256 + threadIdx.x;
    if (c < ncols) dst[db + (long)r * ds + c] += src[(long)r * ncols + c];
}

__global__ void scale_add_id_k(float* __restrict__ dst, const float* __restrict__ src,
                               float s, int n)
{
    int r = blockIdx.y;
    int c = blockIdx.x * 256 + threadIdx.x;
    if (c < n) dst[(long)r * n + c] = s * src[(long)r * n + c] + ((r == c) ? 1.f : 0.f);
}

__global__ void scale_copy_k(float* __restrict__ dst, const float* __restrict__ src,
                             float s, long cnt)
{
    long i = (long)blockIdx.x * 256 + threadIdx.x;
    if (i < cnt) dst[i] = s * src[i];
}

__global__ void g1g2_k(float* __restrict__ g1, float* __restrict__ g2,
                       const float* __restrict__ v1, const float* __restrict__ v2,
                       float h, long cnt)
{
    long i = (long)blockIdx.x * 256 + threadIdx.x;
    if (i < cnt) {
        float a = v1[i], b = v2[i];
        g1[i] = h * (a - b);
        g2[i] = h * b;
    }
}

// ---------------------------------------------------------------------------
// FALLBACK (round-3, 3-limb, 30 MB ws) — only if ws_size < 46 MB.
// ---------------------------------------------------------------------------
template <int BM, int BN, bool TRANSB>
__global__ __launch_bounds__(256) void gemm_mfma(
    const float* __restrict__ A, long ab, long lda,
    const float* __restrict__ B,
    const float* __restrict__ Cin, long cb, long ldc, float beta,
    float* __restrict__ Out, long ob, long ldo,
    int M, int Nn, int K, float alpha, int add_id)
{
    constexpr int LDT = 40;
    __shared__ unsigned short At[3][BM][LDT];
    __shared__ unsigned short Bt[3][BN][LDT];
    const int tid = threadIdx.x;
    const int lane = tid & 63;
    const int wid = tid >> 6;
    const int row0 = blockIdx.x * BM;
    const int col0 = blockIdx.y * BN;
    constexpr int MR = BM / 32;
    constexpr int NR = BN / 32;
    const int wrow = (wid >> 1) * (BM / 2);
    const int wcol = (wid & 1) * (BN / 2);
    const int l16 = lane & 15;
    const int koff = lane >> 4;
    f32x4 acc[MR][NR] = {};

    for (int k0 = 0; k0 < K; k0 += 32) {
        #pragma unroll
        for (int i = 0; i < BM / 32; ++i) {
            int r = i * 32 + (tid >> 3);
            int kl = (tid & 7) * 4;
            int gr = row0 + r;
            float4 v = make_float4(0.f, 0.f, 0.f, 0.f);
            if (gr < M) v = *(const float4*)&A[ab + (long)gr * lda + (k0 + kl)];
            unsigned short h0[4], h1[4], h2[4];
            split3(v.x, h0[0], h1[0], h2[0]);
            split3(v.y, h0[1], h1[1], h2[1]);
            split3(v.z, h0[2], h1[2], h2[2]);
            split3(v.w, h0[3], h1[3], h2[3]);
            *(ushort4*)&At[0][r][kl] = make_ushort4(h0[0], h0[1], h0[2], h0[3]);
            *(ushort4*)&At[1][r][kl] = make_ushort4(h1[0], h1[1], h1[2], h1[3]);
            *(ushort4*)&At[2][r][kl] = make_ushort4(h2[0], h2[1], h2[2], h2[3]);
        }
        if (TRANSB) {
            #pragma unroll
            for (int i = 0; i < BN / 32; ++i) {
                int r = i * 32 + (tid >> 3);
                int kl = (tid & 7) * 4;
                float4 v = *(const float4*)&B[(long)(col0 + r) * K + (k0 + kl)];
                unsigned short h0[4], h1[4], h2[4];
                split3(v.x, h0[0], h1[0], h2[0]);
                split3(v.y, h0[1], h1[1], h2[1]);
                split3(v.z, h0[2], h1[2], h2[2]);
                split3(v.w, h0[3], h1[3], h2[3]);
                *(ushort4*)&Bt[0][r][kl] = make_ushort4(h0[0], h0[1], h0[2], h0[3]);
                *(ushort4*)&Bt[1][r][kl] = make_ushort4(h1[0], h1[1], h1[2], h1[3]);
                *(ushort4*)&Bt[2][r][kl] = make_ushort4(h2[0], h2[1], h2[2], h2[3]);
            }
        } else {
            constexpr int TPK = BN / 4;
            #pragma unroll
            for (int i = 0; i < BN / 32; ++i) {
                int kl = i * (256 / TPK) + tid / TPK;
                int nl = (tid % TPK) * 4;
                float4 v = *(const float4*)&B[(long)(k0 + kl) * Nn + (col0 + nl)];
                unsigned short s0, s1, s2;
                split3(v.x, s0, s1, s2);
                Bt[0][nl + 0][kl] = s0; Bt[1][nl + 0][kl] = s1; Bt[2][nl + 0][kl] = s2;
                split3(v.y, s0, s1, s2);
                Bt[0][nl + 1][kl] = s0; Bt[1][nl + 1][kl] = s1; Bt[2][nl + 1][kl] = s2;
                split3(v.z, s0, s1, s2);
                Bt[0][nl + 2][kl] = s0; Bt[1][nl + 2][kl] = s1; Bt[2][nl + 2][kl] = s2;
                split3(v.w, s0, s1, s2);
                Bt[0][nl + 3][kl] = s0; Bt[1][nl + 3][kl] = s1; Bt[2][nl + 3][kl] = s2;
            }
        }
        __syncthreads();
        bf16x8 bf[NR][3];
        #pragma unroll
        for (int nr = 0; nr < NR; ++nr) {
            int brow = wcol + nr * 16 + l16;
            #pragma unroll
            for (int s = 0; s < 3; ++s)
                bf[nr][s] = *(const bf16x8*)&Bt[s][brow][koff * 8];
        }
        #pragma unroll
        for (int mr = 0; mr < MR; ++mr) {
            int arow = wrow + mr * 16 + l16;
            bf16x8 a0 = *(const bf16x8*)&At[0][arow][koff * 8];
            bf16x8 a1 = *(const bf16x8*)&At[1][arow][koff * 8];
            bf16x8 a2 = *(const bf16x8*)&At[2][arow][koff * 8];
            #pragma unroll
            for (int nr = 0; nr < NR; ++nr) {
                f32x4 c = acc[mr][nr];
                c = __builtin_amdgcn_mfma_f32_16x16x32_bf16(a0, bf[nr][0], c, 0, 0, 0);
                c = __builtin_amdgcn_mfma_f32_16x16x32_bf16(a0, bf[nr][1], c, 0, 0, 0);
                c = __builtin_amdgcn_mfma_f32_16x16x32_bf16(a1, bf[nr][0], c, 0, 0, 0);
                c = __builtin_amdgcn_mfma_f32_16x16x32_bf16(a0, bf[nr][2], c, 0, 0, 0);
                c = __builtin_amdgcn_mfma_f32_16x16x32_bf16(a1, bf[nr][1], c, 0, 0, 0);
                c = __builtin_amdgcn_mfma_f32_16x16x32_bf16(a2, bf[nr][0], c, 0, 0, 0);
                acc[mr][nr] = c;
            }
        }
        __syncthreads();
    }
    #pragma unroll
    for (int mr = 0; mr < MR; ++mr) {
        #pragma unroll
        for (int r = 0; r < 4; ++r) {
            int gr = row0 + wrow + mr * 16 + koff * 4 + r;
            if (gr >= M) continue;
            #pragma unroll
            for (int nr = 0; nr < NR; ++nr) {
                int gc = col0 + wcol + nr * 16 + l16;
                float v = alpha * acc[mr][nr][r];
                if (Cin) v += beta * Cin[cb + (long)gr * ldc + gc];
                if (add_id && gr == gc) v += 1.f;
                Out[ob + (long)gr * ldo + gc] = v;
            }
        }
    }
}

static void fallback_launch(void* const* d_in, void* d_out, void* d_ws,
                            hipStream_t stream)
{
    const float* y0 = (const float*)d_in[1];
    const float* u  = (const float*)d_in[2];
    const float* Am = (const float*)d_in[3];
    const float* Bm = (const float*)d_in[4];
    float* Yout = (float*)d_out;
    float* w = (float*)d_ws;
    const float h = 0.01f;
    const int N = GN;

    float* Eyy = w;
    float* T1  = Eyy + (long)N * N;
    float* T2  = T1  + (long)N * N;
    float* V1  = T2  + (long)N * N;
    float* Vt  = V1  + (long)N * GM;
    float* V2  = Vt  + (long)N * GM;
    float* G1  = V2  + (long)N * GM;
    float* G2  = G1  + (long)N * GM;
    float* Z   = G2  + (long)N * GM;
    float* Zt  = Z   + (long)CCH * N;
    dim3 blk(256);

    auto gemm = [&](bool transb, const float* A, long ab, long lda,
                    const float* B, const float* Cin, long cb, long ldc, float beta,
                    float* Out, long ob, long ldo,
                    int M, int Nn, int K, float alpha, int add_id) {
        if (M > 1536 && (Nn % 128) == 0) {
            dim3 grid((M + 127) / 128, Nn / 128);
            if (transb)
                gemm_mfma<128, 128, true><<<grid, blk, 0, stream>>>(A, ab, lda, B, Cin, cb, ldc, beta, Out, ob, ldo, M, Nn, K, alpha, add_id);
            else
                gemm_mfma<128, 128, false><<<grid, blk, 0, stream>>>(A, ab, lda, B, Cin, cb, ldc, beta, Out, ob, ldo, M, Nn, K, alpha, add_id);
        } else {
            dim3 grid((M + 63) / 64, Nn / 64);
            if (transb)
                gemm_mfma<64, 64, true><<<grid, blk, 0, stream>>>(A, ab, lda, B, Cin, cb, ldc, beta, Out, ob, ldo, M, Nn, K, alpha, add_id);
            else
                gemm_mfma<64, 64, false><<<grid, blk, 0, stream>>>(A, ab, lda, B, Cin, cb, ldc, beta, Out, ob, ldo, M, Nn, K, alpha, add_id);
        }
    };

    scale_add_id_k<<<dim3(4, N), blk, 0, stream>>>(T1, Am, h / 5.f, N);
    {
        float* pc = T1; float* pn = T2;
        for (int k = 4; k >= 1; --k) {
            float* out = (k == 1) ? Eyy : pn;
            gemm(false, Am, 0, N, pc, nullptr, 0, 0, 0.f, out, 0, N, N, N, N, h / (float)k, 1);
            pn = pc; pc = out;
        }
    }
    const long NM = (long)N * GM;
    scale_copy_k<<<dim3((unsigned)((NM + 255) / 256)), blk, 0, stream>>>(V1, Bm, 1.f / 120.f, NM);
    {
        const float f1[4] = {1.f / 24.f, 1.f / 6.f, 0.5f, 1.f};
        float* pc = V1; float* pn = Vt;
        for (int j = 3; j >= 0; --j) {
            gemm(false, Am, 0, N, pc, Bm, 0, GM, f1[3 - j], pn, 0, GM, N, GM, N, h, 0);
            float* t = pc; pc = pn; pn = t;
        }
    }
    scale_copy_k<<<dim3((unsigned)((NM + 255) / 256)), blk, 0, stream>>>(V2, Bm, 1.f / 720.f, NM);
    {
        const float f2[4] = {1.f / 120.f, 1.f / 24.f, 1.f / 6.f, 0.5f};
        float* pc = V2; float* pn = Vt;
        for (int j = 3; j >= 0; --j) {
            gemm(false, Am, 0, N, pc, Bm, 0, GM, f2[3 - j], pn, 0, GM, N, GM, N, h, 0);
            float* t = pc; pc = pn; pn = t;
        }
    }
    g1g2_k<<<dim3((unsigned)((NM + 255) / 256)), blk, 0, stream>>>(G1, G2, V1, V2, h, NM);
    gemm(true, u, 0, GM, G1, nullptr, 0, 0, 0.f, Yout, (long)N, N, GT - 1, N, GM, 1.f, 0);
    gemm(true, u, GM, GM, G2, Yout, (long)N, N, 1.f, Yout, (long)N, N, GT - 1, N, GM, 1.f, 0);
    copy_rows_k<<<dim3(4, 1), blk, 0, stream>>>(Yout, 0, 0, y0, 0, 0, N);
    for (int s = 2; s <= SCH; ++s) {
        int Mr = (GT - 1 - s) / SCH + 1;
        gemm(true, Yout, (long)(s - 1) * N, (long)SCH * N, Eyy,
             Yout, (long)s * N, (long)SCH * N, 1.f,
             Yout, (long)s * N, (long)SCH * N, Mr, N, N, 1.f, 0);
    }
    copy_rows_k<<<dim3(4, 1), blk, 0, stream>>>(Z, 0, 0, y0, 0, 0, N);
    copy_rows_k<<<dim3(4, CCH - 1), blk, 0, stream>>>(Z, (long)N, (long)N,
                                                      Yout, (long)SCH * N, (long)SCH * N, N);
    gemm(false, Eyy, 0, N, Eyy, nullptr, 0, 0, 0.f, T1, 0, N, N, N, N, 1.f, 0);
    gemm(false, T1, 0, N, T1, nullptr, 0, 0, 0.f, T2, 0, N, N, N, N, 1.f, 0);
    gemm(false, T2, 0, N, T2, nullptr, 0, 0, 0.f, T1, 0, N, N, N, N, 1.f, 0);
    {
        float* Mc = T1; float* Mo = T2;
        float* Zc = Z;  float* Zn = Zt;
        for (int p = 0; p < 10; ++p) {
            int o = 1 << p;
            gemm(true, Zc, 0, N, Mc, Zc, (long)o * N, N, 1.f,
                 Zn, (long)o * N, N, CCH - o, N, N, 1.f, 0);
            copy_rows_k<<<dim3(4, o), blk, 0, stream>>>(Zn, 0, N, Zc, 0, N, N);
            if (p < 9) {
                gemm(false, Mc, 0, N, Mc, nullptr, 0, 0, 0.f, Mo, 0, N, N, N, N, 1.f, 0);
                float* t = Mc; Mc = Mo; Mo = t;
            }
            float* t = Zc; Zc = Zn; Zn = t;
        }
        copy_rows_k<<<dim3(4, CCH), blk, 0, stream>>>(Yout, 0, (long)SCH * N, Zc, 0, N, N);
        float* Q = Zc; float* Qt = Zn;
        for (int s = 1; s <= SCH - 1; ++s) {
            gemm(true, Q, 0, N, Eyy, nullptr, 0, 0, 0.f, Qt, 0, N, CCH, N, N, 1.f, 0);
            int Mr = (GT - 1 - s) / SCH + 1;
            add_rows_k<<<dim3(4, Mr), blk, 0, stream>>>(Yout, (long)s * N, (long)SCH * N, Qt, N);
            float* t = Q; Q = Qt; Qt = t;
        }
    }
}

// ---------------------------------------------------------------------------
extern "C" void kernel_launch(void* const* d_in, const int* in_sizes, int n_in,
                              void* d_out, int out_size, void* d_ws, size_t ws_size,
                              hipStream_t stream)
{
    (void)in_sizes; (void)n_in; (void)out_size;
    const size_t NEED = 46ull * 1024 * 1024;
    if (ws_size < NEED) { fallback_launch(d_in, d_out, d_ws, stream); return; }

    const float* y0 = (const float*)d_in[1];
    const float* u  = (const float*)d_in[2];
    const float* Am = (const float*)d_in[3];
    const float* Bm = (const float*)d_in[4];
    float* Yout = (float*)d_out;
    char* w = (char*)d_ws;
    const float h = 0.01f;
    const size_t MB = 1024 * 1024;
    const long P1M = 1 << 20;
    const long P2M = 1 << 21;
    const long PUS = 1 << 22;
    const long PBS = 1 << 19;
    const int  BIG = 1 << 30;

    // ws layout (46 MB, time-phased):
    unsigned short* PU   = (unsigned short*)(w);            // [0,16) c-staging
    unsigned short* PZW1 = (unsigned short*)(w);            // [0,8) after PU dead
    unsigned short* PZW2 = (unsigned short*)(w + 8 * MB);   // [8,16)
    unsigned short* CH1  = (unsigned short*)(w + 16 * MB);  // [16,24) chain ping
    unsigned short* SQb  = (unsigned short*)(w + 16 * MB);  // [16,20) after CH1 dead
    unsigned short* PWb  = (unsigned short*)(w + 20 * MB);  // [20,24)
    unsigned short* CH2  = (unsigned short*)(w + 24 * MB);  // [24,32) chain pong
    unsigned short* PY1  = (unsigned short*)(w + 24 * MB);  // [24,28)
    unsigned short* PY2  = (unsigned short*)(w + 28 * MB);  // [28,32)
    unsigned short* PE   = (unsigned short*)(w + 32 * MB);  // [32,36) planes(E)
    unsigned short* PG   = (unsigned short*)(w + 36 * MB);  // [36,40) -> SQa
    unsigned short* SQa  = PG;
    unsigned short* PA   = (unsigned short*)(w + 40 * MB);  // [40,44) -> PWa
    unsigned short* PWa  = PA;
    unsigned short* PBT  = (unsigned short*)(w + 44 * MB);  // [44,46)

    dim3 blk(256), blk5(512);

    // G64: square-GEMM config (BM=64, 2x2 quads, K-split)
    auto G64 = [&](const unsigned short* Ap, long apsz, int alda, int aldsh,
                   int ashift, int ashiftN,
                   const unsigned short* Bp,
                   const float* Cf, long cfb, long cfld,
                   const unsigned short* Cp, long cpsz, int cmask,
                   int bzero, int bsplit, float beta, float betaB,
                   float* Of, long ofb, long ofld,
                   unsigned short* Pout, long ppsz, int pstep8, int pmode,
                   int segN, int zoff, int M, float alpha, float alphaB,
                   int asplit, int add_id,
                   const unsigned short* Ap2, long apsz2, const unsigned short* Bp2,
                   unsigned short* Pout2, long ppsz2, int p2off, int seg2,
                   unsigned short* PoutT, int tposeN) {
        dim3 grid((M + 63) / 64, 16);
        gemm_pp<64, 2, 2><<<grid, blk5, 0, stream>>>(
            Ap, apsz, alda, aldsh, ashift, ashiftN, Bp, P1M,
            Cf, cfb, cfld, Cp, cpsz, cmask, bzero, bsplit, beta, betaB,
            Of, ofb, ofld, Pout, ppsz, pstep8, pmode, segN, zoff,
            M, alpha, alphaB, asplit, add_id,
            Ap2, apsz2, Bp2, Pout2, ppsz2, p2off, seg2, PoutT, tposeN);
    };

    // ---- 1. planes(Am) ----
    split_pl_k<<<dim3(4096), blk, 0, stream>>>(Am, PA, P1M, 10, 1.f, (long)1 << 20);

    // ---- 2. seeds: CH1 = [I+(h/5)A^T ; B^T/120 ; B^T/720], PBT = B^T ----
    trsp_k<<<dim3(32, 32), blk, 0, stream>>>(Am, 1024, h / 5.f, 1, CH1, P2M, 0);
    trsp_k<<<dim3(16, 32), blk, 0, stream>>>(Bm, 512, 1.f / 120.f, 0, CH1, P2M, 1024);
    trsp_k<<<dim3(16, 32), blk, 0, stream>>>(Bm, 512, 1.f / 720.f, 0, CH1, P2M, 1536);
    trsp_k<<<dim3(16, 32), blk, 0, stream>>>(Bm, 512, 1.f, 0, PBT, PBS, 0);

    // ---- 3. fused chain x4: expm Horner (rows<1024) + phi chains (rows 1024+) ----
    {
        const float alE[4] = {h / 4.f, h / 3.f, h / 2.f, h};
        const float f1[4] = {1.f / 24.f, 1.f / 6.f, 0.5f, 1.f};
        const float f2[4] = {1.f / 120.f, 1.f / 24.f, 1.f / 6.f, 0.5f};
        unsigned short* cc = CH1; unsigned short* cn = CH2;
        for (int j = 0; j < 4; ++j) {
            G64(cc, P2M, 1024, 10, 0, 0, PA,
                nullptr, 0, 0, PBT, PBS, 511,
                1024, 1536, f1[j], f2[j],
                nullptr, 0, 0, cn, P2M, 0, 1,
                BIG, 0, 2048, alE[j], h, 1024, 1,
                nullptr, 0, nullptr, nullptr, 0, 0, BIG, nullptr, BIG);
            unsigned short* t = cc; cc = cn; cn = t;
        }  // final in CH1
    }
    tspp_k<<<dim3(32, 32), blk, 0, stream>>>(CH1, P2M, 0, PE, P1M);
    gtspp_k<<<dim3(16, 32, 2), blk, 0, stream>>>(CH1 + (1 << 20), P2M, PG, P1M, h);

    // ---- 4. planes(u) ----
    split_pl_k<<<dim3(16384), blk, 0, stream>>>(u, PU, PUS, 9, 1.f, PUS);

    // ---- 5. c-staging: Yout[t] = [u_{t-1}|u_t]@Gcat^T (+planes of rows 8i+1) ----
    gemm_pp<128, 4, 1><<<dim3(64, 8), blk5, 0, stream>>>(
        PU, PUS, 512, 9, 0, 0, PG, P1M,
        nullptr, 0, 0, nullptr, 0, -1, 0, BIG, 0.f, 0.f,
        Yout, 1024, 1024, PY1, P1M, 1, 1,
        BIG, 0, GT - 1, 1.f, 1.f, BIG, 0,
        nullptr, 0, nullptr, nullptr, 0, 0, BIG, nullptr, BIG);
    copy_rows_k<<<dim3(4, 1), blk, 0, stream>>>(Yout, 0, 0, y0, 0, 0, 1024);

    // ---- 6. phase 1 fused with E-squarings (dual blocks at rows 1024+) ----
    // F1: s=2 | E^2T = E^T@planes(E) -> SQa (direct) + planes(E^2) -> PWa (tposed)
    G64(PY1, P1M, 1024, 10, 0, 0, PE,
        Yout, 2 * 1024, 8192, nullptr, 0, -1, 0, BIG, 1.f, 0.f,
        Yout, 2 * 1024, 8192, PY2, P1M, 0, 1,
        BIG, 0, 2048, 1.f, 1.f, BIG, 0,
        CH1, P2M, PE, SQa, P1M, 0, 1024, PWa, 1024);
    // F2: s=3 | E^4T = E^2T@planes(E^2) -> SQb + planes(E^4) -> PWb
    G64(PY2, P1M, 1024, 10, 0, 0, PE,
        Yout, 3 * 1024, 8192, nullptr, 0, -1, 0, BIG, 1.f, 0.f,
        Yout, 3 * 1024, 8192, PY1, P1M, 0, 1,
        BIG, 0, 2048, 1.f, 1.f, BIG, 0,
        SQa, P1M, PWa, SQb, P1M, 0, 1024, PWb, 1024);
    // F3: s=4 | E^8T -> PZW1 rows 1024+ + planes(E^8) -> PWa
    G64(PY1, P1M, 1024, 10, 0, 0, PE,
        Yout, 4 * 1024, 8192, nullptr, 0, -1, 0, BIG, 1.f, 0.f,
        Yout, 4 * 1024, 8192, PY2, P1M, 0, 1,
        BIG, 0, 2048, 1.f, 1.f, BIG, 0,
        SQb, P1M, PWb, PZW1, P2M, 1024, 1024, PWa, 1024);
    // s = 5..7 solo
    {
        unsigned short* pc = PY2; unsigned short* pn = PY1;
        for (int s = 5; s <= 7; ++s) {
            G64(pc, P1M, 1024, 10, 0, 0, PE,
                Yout, (long)s * 1024, 8192, nullptr, 0, -1, 0, BIG, 1.f, 0.f,
                Yout, (long)s * 1024, 8192, pn, P1M, 0, 1,
                BIG, 0, 1024, 1.f, 1.f, BIG, 0,
                nullptr, 0, nullptr, nullptr, 0, 0, BIG, nullptr, BIG);
            unsigned short* t = pc; pc = pn; pn = t;
        }
        // s=8 -> boundary rows 8(i+1): plane rows 1..1023 (zoff=1), pc==PY1
        G64(pc, P1M, 1024, 10, 0, 0, PE,
            Yout, 0, 8192, nullptr, 0, -1, 0, BIG, 1.f, 0.f,
            Yout, 0, 8192, PZW1, P2M, 0, 1,
            BIG, 1, 1023, 1.f, 1.f, BIG, 0,
            nullptr, 0, nullptr, nullptr, 0, 0, BIG, nullptr, BIG);
    }
    // z_0 = y0 -> PZW1 plane row 0
    split_pl_k<<<dim3(4), blk, 0, stream>>>(y0, PZW1, P2M, 10, 1.f, 1024);

    // ---- 7. fused doubling: one GEMM per round, transpose in epilogue ----
    // rows<1024 (Z): Zn[i] = Zc[i] + Zc[i-o]@W^T (aa=0 rows<o -> passthrough)
    // rows 1024+ (W): Wnext^T = W^T@W^T -> PZn planes + planes(Wnext) -> PWnext
    {
        unsigned short* PZc = PZW1; unsigned short* PZn = PZW2;
        for (int p = 0; p < 10; ++p) {
            int o = 1 << p;
            unsigned short* PWcur = (p & 1) ? PWb : PWa;
            unsigned short* PWnxt = (p & 1) ? PWa : PWb;
            if (p < 9) {
                G64(PZc, P2M, 1024, 10, o, 1024, PWcur,
                    nullptr, 0, 0, PZc, P2M, 0x7fffffff,
                    0, 1024, 1.f, 0.f,
                    nullptr, 0, 0, PZn, P2M, 0, 1,
                    1024, 0, 2048, 0.f, 1.f, o, 0,
                    nullptr, 0, nullptr, nullptr, 0, 0, BIG, PWnxt, 1024);
            } else {   // final round: Z only; write Yout[8i] directly
                G64(PZc, P2M, 1024, 10, o, 1024, PWcur,
                    nullptr, 0, 0, PZc, P2M, 0x7fffffff,
                    0, 1024, 1.f, 0.f,
                    Yout, 0, 8192, PZn, P2M, 0, 1,
                    1024, 0, 1024, 0.f, 1.f, o, 0,
                    nullptr, 0, nullptr, nullptr, 0, 0, BIG, nullptr, BIG);
            }
            unsigned short* t = PZc; PZc = PZn; PZn = t;
        }  // final Z planes in PZW1 (10 swaps)
    }
    copy_rows_k<<<dim3(4, 1), blk, 0, stream>>>(Yout, 0, 0, y0, 0, 0, 1024);

    // ---- 8. phase 3: y_{8i+s} += E^s z_i, s=1..7 ----
    {
        const unsigned short* pc = PZW1; long apsz = P2M;
        unsigned short* pn = PY1;
        for (int s = 1; s <= 7; ++s) {
            G64(pc, apsz, 1024, 10, 0, 0, PE,
                Yout, (long)s * 1024, 8192, nullptr, 0, -1, 0, BIG, 1.f, 0.f,
                Yout, (long)s * 1024, 8192,
                (s < 7) ? pn : nullptr, P1M, 0, 2,
                BIG, 0, 1024, 1.f, 1.f, BIG, 0,
                nullptr, 0, nullptr, nullptr, 0, 0, BIG, nullptr, BIG);
            pc = pn; apsz = P1M;
            pn = (pn == PY1) ? PY2 : PY1;
        }
    }
}

// Round 10
// 757.983 us; speedup vs baseline: 2.0330x; 1.0666x over previous
//
#include <hip/hip_runtime.h>

// Problem constants (fixed in the reference file)
#define GT 8192      // time steps
#define GN 1024      // state dim
#define GM 512       // input dim
#define CCH 1024     // scan chunks
#define SCH 8        // steps per chunk

typedef __attribute__((ext_vector_type(8))) short bf16x8;
typedef __attribute__((ext_vector_type(4))) float f32x4;

__device__ __forceinline__ unsigned short f2bf(float x) {   // RNE fp32->bf16
    unsigned int u = __float_as_uint(x);
    u += 0x7FFF + ((u >> 16) & 1);
    return (unsigned short)(u >> 16);
}
__device__ __forceinline__ float bf2f(unsigned short b) {
    return __uint_as_float(((unsigned int)b) << 16);
}
__device__ __forceinline__ void split2(float x, unsigned short& h0, unsigned short& h1) {
    h0 = f2bf(x);
    h1 = f2bf(x - bf2f(h0));
}
__device__ __forceinline__ void split3(float x, unsigned short& s0,
                                       unsigned short& s1, unsigned short& s2) {
    s0 = f2bf(x); float r = x - bf2f(s0);
    s1 = f2bf(r); r -= bf2f(s1);
    s2 = f2bf(r);
}
// storage swizzle: XOR element bits 3-4 with (row>>1)&3 (row = e>>sh). Involution.
__device__ __forceinline__ long swz(long e, int sh) {
    return e ^ (((e >> (sh + 1)) & 3) << 3);
}
// async 16B global->LDS (dest wave-uniform base; HW scatters lane*16; src per-lane)
__device__ __forceinline__ void gl16(const unsigned short* g, unsigned short* l) {
    __builtin_amdgcn_global_load_lds(
        (const __attribute__((address_space(1))) unsigned int*)g,
        (__attribute__((address_space(3))) unsigned int*)l, 16, 0, 0);
}

// ---------------------------------------------------------------------------
// Plane x plane GEMM; 512 threads = 8 waves = (2 x WN quads) x KS k-groups.
// KS=2: waves 0-3 / 4-7 split the 64-k step; f32 LDS reduce at end.
// Out = aa * A @ B^T (+ bb*Cin) (+I), K=1024, N=1024, 2-limb bf16 planes,
// 3 limb products. A element (r,k) at swz(r*alda+k, aldsh), limb1 +apsz.
// A row: ar = (row0+lr)&amask, then if ar<ashiftN: ar = max(ar-ashift,0).
// B base += (row0>>10)*bstride (power-table select); limb1 at +bpsz.
// trow = (((gr<segN)? gr+zoff : gr)) & trmask.
// aa = trow<asplit? alpha:alphaB; bb = trow<bzero? 0 : (trow<bsplit? beta:betaB).
// Of addr = ofb + (row0>>10)*ofstep + trow*ofld; Cin likewise (shared ofstep).
// Pout row = (pstep8? trow>>3 : trow) + (row0>>10)*prowstep; pmode 1=v, 2=aa*acc.
// DUAL (Ap2 set): blocks row0>=seg2 compute Ap2@Bp2^T pure (A row gr-seg2),
//   planes -> Pout2 (nullable) row gr-seg2+p2off (stride ppsz2).
// TRANSPOSE (PoutT set, BM==64): blocks row0>=tposeN also emit transposed tile
//   planes to PoutT (limb stride 1M): PoutT[col0+i][row0-tposeN+j].
// ---------------------------------------------------------------------------
template <int BM, int WN, int KS>
__global__ __launch_bounds__(512) void gemm_pp(
    const unsigned short* __restrict__ Ap, long apsz, int alda, int aldsh,
    int amask, int ashift, int ashiftN,
    const unsigned short* __restrict__ Bp, long bpsz, long bstride,
    const float* __restrict__ Cf, long cfb, long cfld,
    const unsigned short* __restrict__ Cp, long cpsz, int cmask,
    int bzero, int bsplit, float beta, float betaB,
    float* __restrict__ Of, long ofb, long ofld, long ofstep,
    unsigned short* __restrict__ Pout, long ppsz, int pstep8, int pmode, int prowstep,
    int segN, int zoff, int trmask,
    int M, float alpha, float alphaB, int asplit, int add_id,
    const unsigned short* __restrict__ Ap2, long apsz2,
    const unsigned short* __restrict__ Bp2,
    unsigned short* __restrict__ Pout2, long ppsz2, int p2off, int seg2,
    unsigned short* __restrict__ PoutT, int tposeN)
{
    constexpr int NQ = 2 * WN;             // output quads
    constexpr int MTM = BM / 32;           // 16-tiles in M per wave
    constexpr int MTN = BM / (WN * 16);    // 16-tiles in N per wave
    constexpr int CPW = KS * BM / 32;      // staging chunks per wave
    __shared__ __align__(16) unsigned short At[2][KS][2][BM][32];
    __shared__ __align__(16) unsigned short Bt[2][KS][2][BM][32];

    const int tid = threadIdx.x;
    const int lane = tid & 63;
    const int w = tid >> 6;
    const int ksub = w / NQ;
    const int quad = w % NQ;
    const int wr = (quad / WN) * (BM / 2);
    const int wc = (quad % WN) * (BM / WN);
    const int l16 = lane & 15, koff = lane >> 4;
    const int row0 = blockIdx.x * BM;
    const int col0 = blockIdx.y * BM;
    const int lr4 = lane >> 2;
    const int lg = lane & 3;
    const bool s2 = (Ap2 != nullptr) && (row0 >= seg2);
    const bool lead = (KS == 1) || (ksub == 0);
    const int segk = row0 >> 10;

    f32x4 acc[MTM][MTN] = {};

    auto stage = [&](int bsel, int k0) {
        #pragma unroll
        for (int ci = 0; ci < CPW; ++ci) {
            const int c = w * CPW + ci;
            const int op = c / (KS * BM / 8);
            const int rem = c % (KS * BM / 8);
            const int limb = rem / (KS * BM / 16);
            const int rem2 = rem % (KS * BM / 16);
            const int kk = rem2 / (BM / 16);
            const int rb = (rem2 % (BM / 16)) * 16;
            const int lr = rb + lr4;
            const int q = lg ^ ((lr >> 1) & 3);
            long e; int sh; const unsigned short* base;
            if (op == 0) {
                if (!s2) {
                    int ar = (row0 + lr) & amask;
                    if (ar < ashiftN) { ar -= ashift; if (ar < 0) ar = 0; }
                    e = (long)ar * alda + k0 + kk * 32 + (q << 3); sh = aldsh;
                    base = Ap + (limb ? apsz : 0);
                } else {
                    e = (long)(row0 - seg2 + lr) * 1024 + k0 + kk * 32 + (q << 3); sh = 10;
                    base = Ap2 + (limb ? apsz2 : 0);
                }
            } else {
                e = (long)(col0 + lr) * 1024 + k0 + kk * 32 + (q << 3); sh = 10;
                base = (s2 ? Bp2 : (Bp + (long)segk * bstride)) + (limb ? bpsz : 0);
            }
            long f = swz(e, sh);
            unsigned short* l = (op == 0 ? &At[bsel][kk][limb][rb][0]
                                         : &Bt[bsel][kk][limb][rb][0]);
            gl16(base + f, l);
        }
    };

    stage(0, 0);
    __syncthreads();
    int cur = 0;
    for (int k0 = 0; k0 < 1024; k0 += KS * 32) {
        if (k0 + KS * 32 < 1024) stage(cur ^ 1, k0 + KS * 32);

        const int kk = ksub;
        bf16x8 a0[MTM], a1[MTM], b0[MTN], b1[MTN];
        #pragma unroll
        for (int mi = 0; mi < MTM; ++mi) {
            int lr = wr + mi * 16 + l16;
            int off = (koff ^ ((lr >> 1) & 3)) << 3;
            a0[mi] = *(const bf16x8*)&At[cur][kk][0][lr][off];
            a1[mi] = *(const bf16x8*)&At[cur][kk][1][lr][off];
        }
        #pragma unroll
        for (int ni = 0; ni < MTN; ++ni) {
            int lr = wc + ni * 16 + l16;
            int off = (koff ^ ((lr >> 1) & 3)) << 3;
            b0[ni] = *(const bf16x8*)&Bt[cur][kk][0][lr][off];
            b1[ni] = *(const bf16x8*)&Bt[cur][kk][1][lr][off];
        }
        #pragma unroll
        for (int mi = 0; mi < MTM; ++mi)
            #pragma unroll
            for (int ni = 0; ni < MTN; ++ni) {
                f32x4 cc = acc[mi][ni];
                cc = __builtin_amdgcn_mfma_f32_16x16x32_bf16(a0[mi], b0[ni], cc, 0, 0, 0);
                cc = __builtin_amdgcn_mfma_f32_16x16x32_bf16(a0[mi], b1[ni], cc, 0, 0, 0);
                cc = __builtin_amdgcn_mfma_f32_16x16x32_bf16(a1[mi], b0[ni], cc, 0, 0, 0);
                acc[mi][ni] = cc;
            }
        __syncthreads();
        cur ^= 1;
    }

    if (KS == 2) {   // cross-ksub reduce (alias At as f32 scratch)
        float* red = (float*)&At[0][0][0][0][0];
        if (ksub == 1) {
            #pragma unroll
            for (int mi = 0; mi < MTM; ++mi)
                #pragma unroll
                for (int ni = 0; ni < MTN; ++ni)
                    *(f32x4*)&red[(((quad * MTM + mi) * MTN + ni) * 64 + lane) * 4] =
                        acc[mi][ni];
        }
        __syncthreads();
        if (ksub == 0) {
            #pragma unroll
            for (int mi = 0; mi < MTM; ++mi)
                #pragma unroll
                for (int ni = 0; ni < MTN; ++ni) {
                    f32x4 o = *(const f32x4*)
                        &red[(((quad * MTM + mi) * MTN + ni) * 64 + lane) * 4];
                    acc[mi][ni][0] += o[0]; acc[mi][ni][1] += o[1];
                    acc[mi][ni][2] += o[2]; acc[mi][ni][3] += o[3];
                }
        }
    }

    const bool tp = (PoutT != nullptr) && (row0 >= tposeN);
    float* T = (float*)&Bt[0][0][0][0][0];   // 64x65 f32, Bt dead

    if (s2) {                               // dual: pure product (+planes/T)
        if (lead) {
            #pragma unroll
            for (int mi = 0; mi < MTM; ++mi)
                #pragma unroll
                for (int r = 0; r < 4; ++r) {
                    const int gr = row0 + wr + mi * 16 + koff * 4 + r;
                    if (gr >= M) continue;
                    const int prow = gr - seg2 + p2off;
                    #pragma unroll
                    for (int ni = 0; ni < MTN; ++ni) {
                        const int gc = col0 + wc + ni * 16 + l16;
                        float pv = acc[mi][ni][r];
                        if (Pout2) {
                            long f = swz((long)prow * 1024 + gc, 10);
                            unsigned short h0 = f2bf(pv);
                            Pout2[f] = h0;
                            Pout2[ppsz2 + f] = f2bf(pv - bf2f(h0));
                        }
                        if (tp) T[(wr + mi * 16 + koff * 4 + r) * 65 + gc - col0] = pv;
                    }
                }
        }
    } else {
        if (lead) {
            const long ofe = ofb + (long)segk * ofstep;
            const long cfe = cfb + (long)segk * ofstep;
            #pragma unroll
            for (int mi = 0; mi < MTM; ++mi) {
                #pragma unroll
                for (int r = 0; r < 4; ++r) {
                    const int gr = row0 + wr + mi * 16 + koff * 4 + r;
                    if (gr >= M) continue;
                    const int trow = (((gr < segN) ? gr + zoff : gr)) & trmask;
                    if (gr < segN && trow >= segN) continue;
                    const float aa = (trow < asplit) ? alpha : alphaB;
                    const float bb = (trow < bzero) ? 0.f
                                    : ((trow < bsplit) ? beta : betaB);
                    #pragma unroll
                    for (int ni = 0; ni < MTN; ++ni) {
                        const int gc = col0 + wc + ni * 16 + l16;
                        float vp = aa * acc[mi][ni][r];
                        float v = vp;
                        if (bb != 0.f) {
                            int crow = trow & cmask;
                            if (Cf) v += bb * Cf[cfe + (long)crow * cfld + gc];
                            else if (Cp) {
                                long f = swz((long)crow * 1024 + gc, 10);
                                v += bb * (bf2f(Cp[f]) + bf2f(Cp[cpsz + f]));
                            }
                        }
                        if (add_id && gr == gc) v += 1.f;
                        if (Of) Of[ofe + (long)trow * ofld + gc] = v;
                        if (Pout && (!pstep8 || (trow & 7) == 0)) {
                            int prow = (pstep8 ? (trow >> 3) : trow) + segk * prowstep;
                            long f = swz((long)prow * 1024 + gc, 10);
                            float pv = (pmode == 2) ? vp : v;
                            unsigned short h0 = f2bf(pv);
                            Pout[f] = h0;
                            Pout[ppsz + f] = f2bf(pv - bf2f(h0));
                        }
                        if (tp) T[(wr + mi * 16 + koff * 4 + r) * 65 + gc - col0] = v;
                    }
                }
            }
        }
    }

    if (BM == 64 && tp) {                   // transposed plane emission
        __syncthreads();
        if (tid < 256) {
            const int i = tid >> 2;
            const int jb = (tid & 3) * 16;
            const int prow = col0 + i;
            #pragma unroll
            for (int e2 = 0; e2 < 16; ++e2) {
                int j = jb + e2;
                float v = T[j * 65 + i];
                long f = swz((long)prow * 1024 + (row0 - tposeN + j), 10);
                unsigned short h0 = f2bf(v);
                PoutT[f] = h0;
                PoutT[(long)(1 << 20) + f] = f2bf(v - bf2f(h0));
            }
        }
    }
}

// ---- X (cnt fp32, rows of length 2^ldsh) -> swizzled 2-limb planes ----
__global__ void split_pl_k(const float* __restrict__ X, unsigned short* __restrict__ P,
                           long psz, int ldsh, float s, long cnt)
{
    long i = (long)blockIdx.x * 256 + threadIdx.x;
    if (i >= cnt) return;
    float v = s * X[i];
    long f = swz(i, ldsh);
    unsigned short h0 = f2bf(v);
    P[f] = h0;
    P[psz + f] = f2bf(v - bf2f(h0));
}

// ---- planes of s*in^T (+I): out rows (roff+)0..R-1, in is 1024 x R fp32 ----
__global__ void trsp_k(const float* __restrict__ in, int R, float s, int add_id,
                       unsigned short* __restrict__ P, long psz, int roff)
{
    __shared__ float t[32][33];
    const int tx = threadIdx.x & 31, ty4 = threadIdx.x >> 5;
    const int r0 = blockIdx.x * 32, c0 = blockIdx.y * 32;
    #pragma unroll
    for (int i = 0; i < 4; ++i)
        t[ty4 * 4 + i][tx] = in[(long)(c0 + ty4 * 4 + i) * R + r0 + tx];
    __syncthreads();
    #pragma unroll
    for (int i = 0; i < 4; ++i) {
        int r = r0 + ty4 * 4 + i, c = c0 + tx;
        float v = s * t[tx][ty4 * 4 + i];
        if (add_id && r == c) v += 1.f;
        long f = swz((long)(r + roff) * 1024 + c, 10);
        unsigned short h0 = f2bf(v);
        P[f] = h0;
        P[psz + f] = f2bf(v - bf2f(h0));
    }
}

// ---- planes(X) from planes(X^T): OUT[c][r] = IN[irow0+r][c] ----
__global__ void tspp_k(const unsigned short* __restrict__ IN, long ipsz, long irow0,
                       unsigned short* __restrict__ OUT, long opsz)
{
    __shared__ float t[32][33];
    const int tx = threadIdx.x & 31, ty4 = threadIdx.x >> 5;
    const int r0 = blockIdx.x * 32, c0 = blockIdx.y * 32;
    #pragma unroll
    for (int i = 0; i < 4; ++i) {
        long f = swz((irow0 + r0 + ty4 * 4 + i) * 1024 + c0 + tx, 10);
        t[ty4 * 4 + i][tx] = bf2f(IN[f]) + bf2f(IN[ipsz + f]);
    }
    __syncthreads();
    #pragma unroll
    for (int i = 0; i < 4; ++i) {
        int orow = c0 + ty4 * 4 + i;
        long f = swz((long)orow * 1024 + r0 + tx, 10);
        float v = t[tx][ty4 * 4 + i];
        unsigned short h0 = f2bf(v);
        OUT[f] = h0;
        OUT[opsz + f] = f2bf(v - bf2f(h0));
    }
}

// ---- Gcat planes from stacked [V1^T; V2^T] planes ----
__global__ void gtspp_k(const unsigned short* __restrict__ PV, long vpsz,
                        unsigned short* __restrict__ PG, long gpsz, float h)
{
    __shared__ float t[32][33];
    const int tx = threadIdx.x & 31, ty4 = threadIdx.x >> 5;
    const int k0 = blockIdx.x * 32, n0 = blockIdx.y * 32, z = blockIdx.z;
    #pragma unroll
    for (int i = 0; i < 4; ++i) {
        int k = k0 + ty4 * 4 + i, n = n0 + tx;
        long f2 = swz((long)(512 + k) * 1024 + n, 10);
        float v2 = bf2f(PV[f2]) + bf2f(PV[vpsz + f2]);
        float v;
        if (z == 0) {
            long f1 = swz((long)k * 1024 + n, 10);
            v = h * (bf2f(PV[f1]) + bf2f(PV[vpsz + f1]) - v2);
        } else v = h * v2;
        t[ty4 * 4 + i][tx] = v;
    }
    __syncthreads();
    #pragma unroll
    for (int i = 0; i < 4; ++i) {
        int n = n0 + ty4 * 4 + i, kk = z * 512 + k0 + tx;
        long f = swz((long)n * 1024 + kk, 10);
        float v = t[tx][ty4 * 4 + i];
        unsigned short h0 = f2bf(v);
        PG[f] = h0;
        PG[gpsz + f] = f2bf(v - bf2f(h0));
    }
}

// dst[db + r*ds + c] = src[sb + r*ss + c]
__global__ void copy_rows_k(float* __restrict__ dst, long db, long ds,
                            const float* __restrict__ src, long sb, long ss, int ncols)
{
    int r = blockIdx.y;
    int c = blockIdx.x * 256 + threadIdx.x;
    if (c < ncols) dst[db + (long)r * ds + c] = src[sb + (long)r * ss + c];
}

// dst[db + r*ds + c] += src[r*ncols + c]
__global__ void add_rows_k(float* __restrict__ dst, long db, long ds,
                           const float* __restrict__ src, int ncols)
{
    int r = blockIdx.y;
    int c = blockIdx.x * 256 + threadIdx.x;
    if (c < ncols) dst[db + (long)r * ds + c] += src[(long)r * ncols + c];
}

__global__ void scale_add_id_k(float* __restrict__ dst, const float* __restrict__ src,
                               float s, int n)
{
    int r = blockIdx.y;
    int c = blockIdx.x * 256 + threadIdx.x;
    if (c < n) dst[(long)r * n + c] = s * src[(long)r * n + c] + ((r == c) ? 1.f : 0.f);
}

__global__ void scale_copy_k(float* __restrict__ dst, const float* __restrict__ src,
                             float s, long cnt)
{
    long i = (long)blockIdx.x * 256 + threadIdx.x;
    if (i < cnt) dst[i] = s * src[i];
}

__global__ void g1g2_k(float* __restrict__ g1, float* __restrict__ g2,
                       const float* __restrict__ v1, const float* __restrict__ v2,
                       float h, long cnt)
{
    long i = (long)blockIdx.x * 256 + threadIdx.x;
    if (i < cnt) {
        float a = v1[i], b = v2[i];
        g1[i] = h * (a - b);
        g2[i] = h * b;
    }
}

// ---------------------------------------------------------------------------
// FALLBACK (round-3, 3-limb, 30 MB ws) — only if ws_size < 46 MB.
// ---------------------------------------------------------------------------
template <int BM, int BN, bool TRANSB>
__global__ __launch_bounds__(256) void gemm_mfma(
    const float* __restrict__ A, long ab, long lda,
    const float* __restrict__ B,
    const float* __restrict__ Cin, long cb, long ldc, float beta,
    float* __restrict__ Out, long ob, long ldo,
    int M, int Nn, int K, float alpha, int add_id)
{
    constexpr int LDT = 40;
    __shared__ unsigned short At[3][BM][LDT];
    __shared__ unsigned short Bt[3][BN][LDT];
    const int tid = threadIdx.x;
    const int lane = tid & 63;
    const int wid = tid >> 6;
    const int row0 = blockIdx.x * BM;
    const int col0 = blockIdx.y * BN;
    constexpr int MR = BM / 32;
    constexpr int NR = BN / 32;
    const int wrow = (wid >> 1) * (BM / 2);
    const int wcol = (wid & 1) * (BN / 2);
    const int l16 = lane & 15;
    const int koff = lane >> 4;
    f32x4 acc[MR][NR] = {};

    for (int k0 = 0; k0 < K; k0 += 32) {
        #pragma unroll
        for (int i = 0; i < BM / 32; ++i) {
            int r = i * 32 + (tid >> 3);
            int kl = (tid & 7) * 4;
            int gr = row0 + r;
            float4 v = make_float4(0.f, 0.f, 0.f, 0.f);
            if (gr < M) v = *(const float4*)&A[ab + (long)gr * lda + (k0 + kl)];
            unsigned short h0[4], h1[4], h2[4];
            split3(v.x, h0[0], h1[0], h2[0]);
            split3(v.y, h0[1], h1[1], h2[1]);
            split3(v.z, h0[2], h1[2], h2[2]);
            split3(v.w, h0[3], h1[3], h2[3]);
            *(ushort4*)&At[0][r][kl] = make_ushort4(h0[0], h0[1], h0[2], h0[3]);
            *(ushort4*)&At[1][r][kl] = make_ushort4(h1[0], h1[1], h1[2], h1[3]);
            *(ushort4*)&At[2][r][kl] = make_ushort4(h2[0], h2[1], h2[2], h2[3]);
        }
        if (TRANSB) {
            #pragma unroll
            for (int i = 0; i < BN / 32; ++i) {
                int r = i * 32 + (tid >> 3);
                int kl = (tid & 7) * 4;
                float4 v = *(const float4*)&B[(long)(col0 + r) * K + (k0 + kl)];
                unsigned short h0[4], h1[4], h2[4];
                split3(v.x, h0[0], h1[0], h2[0]);
                split3(v.y, h0[1], h1[1], h2[1]);
                split3(v.z, h0[2], h1[2], h2[2]);
                split3(v.w, h0[3], h1[3], h2[3]);
                *(ushort4*)&Bt[0][r][kl] = make_ushort4(h0[0], h0[1], h0[2], h0[3]);
                *(ushort4*)&Bt[1][r][kl] = make_ushort4(h1[0], h1[1], h1[2], h1[3]);
                *(ushort4*)&Bt[2][r][kl] = make_ushort4(h2[0], h2[1], h2[2], h2[3]);
            }
        } else {
            constexpr int TPK = BN / 4;
            #pragma unroll
            for (int i = 0; i < BN / 32; ++i) {
                int kl = i * (256 / TPK) + tid / TPK;
                int nl = (tid % TPK) * 4;
                float4 v = *(const float4*)&B[(long)(k0 + kl) * Nn + (col0 + nl)];
                unsigned short s0, s1, s2;
                split3(v.x, s0, s1, s2);
                Bt[0][nl + 0][kl] = s0; Bt[1][nl + 0][kl] = s1; Bt[2][nl + 0][kl] = s2;
                split3(v.y, s0, s1, s2);
                Bt[0][nl + 1][kl] = s0; Bt[1][nl + 1][kl] = s1; Bt[2][nl + 1][kl] = s2;
                split3(v.z, s0, s1, s2);
                Bt[0][nl + 2][kl] = s0; Bt[1][nl + 2][kl] = s1; Bt[2][nl + 2][kl] = s2;
                split3(v.w, s0, s1, s2);
                Bt[0][nl + 3][kl] = s0; Bt[1][nl + 3][kl] = s1; Bt[2][nl + 3][kl] = s2;
            }
        }
        __syncthreads();
        bf16x8 bf[NR][3];
        #pragma unroll
        for (int nr = 0; nr < NR; ++nr) {
            int brow = wcol + nr * 16 + l16;
            #pragma unroll
            for (int s = 0; s < 3; ++s)
                bf[nr][s] = *(const bf16x8*)&Bt[s][brow][koff * 8];
        }
        #pragma unroll
        for (int mr = 0; mr < MR; ++mr) {
            int arow = wrow + mr * 16 + l16;
            bf16x8 a0 = *(const bf16x8*)&At[0][arow][koff * 8];
            bf16x8 a1 = *(const bf16x8*)&At[1][arow][koff * 8];
            bf16x8 a2 = *(const bf16x8*)&At[2][arow][koff * 8];
            #pragma unroll
            for (int nr = 0; nr < NR; ++nr) {
                f32x4 c = acc[mr][nr];
                c = __builtin_amdgcn_mfma_f32_16x16x32_bf16(a0, bf[nr][0], c, 0, 0, 0);
                c = __builtin_amdgcn_mfma_f32_16x16x32_bf16(a0, bf[nr][1], c, 0, 0, 0);
                c = __builtin_amdgcn_mfma_f32_16x16x32_bf16(a1, bf[nr][0], c, 0, 0, 0);
                c = __builtin_amdgcn_mfma_f32_16x16x32_bf16(a0, bf[nr][2], c, 0, 0, 0);
                c = __builtin_amdgcn_mfma_f32_16x16x32_bf16(a1, bf[nr][1], c, 0, 0, 0);
                c = __builtin_amdgcn_mfma_f32_16x16x32_bf16(a2, bf[nr][0], c, 0, 0, 0);
                acc[mr][nr] = c;
            }
        }
        __syncthreads();
    }
    #pragma unroll
    for (int mr = 0; mr < MR; ++mr) {
        #pragma unroll
        for (int r = 0; r < 4; ++r) {
            int gr = row0 + wrow + mr * 16 + koff * 4 + r;
            if (gr >= M) continue;
            #pragma unroll
            for (int nr = 0; nr < NR; ++nr) {
                int gc = col0 + wcol + nr * 16 + l16;
                float v = alpha * acc[mr][nr][r];
                if (Cin) v += beta * Cin[cb + (long)gr * ldc + gc];
                if (add_id && gr == gc) v += 1.f;
                Out[ob + (long)gr * ldo + gc] = v;
            }
        }
    }
}

static void fallback_launch(void* const* d_in, void* d_out, void* d_ws,
                            hipStream_t stream)
{
    const float* y0 = (const float*)d_in[1];
    const float* u  = (const float*)d_in[2];
    const float* Am = (const float*)d_in[3];
    const float* Bm = (const float*)d_in[4];
    float* Yout = (float*)d_out;
    float* w = (float*)d_ws;
    const float h = 0.01f;
    const int N = GN;

    float* Eyy = w;
    float* T1  = Eyy + (long)N * N;
    float* T2  = T1  + (long)N * N;
    float* V1  = T2  + (long)N * N;
    float* Vt  = V1  + (long)N * GM;
    float* V2  = Vt  + (long)N * GM;
    float* G1  = V2  + (long)N * GM;
    float* G2  = G1  + (long)N * GM;
    float* Z   = G2  + (long)N * GM;
    float* Zt  = Z   + (long)CCH * N;
    dim3 blk(256);

    auto gemm = [&](bool transb, const float* A, long ab, long lda,
                    const float* B, const float* Cin, long cb, long ldc, float beta,
                    float* Out, long ob, long ldo,
                    int M, int Nn, int K, float alpha, int add_id) {
        if (M > 1536 && (Nn % 128) == 0) {
            dim3 grid((M + 127) / 128, Nn / 128);
            if (transb)
                gemm_mfma<128, 128, true><<<grid, blk, 0, stream>>>(A, ab, lda, B, Cin, cb, ldc, beta, Out, ob, ldo, M, Nn, K, alpha, add_id);
            else
                gemm_mfma<128, 128, false><<<grid, blk, 0, stream>>>(A, ab, lda, B, Cin, cb, ldc, beta, Out, ob, ldo, M, Nn, K, alpha, add_id);
        } else {
            dim3 grid((M + 63) / 64, Nn / 64);
            if (transb)
                gemm_mfma<64, 64, true><<<grid, blk, 0, stream>>>(A, ab, lda, B, Cin, cb, ldc, beta, Out, ob, ldo, M, Nn, K, alpha, add_id);
            else
                gemm_mfma<64, 64, false><<<grid, blk, 0, stream>>>(A, ab, lda, B, Cin, cb, ldc, beta, Out, ob, ldo, M, Nn, K, alpha, add_id);
        }
    };

    scale_add_id_k<<<dim3(4, N), blk, 0, stream>>>(T1, Am, h / 5.f, N);
    {
        float* pc = T1; float* pn = T2;
        for (int k = 4; k >= 1; --k) {
            float* out = (k == 1) ? Eyy : pn;
            gemm(false, Am, 0, N, pc, nullptr, 0, 0, 0.f, out, 0, N, N, N, N, h / (float)k, 1);
            pn = pc; pc = out;
        }
    }
    const long NM = (long)N * GM;
    scale_copy_k<<<dim3((unsigned)((NM + 255) / 256)), blk, 0, stream>>>(V1, Bm, 1.f / 120.f, NM);
    {
        const float f1[4] = {1.f / 24.f, 1.f / 6.f, 0.5f, 1.f};
        float* pc = V1; float* pn = Vt;
        for (int j = 3; j >= 0; --j) {
            gemm(false, Am, 0, N, pc, Bm, 0, GM, f1[3 - j], pn, 0, GM, N, GM, N, h, 0);
            float* t = pc; pc = pn; pn = t;
        }
    }
    scale_copy_k<<<dim3((unsigned)((NM + 255) / 256)), blk, 0, stream>>>(V2, Bm, 1.f / 720.f, NM);
    {
        const float f2[4] = {1.f / 120.f, 1.f / 24.f, 1.f / 6.f, 0.5f};
        float* pc = V2; float* pn = Vt;
        for (int j = 3; j >= 0; --j) {
            gemm(false, Am, 0, N, pc, Bm, 0, GM, f2[3 - j], pn, 0, GM, N, GM, N, h, 0);
            float* t = pc; pc = pn; pn = t;
        }
    }
    g1g2_k<<<dim3((unsigned)((NM + 255) / 256)), blk, 0, stream>>>(G1, G2, V1, V2, h, NM);
    gemm(true, u, 0, GM, G1, nullptr, 0, 0, 0.f, Yout, (long)N, N, GT - 1, N, GM, 1.f, 0);
    gemm(true, u, GM, GM, G2, Yout, (long)N, N, 1.f, Yout, (long)N, N, GT - 1, N, GM, 1.f, 0);
    copy_rows_k<<<dim3(4, 1), blk, 0, stream>>>(Yout, 0, 0, y0, 0, 0, N);
    for (int s = 2; s <= SCH; ++s) {
        int Mr = (GT - 1 - s) / SCH + 1;
        gemm(true, Yout, (long)(s - 1) * N, (long)SCH * N, Eyy,
             Yout, (long)s * N, (long)SCH * N, 1.f,
             Yout, (long)s * N, (long)SCH * N, Mr, N, N, 1.f, 0);
    }
    copy_rows_k<<<dim3(4, 1), blk, 0, stream>>>(Z, 0, 0, y0, 0, 0, N);
    copy_rows_k<<<dim3(4, CCH - 1), blk, 0, stream>>>(Z, (long)N, (long)N,
                                                      Yout, (long)SCH * N, (long)SCH * N, N);
    gemm(false, Eyy, 0, N, Eyy, nullptr, 0, 0, 0.f, T1, 0, N, N, N, N, 1.f, 0);
    gemm(false, T1, 0, N, T1, nullptr, 0, 0, 0.f, T2, 0, N, N, N, N, 1.f, 0);
    gemm(false, T2, 0, N, T2, nullptr, 0, 0, 0.f, T1, 0, N, N, N, N, 1.f, 0);
    {
        float* Mc = T1; float* Mo = T2;
        float* Zc = Z;  float* Zn = Zt;
        for (int p = 0; p < 10; ++p) {
            int o = 1 << p;
            gemm(true, Zc, 0, N, Mc, Zc, (long)o * N, N, 1.f,
                 Zn, (long)o * N, N, CCH - o, N, N, 1.f, 0);
            copy_rows_k<<<dim3(4, o), blk, 0, stream>>>(Zn, 0, N, Zc, 0, N, N);
            if (p < 9) {
                gemm(false, Mc, 0, N, Mc, nullptr, 0, 0, 0.f, Mo, 0, N, N, N, N, 1.f, 0);
                float* t = Mc; Mc = Mo; Mo = t;
            }
            float* t = Zc; Zc = Zn; Zn = t;
        }
        copy_rows_k<<<dim3(4, CCH), blk, 0, stream>>>(Yout, 0, (long)SCH * N, Zc, 0, N, N);
        float* Q = Zc; float* Qt = Zn;
        for (int s = 1; s <= SCH - 1; ++s) {
            gemm(true, Q, 0, N, Eyy, nullptr, 0, 0, 0.f, Qt, 0, N, CCH, N, N, 1.f, 0);
            int Mr = (GT - 1 - s) / SCH + 1;
            add_rows_k<<<dim3(4, Mr), blk, 0, stream>>>(Yout, (long)s * N, (long)SCH * N, Qt, N);
            float* t = Q; Q = Qt; Qt = t;
        }
    }
}

// ---------------------------------------------------------------------------
extern "C" void kernel_launch(void* const* d_in, const int* in_sizes, int n_in,
                              void* d_out, int out_size, void* d_ws, size_t ws_size,
                              hipStream_t stream)
{
    (void)in_sizes; (void)n_in; (void)out_size;
    const size_t NEED = 46ull * 1024 * 1024;
    if (ws_size < NEED) { fallback_launch(d_in, d_out, d_ws, stream); return; }

    const float* y0 = (const float*)d_in[1];
    const float* u  = (const float*)d_in[2];
    const float* Am = (const float*)d_in[3];
    const float* Bm = (const float*)d_in[4];
    float* Yout = (float*)d_out;
    char* w = (char*)d_ws;
    const float h = 0.01f;
    const size_t MB = 1024 * 1024;
    const long PP  = 1 << 20;                  // 1024x1024 plane limb stride
    const long P2  = 1 << 21;                  // 2048-row plane limb stride
    const long P4  = 1 << 22;                  // 4096-row plane limb stride
    const long PUS = 1 << 22;                  // u planes limb stride
    const long PBS = 1 << 19;                  // B^T planes limb stride
    const int  BIG = 1 << 30;

    // ws layout (46 MB, time-phased). Liveness documented per phase below.
    unsigned short* PU   = (unsigned short*)(w);            // [0,16)  u planes
    unsigned short* PZW1 = (unsigned short*)(w);            // [0,8)   z+W^T ping
    unsigned short* PA   = (unsigned short*)(w + 8 * MB);   // [8,12)  planes(Am)
    unsigned short* SQa  = (unsigned short*)(w + 8 * MB);   // [8,12)  E^2T (F1..s5)
    unsigned short* SQb  = (unsigned short*)(w + 12 * MB);  // [12,16) E^4T / scratch
    unsigned short* PZW2 = (unsigned short*)(w + 8 * MB);   // [8,16)  z pong (doubling)
    unsigned short* CH1  = (unsigned short*)(w + 16 * MB);  // [16,24) chain ping
    unsigned short* WA   = (unsigned short*)(w + 16 * MB);  // [16,20) w-slot / PWt pong
    unsigned short* PWt0 = (unsigned short*)(w + 20 * MB);  // [20,24) E^8 planes / PWt ping
    unsigned short* CH2  = (unsigned short*)(w + 24 * MB);  // [24,32) chain pong
    unsigned short* WB   = (unsigned short*)(w + 24 * MB);  // [24,28) w-slot
    unsigned short* PE   = (unsigned short*)(w + 28 * MB);  // [28,32) planes(E)  = PWR+0
    unsigned short* PG   = (unsigned short*)(w + 32 * MB);  // [32,36) Gcat -> E^2
    unsigned short* PW2  = PG;                              //          planes(E^2)
    unsigned short* PW3  = (unsigned short*)(w + 36 * MB);  // [36,40) w2 -> planes(E^3)
    unsigned short* PW4  = (unsigned short*)(w + 40 * MB);  // [40,44) planes(E^4)
    unsigned short* PBT  = (unsigned short*)(w + 44 * MB);  // [44,46) planes(B^T)
    unsigned short* QPL  = (unsigned short*)(w + 8 * MB);   // [8,24)  Q planes (phase3)
    unsigned short* PWR  = PE;                              // powers table base

    dim3 blk(256), blk5(512);

    // ---- 1. planes(Am) ----
    split_pl_k<<<dim3(4096), blk, 0, stream>>>(Am, PA, PP, 10, 1.f, (long)1 << 20);

    // ---- 2. seeds: CH1 = [I+(h/5)A^T ; B^T/120 ; B^T/720], PBT = B^T ----
    trsp_k<<<dim3(32, 32), blk, 0, stream>>>(Am, 1024, h / 5.f, 1, CH1, P2, 0);
    trsp_k<<<dim3(16, 32), blk, 0, stream>>>(Bm, 512, 1.f / 120.f, 0, CH1, P2, 1024);
    trsp_k<<<dim3(16, 32), blk, 0, stream>>>(Bm, 512, 1.f / 720.f, 0, CH1, P2, 1536);
    trsp_k<<<dim3(16, 32), blk, 0, stream>>>(Bm, 512, 1.f, 0, PBT, PBS, 0);

    // ---- 3. fused chain x4: expm Horner (rows<1024) + phi chains (rows 1024+) ----
    {
        const float alE[4] = {h / 4.f, h / 3.f, h / 2.f, h};
        const float f1[4] = {1.f / 24.f, 1.f / 6.f, 0.5f, 1.f};
        const float f2[4] = {1.f / 120.f, 1.f / 24.f, 1.f / 6.f, 0.5f};
        unsigned short* cc = CH1; unsigned short* cn = CH2;
        for (int j = 0; j < 4; ++j) {
            gemm_pp<64, 2, 2><<<dim3(32, 16), blk5, 0, stream>>>(
                cc, P2, 1024, 10, -1, 0, 0,
                PA, PP, 0,
                nullptr, 0, 0, PBT, PBS, 511,
                1024, 1536, f1[j], f2[j],
                nullptr, 0, 0, 0,
                cn, P2, 0, 1, 0,
                BIG, 0, -1,
                2048, alE[j], h, 1024, 1,
                nullptr, 0, nullptr, nullptr, 0, 0, BIG, nullptr, BIG);
            unsigned short* t = cc; cc = cn; cn = t;
        }  // final in CH1
    }
    tspp_k<<<dim3(32, 32), blk, 0, stream>>>(CH1, P2, 0, PE, PP);
    gtspp_k<<<dim3(16, 32, 2), blk, 0, stream>>>(CH1 + (1 << 20), P2, PG, PP, h);

    // ---- 4. planes(u) ----
    split_pl_k<<<dim3(16384), blk, 0, stream>>>(u, PU, PUS, 9, 1.f, PUS);

    // ---- 5. c-staging: Yout[t] = [u_{t-1}|u_t]@Gcat^T (+w1 planes -> WB) ----
    gemm_pp<128, 4, 1><<<dim3(64, 8), blk5, 0, stream>>>(
        PU, PUS, 512, 9, -1, 0, 0,
        PG, PP, 0,
        nullptr, 0, 0, nullptr, 0, -1,
        0, BIG, 0.f, 0.f,
        Yout, 1024, 1024, 0,
        WB, PP, 1, 1, 0,
        BIG, 0, -1,
        GT - 1, 1.f, 1.f, BIG, 0,
        nullptr, 0, nullptr, nullptr, 0, 0, BIG, nullptr, BIG);

    // ---- 6. phase 1 (serial s=2..8) fused with E-squarings + E^3 power ----
    // F1: s=2 | dual: E^2T = E^T@planes(E) -> SQa ; PoutT: planes(E^2) -> PW2
    gemm_pp<64, 2, 2><<<dim3(32, 16), blk5, 0, stream>>>(
        WB, PP, 1024, 10, -1, 0, 0,
        PE, PP, 0,
        Yout, 2 * 1024, 8192, nullptr, 0, -1,
        0, BIG, 1.f, 0.f,
        Yout, 2 * 1024, 8192, 0,
        PW3, PP, 0, 1, 0,                       // w2 planes -> PW3 region
        BIG, 0, -1,
        2048, 1.f, 1.f, BIG, 0,
        CH1, P2, PE, SQa, PP, 0, 1024, PW2, 1024);
    // F2: s=3 | dual: E^4T = E^2T@planes(E^2) -> SQb ; PoutT: planes(E^4) -> PW4
    gemm_pp<64, 2, 2><<<dim3(32, 16), blk5, 0, stream>>>(
        PW3, PP, 1024, 10, -1, 0, 0,
        PE, PP, 0,
        Yout, 3 * 1024, 8192, nullptr, 0, -1,
        0, BIG, 1.f, 0.f,
        Yout, 3 * 1024, 8192, 0,
        WB, PP, 0, 1, 0,                        // w3 -> WB
        BIG, 0, -1,
        2048, 1.f, 1.f, BIG, 0,
        SQa, PP, PW2, SQb, PP, 0, 1024, PW4, 1024);
    // F3: s=4 | dual: E^8T -> PZW1 rows 1024+ ; PoutT: planes(E^8) -> PWt0
    gemm_pp<64, 2, 2><<<dim3(32, 16), blk5, 0, stream>>>(
        WB, PP, 1024, 10, -1, 0, 0,
        PE, PP, 0,
        Yout, 4 * 1024, 8192, nullptr, 0, -1,
        0, BIG, 1.f, 0.f,
        Yout, 4 * 1024, 8192, 0,
        WA, PP, 0, 1, 0,                        // w4 -> WA
        BIG, 0, -1,
        2048, 1.f, 1.f, BIG, 0,
        SQb, PP, PW4, PZW1, P2, 1024, 1024, PWt0, 1024);
    // s=5 | dual: E^3T = E^2T@planes(E) (planes discarded) ; PoutT: E^3 -> PW3
    gemm_pp<64, 2, 2><<<dim3(32, 16), blk5, 0, stream>>>(
        WA, PP, 1024, 10, -1, 0, 0,
        PE, PP, 0,
        Yout, 5 * 1024, 8192, nullptr, 0, -1,
        0, BIG, 1.f, 0.f,
        Yout, 5 * 1024, 8192, 0,
        WB, PP, 0, 1, 0,                        // w5 -> WB
        BIG, 0, -1,
        2048, 1.f, 1.f, BIG, 0,
        SQa, PP, PE, nullptr, 0, 0, 1024, PW3, 1024);
    // s=6, s=7 solo
    gemm_pp<64, 2, 2><<<dim3(16, 16), blk5, 0, stream>>>(
        WB, PP, 1024, 10, -1, 0, 0,
        PE, PP, 0,
        Yout, 6 * 1024, 8192, nullptr, 0, -1,
        0, BIG, 1.f, 0.f,
        Yout, 6 * 1024, 8192, 0,
        WA, PP, 0, 1, 0,
        BIG, 0, -1,
        1024, 1.f, 1.f, BIG, 0,
        nullptr, 0, nullptr, nullptr, 0, 0, BIG, nullptr, BIG);
    gemm_pp<64, 2, 2><<<dim3(16, 16), blk5, 0, stream>>>(
        WA, PP, 1024, 10, -1, 0, 0,
        PE, PP, 0,
        Yout, 7 * 1024, 8192, nullptr, 0, -1,
        0, BIG, 1.f, 0.f,
        Yout, 7 * 1024, 8192, 0,
        WB, PP, 0, 1, 0,
        BIG, 0, -1,
        1024, 1.f, 1.f, BIG, 0,
        nullptr, 0, nullptr, nullptr, 0, 0, BIG, nullptr, BIG);
    // s=8 -> boundary rows 8(i+1): z planes -> PZW1 rows 1..1023 (zoff=1)
    gemm_pp<64, 2, 2><<<dim3(16, 16), blk5, 0, stream>>>(
        WB, PP, 1024, 10, -1, 0, 0,
        PE, PP, 0,
        Yout, 0, 8192, nullptr, 0, -1,
        0, BIG, 1.f, 0.f,
        Yout, 0, 8192, 0,
        PZW1, P2, 0, 1, 0,
        BIG, 1, -1,
        1023, 1.f, 1.f, BIG, 0,
        nullptr, 0, nullptr, nullptr, 0, 0, BIG, nullptr, BIG);
    // z_0 = y0 -> PZW1 plane row 0
    split_pl_k<<<dim3(4), blk, 0, stream>>>(y0, PZW1, P2, 10, 1.f, 1024);

    // ---- 7. fused doubling: one GEMM per round, W-transpose in epilogue ----
    {
        unsigned short* PZc = PZW1; unsigned short* PZn = PZW2;
        for (int p = 0; p < 10; ++p) {
            int o = 1 << p;
            int Mr = (p == 9) ? 1024 : 2048;
            unsigned short* PWc = (p & 1) ? WA : PWt0;
            unsigned short* PWn = (p & 1) ? PWt0 : WA;
            gemm_pp<64, 2, 2><<<dim3(Mr / 64, 16), blk5, 0, stream>>>(
                PZc, P2, 1024, 10, -1, o, 1024,
                PWc, PP, 0,
                nullptr, 0, 0,
                PZc, P2, 0x7fffffff,
                0, 1024, 1.f, 0.f,
                (p == 9) ? Yout : nullptr, 0, 8192, 0,
                PZn, P2, 0, 1, 0,
                1024, 0, -1,
                Mr, 0.f, 1.f, o, 0,
                nullptr, 0, nullptr, nullptr, 0, 0, BIG,
                (p < 9) ? PWn : nullptr, 1024);
            unsigned short* t = PZc; PZc = PZn; PZn = t;
        }  // final Z planes in PZW1
    }
    copy_rows_k<<<dim3(4, 1), blk, 0, stream>>>(Yout, 0, 0, y0, 0, 0, 1024);

    // ---- 8. phase 3 via powers: L1 [Q1..Q4]=Z@[E..E^4]^T ; L2 [Q5..Q7]=[Q1..Q3]@E^4T
    gemm_pp<64, 2, 2><<<dim3(64, 16), blk5, 0, stream>>>(
        PZW1, P2, 1024, 10, 1023, 0, 0,         // A row = gr & 1023 (Z)
        PWR, PP, (long)(1 << 21),               // B = powers[row0>>10]
        Yout, 1024, 8192, nullptr, 0, -1,
        0, BIG, 1.f, 0.f,
        Yout, 1024, 8192, 1024,                 // s = 1 + segk
        QPL, P4, 0, 2, 1024,                    // Q planes row = gr, pure product
        0, 0, 1023,
        4096, 1.f, 1.f, BIG, 0,
        nullptr, 0, nullptr, nullptr, 0, 0, BIG, nullptr, BIG);
    gemm_pp<64, 2, 2><<<dim3(48, 16), blk5, 0, stream>>>(
        QPL, P4, 1024, 10, -1, 0, 0,            // A row = gr (Q1..Q3)
        PW4, PP, 0,
        Yout, 5 * 1024, 8192, nullptr, 0, -1,
        0, BIG, 1.f, 0.f,
        Yout, 5 * 1024, 8192, 1024,             // s = 5 + segk
        nullptr, 0, 0, 1, 0,
        0, 0, 1023,
        3072, 1.f, 1.f, BIG, 0,
        nullptr, 0, nullptr, nullptr, 0, 0, BIG, nullptr, BIG);
}

// Round 11
// 705.194 us; speedup vs baseline: 2.1852x; 1.0749x over previous
//
#include <hip/hip_runtime.h>

// Problem constants (fixed in the reference file)
#define GT 8192      // time steps
#define GN 1024      // state dim
#define GM 512       // input dim
#define CCH 1024     // scan chunks
#define SCH 8        // steps per chunk

typedef __attribute__((ext_vector_type(8))) short bf16x8;
typedef __attribute__((ext_vector_type(4))) float f32x4;

__device__ __forceinline__ unsigned short f2bf(float x) {   // RNE fp32->bf16
    unsigned int u = __float_as_uint(x);
    u += 0x7FFF + ((u >> 16) & 1);
    return (unsigned short)(u >> 16);
}
__device__ __forceinline__ float bf2f(unsigned short b) {
    return __uint_as_float(((unsigned int)b) << 16);
}
__device__ __forceinline__ void split2(float x, unsigned short& h0, unsigned short& h1) {
    h0 = f2bf(x);
    h1 = f2bf(x - bf2f(h0));
}
__device__ __forceinline__ void split3(float x, unsigned short& s0,
                                       unsigned short& s1, unsigned short& s2) {
    s0 = f2bf(x); float r = x - bf2f(s0);
    s1 = f2bf(r); r -= bf2f(s1);
    s2 = f2bf(r);
}
// storage swizzle: XOR element bits 3-4 with (row>>1)&3 (row = e>>sh). Involution.
__device__ __forceinline__ long swz(long e, int sh) {
    return e ^ (((e >> (sh + 1)) & 3) << 3);
}
// async 16B global->LDS (dest wave-uniform base; HW scatters lane*16; src per-lane)
__device__ __forceinline__ void gl16(const unsigned short* g, unsigned short* l) {
    __builtin_amdgcn_global_load_lds(
        (const __attribute__((address_space(1))) unsigned int*)g,
        (__attribute__((address_space(3))) unsigned int*)l, 16, 0, 0);
}

// ---------------------------------------------------------------------------
// Plane x plane GEMM; 512 threads = 8 waves = (2 x WN quads) x KS k-groups.
// KS=2: waves 0-3 / 4-7 split the 64-k step; f32 LDS reduce at end.
// Out = aa * A @ B^T (+ bb*Cin) (+I), K=1024, N=1024, 2-limb bf16 planes,
// 3 limb products (2 if a2limb==0: A is single-limb bf16).
// A element (r,k) at swz(r*alda+k, aldsh), limb1 +apsz.
// A row: ar = (row0+lr)&amask, then if ar<ashiftN: ar = max(ar-ashift,0).
// B base += (row0>>10)*bstride (power-table select); limb1 at +bpsz.
// trow = (((gr<segN)? gr+zoff : gr)) & trmask.
// aa = trow<asplit? alpha:alphaB; bb = trow<bzero? 0 : (trow<bsplit? beta:betaB).
// Of addr = ofb + (row0>>10)*ofstep + trow*ofld; Cin likewise (shared ofstep).
// Pout row = (pstep8? trow>>3 : trow) + (row0>>10)*prowstep; pmode 1=v, 2=aa*acc.
// DUAL (Ap2 set): blocks row0>=seg2 compute Ap2@Bp2^T pure (A row gr-seg2),
//   planes -> Pout2 (nullable) row gr-seg2+p2off (stride ppsz2). Always 2-limb.
// TRANSPOSE (PoutT set, BM==64): blocks row0>=tposeN also emit transposed tile
//   planes to PoutT (limb stride 1M): PoutT[col0+i][row0-tposeN+j].
// ---------------------------------------------------------------------------
template <int BM, int WN, int KS>
__global__ __launch_bounds__(512) void gemm_pp(
    const unsigned short* __restrict__ Ap, long apsz, int alda, int aldsh, int a2limb,
    int amask, int ashift, int ashiftN,
    const unsigned short* __restrict__ Bp, long bpsz, long bstride,
    const float* __restrict__ Cf, long cfb, long cfld,
    const unsigned short* __restrict__ Cp, long cpsz, int cmask,
    int bzero, int bsplit, float beta, float betaB,
    float* __restrict__ Of, long ofb, long ofld, long ofstep,
    unsigned short* __restrict__ Pout, long ppsz, int pstep8, int pmode, int prowstep,
    int segN, int zoff, int trmask,
    int M, float alpha, float alphaB, int asplit, int add_id,
    const unsigned short* __restrict__ Ap2, long apsz2,
    const unsigned short* __restrict__ Bp2,
    unsigned short* __restrict__ Pout2, long ppsz2, int p2off, int seg2,
    unsigned short* __restrict__ PoutT, int tposeN)
{
    constexpr int NQ = 2 * WN;             // output quads
    constexpr int MTM = BM / 32;           // 16-tiles in M per wave
    constexpr int MTN = BM / (WN * 16);    // 16-tiles in N per wave
    constexpr int CPW = KS * BM / 32;      // staging chunks per wave
    __shared__ __align__(16) unsigned short At[2][KS][2][BM][32];
    __shared__ __align__(16) unsigned short Bt[2][KS][2][BM][32];

    const int tid = threadIdx.x;
    const int lane = tid & 63;
    const int w = tid >> 6;
    const int ksub = w / NQ;
    const int quad = w % NQ;
    const int wr = (quad / WN) * (BM / 2);
    const int wc = (quad % WN) * (BM / WN);
    const int l16 = lane & 15, koff = lane >> 4;
    const int row0 = blockIdx.x * BM;
    const int col0 = blockIdx.y * BM;
    const int lr4 = lane >> 2;
    const int lg = lane & 3;
    const bool s2 = (Ap2 != nullptr) && (row0 >= seg2);
    const bool lead = (KS == 1) || (ksub == 0);
    const int segk = row0 >> 10;
    const bool alimb2 = a2limb || s2;

    f32x4 acc[MTM][MTN] = {};

    auto stage = [&](int bsel, int k0) {
        #pragma unroll
        for (int ci = 0; ci < CPW; ++ci) {
            const int c = w * CPW + ci;
            const int op = c / (KS * BM / 8);
            const int rem = c % (KS * BM / 8);
            const int limb = rem / (KS * BM / 16);
            const int rem2 = rem % (KS * BM / 16);
            const int kk = rem2 / (BM / 16);
            const int rb = (rem2 % (BM / 16)) * 16;
            const int lr = rb + lr4;
            const int q = lg ^ ((lr >> 1) & 3);
            if (op == 0 && limb == 1 && !alimb2) continue;   // 1-limb A
            long e; int sh; const unsigned short* base;
            if (op == 0) {
                if (!s2) {
                    int ar = (row0 + lr) & amask;
                    if (ar < ashiftN) { ar -= ashift; if (ar < 0) ar = 0; }
                    e = (long)ar * alda + k0 + kk * 32 + (q << 3); sh = aldsh;
                    base = Ap + (limb ? apsz : 0);
                } else {
                    e = (long)(row0 - seg2 + lr) * 1024 + k0 + kk * 32 + (q << 3); sh = 10;
                    base = Ap2 + (limb ? apsz2 : 0);
                }
            } else {
                e = (long)(col0 + lr) * 1024 + k0 + kk * 32 + (q << 3); sh = 10;
                base = (s2 ? Bp2 : (Bp + (long)segk * bstride)) + (limb ? bpsz : 0);
            }
            long f = swz(e, sh);
            unsigned short* l = (op == 0 ? &At[bsel][kk][limb][rb][0]
                                         : &Bt[bsel][kk][limb][rb][0]);
            gl16(base + f, l);
        }
    };

    stage(0, 0);
    __syncthreads();
    int cur = 0;
    for (int k0 = 0; k0 < 1024; k0 += KS * 32) {
        if (k0 + KS * 32 < 1024) stage(cur ^ 1, k0 + KS * 32);

        const int kk = ksub;
        bf16x8 a0[MTM], a1[MTM], b0[MTN], b1[MTN];
        #pragma unroll
        for (int mi = 0; mi < MTM; ++mi) {
            int lr = wr + mi * 16 + l16;
            int off = (koff ^ ((lr >> 1) & 3)) << 3;
            a0[mi] = *(const bf16x8*)&At[cur][kk][0][lr][off];
            if (alimb2) a1[mi] = *(const bf16x8*)&At[cur][kk][1][lr][off];
        }
        #pragma unroll
        for (int ni = 0; ni < MTN; ++ni) {
            int lr = wc + ni * 16 + l16;
            int off = (koff ^ ((lr >> 1) & 3)) << 3;
            b0[ni] = *(const bf16x8*)&Bt[cur][kk][0][lr][off];
            b1[ni] = *(const bf16x8*)&Bt[cur][kk][1][lr][off];
        }
        #pragma unroll
        for (int mi = 0; mi < MTM; ++mi)
            #pragma unroll
            for (int ni = 0; ni < MTN; ++ni) {
                f32x4 cc = acc[mi][ni];
                cc = __builtin_amdgcn_mfma_f32_16x16x32_bf16(a0[mi], b0[ni], cc, 0, 0, 0);
                cc = __builtin_amdgcn_mfma_f32_16x16x32_bf16(a0[mi], b1[ni], cc, 0, 0, 0);
                if (alimb2)
                    cc = __builtin_amdgcn_mfma_f32_16x16x32_bf16(a1[mi], b0[ni], cc, 0, 0, 0);
                acc[mi][ni] = cc;
            }
        __syncthreads();
        cur ^= 1;
    }

    if (KS == 2) {   // cross-ksub reduce (alias At as f32 scratch)
        float* red = (float*)&At[0][0][0][0][0];
        if (ksub == 1) {
            #pragma unroll
            for (int mi = 0; mi < MTM; ++mi)
                #pragma unroll
                for (int ni = 0; ni < MTN; ++ni)
                    *(f32x4*)&red[(((quad * MTM + mi) * MTN + ni) * 64 + lane) * 4] =
                        acc[mi][ni];
        }
        __syncthreads();
        if (ksub == 0) {
            #pragma unroll
            for (int mi = 0; mi < MTM; ++mi)
                #pragma unroll
                for (int ni = 0; ni < MTN; ++ni) {
                    f32x4 o = *(const f32x4*)
                        &red[(((quad * MTM + mi) * MTN + ni) * 64 + lane) * 4];
                    acc[mi][ni][0] += o[0]; acc[mi][ni][1] += o[1];
                    acc[mi][ni][2] += o[2]; acc[mi][ni][3] += o[3];
                }
        }
    }

    const bool tp = (PoutT != nullptr) && (row0 >= tposeN);
    float* T = (float*)&Bt[0][0][0][0][0];   // 64x65 f32, Bt dead

    if (s2) {                               // dual: pure product (+planes/T)
        if (lead) {
            #pragma unroll
            for (int mi = 0; mi < MTM; ++mi)
                #pragma unroll
                for (int r = 0; r < 4; ++r) {
                    const int gr = row0 + wr + mi * 16 + koff * 4 + r;
                    if (gr >= M) continue;
                    const int prow = gr - seg2 + p2off;
                    #pragma unroll
                    for (int ni = 0; ni < MTN; ++ni) {
                        const int gc = col0 + wc + ni * 16 + l16;
                        float pv = acc[mi][ni][r];
                        if (Pout2) {
                            long f = swz((long)prow * 1024 + gc, 10);
                            unsigned short h0 = f2bf(pv);
                            Pout2[f] = h0;
                            Pout2[ppsz2 + f] = f2bf(pv - bf2f(h0));
                        }
                        if (tp) T[(wr + mi * 16 + koff * 4 + r) * 65 + gc - col0] = pv;
                    }
                }
        }
    } else {
        if (lead) {
            const long ofe = ofb + (long)segk * ofstep;
            const long cfe = cfb + (long)segk * ofstep;
            #pragma unroll
            for (int mi = 0; mi < MTM; ++mi) {
                #pragma unroll
                for (int r = 0; r < 4; ++r) {
                    const int gr = row0 + wr + mi * 16 + koff * 4 + r;
                    if (gr >= M) continue;
                    const int trow = (((gr < segN) ? gr + zoff : gr)) & trmask;
                    if (gr < segN && trow >= segN) continue;
                    const float aa = (trow < asplit) ? alpha : alphaB;
                    const float bb = (trow < bzero) ? 0.f
                                    : ((trow < bsplit) ? beta : betaB);
                    #pragma unroll
                    for (int ni = 0; ni < MTN; ++ni) {
                        const int gc = col0 + wc + ni * 16 + l16;
                        float vp = aa * acc[mi][ni][r];
                        float v = vp;
                        if (bb != 0.f) {
                            int crow = trow & cmask;
                            if (Cf) v += bb * Cf[cfe + (long)crow * cfld + gc];
                            else if (Cp) {
                                long f = swz((long)crow * 1024 + gc, 10);
                                v += bb * (bf2f(Cp[f]) + bf2f(Cp[cpsz + f]));
                            }
                        }
                        if (add_id && gr == gc) v += 1.f;
                        if (Of) Of[ofe + (long)trow * ofld + gc] = v;
                        if (Pout && (!pstep8 || (trow & 7) == 0)) {
                            int prow = (pstep8 ? (trow >> 3) : trow) + segk * prowstep;
                            long f = swz((long)prow * 1024 + gc, 10);
                            float pv = (pmode == 2) ? vp : v;
                            unsigned short h0 = f2bf(pv);
                            Pout[f] = h0;
                            Pout[ppsz + f] = f2bf(pv - bf2f(h0));
                        }
                        if (tp) T[(wr + mi * 16 + koff * 4 + r) * 65 + gc - col0] = v;
                    }
                }
            }
        }
    }

    if (BM == 64 && tp) {                   // transposed plane emission
        __syncthreads();
        if (tid < 256) {
            const int i = tid >> 2;
            const int jb = (tid & 3) * 16;
            const int prow = col0 + i;
            #pragma unroll
            for (int e2 = 0; e2 < 16; ++e2) {
                int j = jb + e2;
                float v = T[j * 65 + i];
                long f = swz((long)prow * 1024 + (row0 - tposeN + j), 10);
                unsigned short h0 = f2bf(v);
                PoutT[f] = h0;
                PoutT[(long)(1 << 20) + f] = f2bf(v - bf2f(h0));
            }
        }
    }
}

// ---- X (cnt fp32, rows of length 2^ldsh) -> swizzled 2-limb planes ----
__global__ void split_pl_k(const float* __restrict__ X, unsigned short* __restrict__ P,
                           long psz, int ldsh, float s, long cnt)
{
    long i = (long)blockIdx.x * 256 + threadIdx.x;
    if (i >= cnt) return;
    float v = s * X[i];
    long f = swz(i, ldsh);
    unsigned short h0 = f2bf(v);
    P[f] = h0;
    P[psz + f] = f2bf(v - bf2f(h0));
}

// ---- X -> swizzled SINGLE-limb plane (bf16) ----
__global__ void split1_pl_k(const float* __restrict__ X, unsigned short* __restrict__ P,
                            int ldsh, long cnt)
{
    long i = (long)blockIdx.x * 256 + threadIdx.x;
    if (i >= cnt) return;
    P[swz(i, ldsh)] = f2bf(X[i]);
}

// ---- planes of s*in^T (+I): out rows (roff+)0..R-1, in is 1024 x R fp32 ----
__global__ void trsp_k(const float* __restrict__ in, int R, float s, int add_id,
                       unsigned short* __restrict__ P, long psz, int roff)
{
    __shared__ float t[32][33];
    const int tx = threadIdx.x & 31, ty4 = threadIdx.x >> 5;
    const int r0 = blockIdx.x * 32, c0 = blockIdx.y * 32;
    #pragma unroll
    for (int i = 0; i < 4; ++i)
        t[ty4 * 4 + i][tx] = in[(long)(c0 + ty4 * 4 + i) * R + r0 + tx];
    __syncthreads();
    #pragma unroll
    for (int i = 0; i < 4; ++i) {
        int r = r0 + ty4 * 4 + i, c = c0 + tx;
        float v = s * t[tx][ty4 * 4 + i];
        if (add_id && r == c) v += 1.f;
        long f = swz((long)(r + roff) * 1024 + c, 10);
        unsigned short h0 = f2bf(v);
        P[f] = h0;
        P[psz + f] = f2bf(v - bf2f(h0));
    }
}

// ---- planes(X) from planes(X^T): OUT[c][r] = IN[irow0+r][c] ----
__global__ void tspp_k(const unsigned short* __restrict__ IN, long ipsz, long irow0,
                       unsigned short* __restrict__ OUT, long opsz)
{
    __shared__ float t[32][33];
    const int tx = threadIdx.x & 31, ty4 = threadIdx.x >> 5;
    const int r0 = blockIdx.x * 32, c0 = blockIdx.y * 32;
    #pragma unroll
    for (int i = 0; i < 4; ++i) {
        long f = swz((irow0 + r0 + ty4 * 4 + i) * 1024 + c0 + tx, 10);
        t[ty4 * 4 + i][tx] = bf2f(IN[f]) + bf2f(IN[ipsz + f]);
    }
    __syncthreads();
    #pragma unroll
    for (int i = 0; i < 4; ++i) {
        int orow = c0 + ty4 * 4 + i;
        long f = swz((long)orow * 1024 + r0 + tx, 10);
        float v = t[tx][ty4 * 4 + i];
        unsigned short h0 = f2bf(v);
        OUT[f] = h0;
        OUT[opsz + f] = f2bf(v - bf2f(h0));
    }
}

// ---- Gcat planes from stacked [V1^T; V2^T] planes ----
__global__ void gtspp_k(const unsigned short* __restrict__ PV, long vpsz,
                        unsigned short* __restrict__ PG, long gpsz, float h)
{
    __shared__ float t[32][33];
    const int tx = threadIdx.x & 31, ty4 = threadIdx.x >> 5;
    const int k0 = blockIdx.x * 32, n0 = blockIdx.y * 32, z = blockIdx.z;
    #pragma unroll
    for (int i = 0; i < 4; ++i) {
        int k = k0 + ty4 * 4 + i, n = n0 + tx;
        long f2 = swz((long)(512 + k) * 1024 + n, 10);
        float v2 = bf2f(PV[f2]) + bf2f(PV[vpsz + f2]);
        float v;
        if (z == 0) {
            long f1 = swz((long)k * 1024 + n, 10);
            v = h * (bf2f(PV[f1]) + bf2f(PV[vpsz + f1]) - v2);
        } else v = h * v2;
        t[ty4 * 4 + i][tx] = v;
    }
    __syncthreads();
    #pragma unroll
    for (int i = 0; i < 4; ++i) {
        int n = n0 + ty4 * 4 + i, kk = z * 512 + k0 + tx;
        long f = swz((long)n * 1024 + kk, 10);
        float v = t[tx][ty4 * 4 + i];
        unsigned short h0 = f2bf(v);
        PG[f] = h0;
        PG[gpsz + f] = f2bf(v - bf2f(h0));
    }
}

// dst[db + r*ds + c] = src[sb + r*ss + c]
__global__ void copy_rows_k(float* __restrict__ dst, long db, long ds,
                            const float* __restrict__ src, long sb, long ss, int ncols)
{
    int r = blockIdx.y;
    int c = blockIdx.x * 256 + threadIdx.x;
    if (c < ncols) dst[db + (long)r * ds + c] = src[sb + (long)r * ss + c];
}

// dst[db + r*ds + c] += src[r*ncols + c]
__global__ void add_rows_k(float* __restrict__ dst, long db, long ds,
                           const float* __restrict__ src, int ncols)
{
    int r = blockIdx.y;
    int c = blockIdx.x * 256 + threadIdx.x;
    if (c < ncols) dst[db + (long)r * ds + c] += src[(long)r * ncols + c];
}

__global__ void scale_add_id_k(float* __restrict__ dst, const float* __restrict__ src,
                               float s, int n)
{
    int r = blockIdx.y;
    int c = blockIdx.x * 256 + threadIdx.x;
    if (c < n) dst[(long)r * n + c] = s * src[(long)r * n + c] + ((r == c) ? 1.f : 0.f);
}

__global__ void scale_copy_k(float* __restrict__ dst, const float* __restrict__ src,
                             float s, long cnt)
{
    long i = (long)blockIdx.x * 256 + threadIdx.x;
    if (i < cnt) dst[i] = s * src[i];
}

__global__ void g1g2_k(float* __restrict__ g1, float* __restrict__ g2,
                       const float* __restrict__ v1, const float* __restrict__ v2,
                       float h, long cnt)
{
    long i = (long)blockIdx.x * 256 + threadIdx.x;
    if (i < cnt) {
        float a = v1[i], b = v2[i];
        g1[i] = h * (a - b);
        g2[i] = h * b;
    }
}

// ---------------------------------------------------------------------------
// FALLBACK (round-3, 3-limb, 30 MB ws) — only if ws_size < 46 MB.
// ---------------------------------------------------------------------------
template <int BM, int BN, bool TRANSB>
__global__ __launch_bounds__(256) void gemm_mfma(
    const float* __restrict__ A, long ab, long lda,
    const float* __restrict__ B,
    const float* __restrict__ Cin, long cb, long ldc, float beta,
    float* __restrict__ Out, long ob, long ldo,
    int M, int Nn, int K, float alpha, int add_id)
{
    constexpr int LDT = 40;
    __shared__ unsigned short At[3][BM][LDT];
    __shared__ unsigned short Bt[3][BN][LDT];
    const int tid = threadIdx.x;
    const int lane = tid & 63;
    const int wid = tid >> 6;
    const int row0 = blockIdx.x * BM;
    const int col0 = blockIdx.y * BN;
    constexpr int MR = BM / 32;
    constexpr int NR = BN / 32;
    const int wrow = (wid >> 1) * (BM / 2);
    const int wcol = (wid & 1) * (BN / 2);
    const int l16 = lane & 15;
    const int koff = lane >> 4;
    f32x4 acc[MR][NR] = {};

    for (int k0 = 0; k0 < K; k0 += 32) {
        #pragma unroll
        for (int i = 0; i < BM / 32; ++i) {
            int r = i * 32 + (tid >> 3);
            int kl = (tid & 7) * 4;
            int gr = row0 + r;
            float4 v = make_float4(0.f, 0.f, 0.f, 0.f);
            if (gr < M) v = *(const float4*)&A[ab + (long)gr * lda + (k0 + kl)];
            unsigned short h0[4], h1[4], h2[4];
            split3(v.x, h0[0], h1[0], h2[0]);
            split3(v.y, h0[1], h1[1], h2[1]);
            split3(v.z, h0[2], h1[2], h2[2]);
            split3(v.w, h0[3], h1[3], h2[3]);
            *(ushort4*)&At[0][r][kl] = make_ushort4(h0[0], h0[1], h0[2], h0[3]);
            *(ushort4*)&At[1][r][kl] = make_ushort4(h1[0], h1[1], h1[2], h1[3]);
            *(ushort4*)&At[2][r][kl] = make_ushort4(h2[0], h2[1], h2[2], h2[3]);
        }
        if (TRANSB) {
            #pragma unroll
            for (int i = 0; i < BN / 32; ++i) {
                int r = i * 32 + (tid >> 3);
                int kl = (tid & 7) * 4;
                float4 v = *(const float4*)&B[(long)(col0 + r) * K + (k0 + kl)];
                unsigned short h0[4], h1[4], h2[4];
                split3(v.x, h0[0], h1[0], h2[0]);
                split3(v.y, h0[1], h1[1], h2[1]);
                split3(v.z, h0[2], h1[2], h2[2]);
                split3(v.w, h0[3], h1[3], h2[3]);
                *(ushort4*)&Bt[0][r][kl] = make_ushort4(h0[0], h0[1], h0[2], h0[3]);
                *(ushort4*)&Bt[1][r][kl] = make_ushort4(h1[0], h1[1], h1[2], h1[3]);
                *(ushort4*)&Bt[2][r][kl] = make_ushort4(h2[0], h2[1], h2[2], h2[3]);
            }
        } else {
            constexpr int TPK = BN / 4;
            #pragma unroll
            for (int i = 0; i < BN / 32; ++i) {
                int kl = i * (256 / TPK) + tid / TPK;
                int nl = (tid % TPK) * 4;
                float4 v = *(const float4*)&B[(long)(k0 + kl) * Nn + (col0 + nl)];
                unsigned short s0, s1, s2;
                split3(v.x, s0, s1, s2);
                Bt[0][nl + 0][kl] = s0; Bt[1][nl + 0][kl] = s1; Bt[2][nl + 0][kl] = s2;
                split3(v.y, s0, s1, s2);
                Bt[0][nl + 1][kl] = s0; Bt[1][nl + 1][kl] = s1; Bt[2][nl + 1][kl] = s2;
                split3(v.z, s0, s1, s2);
                Bt[0][nl + 2][kl] = s0; Bt[1][nl + 2][kl] = s1; Bt[2][nl + 2][kl] = s2;
                split3(v.w, s0, s1, s2);
                Bt[0][nl + 3][kl] = s0; Bt[1][nl + 3][kl] = s1; Bt[2][nl + 3][kl] = s2;
            }
        }
        __syncthreads();
        bf16x8 bf[NR][3];
        #pragma unroll
        for (int nr = 0; nr < NR; ++nr) {
            int brow = wcol + nr * 16 + l16;
            #pragma unroll
            for (int s = 0; s < 3; ++s)
                bf[nr][s] = *(const bf16x8*)&Bt[s][brow][koff * 8];
        }
        #pragma unroll
        for (int mr = 0; mr < MR; ++mr) {
            int arow = wrow + mr * 16 + l16;
            bf16x8 a0 = *(const bf16x8*)&At[0][arow][koff * 8];
            bf16x8 a1 = *(const bf16x8*)&At[1][arow][koff * 8];
            bf16x8 a2 = *(const bf16x8*)&At[2][arow][koff * 8];
            #pragma unroll
            for (int nr = 0; nr < NR; ++nr) {
                f32x4 c = acc[mr][nr];
                c = __builtin_amdgcn_mfma_f32_16x16x32_bf16(a0, bf[nr][0], c, 0, 0, 0);
                c = __builtin_amdgcn_mfma_f32_16x16x32_bf16(a0, bf[nr][1], c, 0, 0, 0);
                c = __builtin_amdgcn_mfma_f32_16x16x32_bf16(a1, bf[nr][0], c, 0, 0, 0);
                c = __builtin_amdgcn_mfma_f32_16x16x32_bf16(a0, bf[nr][2], c, 0, 0, 0);
                c = __builtin_amdgcn_mfma_f32_16x16x32_bf16(a1, bf[nr][1], c, 0, 0, 0);
                c = __builtin_amdgcn_mfma_f32_16x16x32_bf16(a2, bf[nr][0], c, 0, 0, 0);
                acc[mr][nr] = c;
            }
        }
        __syncthreads();
    }
    #pragma unroll
    for (int mr = 0; mr < MR; ++mr) {
        #pragma unroll
        for (int r = 0; r < 4; ++r) {
            int gr = row0 + wrow + mr * 16 + koff * 4 + r;
            if (gr >= M) continue;
            #pragma unroll
            for (int nr = 0; nr < NR; ++nr) {
                int gc = col0 + wcol + nr * 16 + l16;
                float v = alpha * acc[mr][nr][r];
                if (Cin) v += beta * Cin[cb + (long)gr * ldc + gc];
                if (add_id && gr == gc) v += 1.f;
                Out[ob + (long)gr * ldo + gc] = v;
            }
        }
    }
}

static void fallback_launch(void* const* d_in, void* d_out, void* d_ws,
                            hipStream_t stream)
{
    const float* y0 = (const float*)d_in[1];
    const float* u  = (const float*)d_in[2];
    const float* Am = (const float*)d_in[3];
    const float* Bm = (const float*)d_in[4];
    float* Yout = (float*)d_out;
    float* w = (float*)d_ws;
    const float h = 0.01f;
    const int N = GN;

    float* Eyy = w;
    float* T1  = Eyy + (long)N * N;
    float* T2  = T1  + (long)N * N;
    float* V1  = T2  + (long)N * N;
    float* Vt  = V1  + (long)N * GM;
    float* V2  = Vt  + (long)N * GM;
    float* G1  = V2  + (long)N * GM;
    float* G2  = G1  + (long)N * GM;
    float* Z   = G2  + (long)N * GM;
    float* Zt  = Z   + (long)CCH * N;
    dim3 blk(256);

    auto gemm = [&](bool transb, const float* A, long ab, long lda,
                    const float* B, const float* Cin, long cb, long ldc, float beta,
                    float* Out, long ob, long ldo,
                    int M, int Nn, int K, float alpha, int add_id) {
        if (M > 1536 && (Nn % 128) == 0) {
            dim3 grid((M + 127) / 128, Nn / 128);
            if (transb)
                gemm_mfma<128, 128, true><<<grid, blk, 0, stream>>>(A, ab, lda, B, Cin, cb, ldc, beta, Out, ob, ldo, M, Nn, K, alpha, add_id);
            else
                gemm_mfma<128, 128, false><<<grid, blk, 0, stream>>>(A, ab, lda, B, Cin, cb, ldc, beta, Out, ob, ldo, M, Nn, K, alpha, add_id);
        } else {
            dim3 grid((M + 63) / 64, Nn / 64);
            if (transb)
                gemm_mfma<64, 64, true><<<grid, blk, 0, stream>>>(A, ab, lda, B, Cin, cb, ldc, beta, Out, ob, ldo, M, Nn, K, alpha, add_id);
            else
                gemm_mfma<64, 64, false><<<grid, blk, 0, stream>>>(A, ab, lda, B, Cin, cb, ldc, beta, Out, ob, ldo, M, Nn, K, alpha, add_id);
        }
    };

    scale_add_id_k<<<dim3(4, N), blk, 0, stream>>>(T1, Am, h / 5.f, N);
    {
        float* pc = T1; float* pn = T2;
        for (int k = 4; k >= 1; --k) {
            float* out = (k == 1) ? Eyy : pn;
            gemm(false, Am, 0, N, pc, nullptr, 0, 0, 0.f, out, 0, N, N, N, N, h / (float)k, 1);
            pn = pc; pc = out;
        }
    }
    const long NM = (long)N * GM;
    scale_copy_k<<<dim3((unsigned)((NM + 255) / 256)), blk, 0, stream>>>(V1, Bm, 1.f / 120.f, NM);
    {
        const float f1[4] = {1.f / 24.f, 1.f / 6.f, 0.5f, 1.f};
        float* pc = V1; float* pn = Vt;
        for (int j = 3; j >= 0; --j) {
            gemm(false, Am, 0, N, pc, Bm, 0, GM, f1[3 - j], pn, 0, GM, N, GM, N, h, 0);
            float* t = pc; pc = pn; pn = t;
        }
    }
    scale_copy_k<<<dim3((unsigned)((NM + 255) / 256)), blk, 0, stream>>>(V2, Bm, 1.f / 720.f, NM);
    {
        const float f2[4] = {1.f / 120.f, 1.f / 24.f, 1.f / 6.f, 0.5f};
        float* pc = V2; float* pn = Vt;
        for (int j = 3; j >= 0; --j) {
            gemm(false, Am, 0, N, pc, Bm, 0, GM, f2[3 - j], pn, 0, GM, N, GM, N, h, 0);
            float* t = pc; pc = pn; pn = t;
        }
    }
    g1g2_k<<<dim3((unsigned)((NM + 255) / 256)), blk, 0, stream>>>(G1, G2, V1, V2, h, NM);
    gemm(true, u, 0, GM, G1, nullptr, 0, 0, 0.f, Yout, (long)N, N, GT - 1, N, GM, 1.f, 0);
    gemm(true, u, GM, GM, G2, Yout, (long)N, N, 1.f, Yout, (long)N, N, GT - 1, N, GM, 1.f, 0);
    copy_rows_k<<<dim3(4, 1), blk, 0, stream>>>(Yout, 0, 0, y0, 0, 0, N);
    for (int s = 2; s <= SCH; ++s) {
        int Mr = (GT - 1 - s) / SCH + 1;
        gemm(true, Yout, (long)(s - 1) * N, (long)SCH * N, Eyy,
             Yout, (long)s * N, (long)SCH * N, 1.f,
             Yout, (long)s * N, (long)SCH * N, Mr, N, N, 1.f, 0);
    }
    copy_rows_k<<<dim3(4, 1), blk, 0, stream>>>(Z, 0, 0, y0, 0, 0, N);
    copy_rows_k<<<dim3(4, CCH - 1), blk, 0, stream>>>(Z, (long)N, (long)N,
                                                      Yout, (long)SCH * N, (long)SCH * N, N);
    gemm(false, Eyy, 0, N, Eyy, nullptr, 0, 0, 0.f, T1, 0, N, N, N, N, 1.f, 0);
    gemm(false, T1, 0, N, T1, nullptr, 0, 0, 0.f, T2, 0, N, N, N, N, 1.f, 0);
    gemm(false, T2, 0, N, T2, nullptr, 0, 0, 0.f, T1, 0, N, N, N, N, 1.f, 0);
    {
        float* Mc = T1; float* Mo = T2;
        float* Zc = Z;  float* Zn = Zt;
        for (int p = 0; p < 10; ++p) {
            int o = 1 << p;
            gemm(true, Zc, 0, N, Mc, Zc, (long)o * N, N, 1.f,
                 Zn, (long)o * N, N, CCH - o, N, N, 1.f, 0);
            copy_rows_k<<<dim3(4, o), blk, 0, stream>>>(Zn, 0, N, Zc, 0, N, N);
            if (p < 9) {
                gemm(false, Mc, 0, N, Mc, nullptr, 0, 0, 0.f, Mo, 0, N, N, N, N, 1.f, 0);
                float* t = Mc; Mc = Mo; Mo = t;
            }
            float* t = Zc; Zc = Zn; Zn = t;
        }
        copy_rows_k<<<dim3(4, CCH), blk, 0, stream>>>(Yout, 0, (long)SCH * N, Zc, 0, N, N);
        float* Q = Zc; float* Qt = Zn;
        for (int s = 1; s <= SCH - 1; ++s) {
            gemm(true, Q, 0, N, Eyy, nullptr, 0, 0, 0.f, Qt, 0, N, CCH, N, N, 1.f, 0);
            int Mr = (GT - 1 - s) / SCH + 1;
            add_rows_k<<<dim3(4, Mr), blk, 0, stream>>>(Yout, (long)s * N, (long)SCH * N, Qt, N);
            float* t = Q; Q = Qt; Qt = t;
        }
    }
}

// ---------------------------------------------------------------------------
extern "C" void kernel_launch(void* const* d_in, const int* in_sizes, int n_in,
                              void* d_out, int out_size, void* d_ws, size_t ws_size,
                              hipStream_t stream)
{
    (void)in_sizes; (void)n_in; (void)out_size;
    const size_t NEED = 46ull * 1024 * 1024;
    if (ws_size < NEED) { fallback_launch(d_in, d_out, d_ws, stream); return; }

    const float* y0 = (const float*)d_in[1];
    const float* u  = (const float*)d_in[2];
    const float* Am = (const float*)d_in[3];
    const float* Bm = (const float*)d_in[4];
    float* Yout = (float*)d_out;
    char* w = (char*)d_ws;
    const float h = 0.01f;
    const size_t MB = 1024 * 1024;
    const long PP  = 1 << 20;                  // 1024x1024 plane limb stride
    const long P2  = 1 << 21;                  // 2048-row plane limb stride
    const long P4  = 1 << 22;                  // 4096-row plane limb stride
    const long PBS = 1 << 19;                  // B^T planes limb stride
    const int  BIG = 1 << 30;

    // ws layout (46 MB, time-phased):
    unsigned short* PU   = (unsigned short*)(w);            // [0,8)   u 1-limb plane
    unsigned short* PZW1 = (unsigned short*)(w);            // [0,8)   z+W^T ping
    unsigned short* PA   = (unsigned short*)(w + 8 * MB);   // [8,12)  planes(Am)
    unsigned short* SQa  = (unsigned short*)(w + 8 * MB);   // [8,12)  E^2T
    unsigned short* SQb  = (unsigned short*)(w + 12 * MB);  // [12,16) E^4T
    unsigned short* PZW2 = (unsigned short*)(w + 8 * MB);   // [8,16)  z pong
    unsigned short* CH1  = (unsigned short*)(w + 16 * MB);  // [16,24) chain ping
    unsigned short* WA   = (unsigned short*)(w + 16 * MB);  // [16,20) w-slot / PWt pong
    unsigned short* PWt0 = (unsigned short*)(w + 20 * MB);  // [20,24) E^8 planes / PWt ping
    unsigned short* CH2  = (unsigned short*)(w + 24 * MB);  // [24,32) chain pong
    unsigned short* WB   = (unsigned short*)(w + 24 * MB);  // [24,28) w-slot
    unsigned short* PE   = (unsigned short*)(w + 28 * MB);  // [28,32) planes(E) = PWR+0
    unsigned short* PG   = (unsigned short*)(w + 32 * MB);  // [32,36) Gcat -> E^2
    unsigned short* PW2  = PG;
    unsigned short* PW3  = (unsigned short*)(w + 36 * MB);  // [36,40) w2 -> planes(E^3)
    unsigned short* PW4  = (unsigned short*)(w + 40 * MB);  // [40,44) planes(E^4)
    unsigned short* PBT  = (unsigned short*)(w + 44 * MB);  // [44,46) planes(B^T)
    unsigned short* QPL  = (unsigned short*)(w + 8 * MB);   // [8,24)  Q planes (phase3)
    unsigned short* PWR  = PE;                              // powers table base

    dim3 blk(256), blk5(512);

    // ---- 1. planes(Am) ----
    split_pl_k<<<dim3(4096), blk, 0, stream>>>(Am, PA, PP, 10, 1.f, (long)1 << 20);

    // ---- 2. seeds (degree-3 Horner / 3-term phis):
    //      CH1 = [I+(h/3)A^T ; B^T/6 ; B^T/24], PBT = B^T ----
    trsp_k<<<dim3(32, 32), blk, 0, stream>>>(Am, 1024, h / 3.f, 1, CH1, P2, 0);
    trsp_k<<<dim3(16, 32), blk, 0, stream>>>(Bm, 512, 1.f / 6.f, 0, CH1, P2, 1024);
    trsp_k<<<dim3(16, 32), blk, 0, stream>>>(Bm, 512, 1.f / 24.f, 0, CH1, P2, 1536);
    trsp_k<<<dim3(16, 32), blk, 0, stream>>>(Bm, 512, 1.f, 0, PBT, PBS, 0);

    // ---- 3. fused chain x2: exp deg-3 (rows<1024) + phi 3-term (rows 1024+) ----
    {
        const float alE[2] = {h / 2.f, h};
        const float f1[2] = {0.5f, 1.f};
        const float f2[2] = {1.f / 6.f, 0.5f};
        unsigned short* cc = CH1; unsigned short* cn = CH2;
        for (int j = 0; j < 2; ++j) {
            gemm_pp<64, 2, 2><<<dim3(32, 16), blk5, 0, stream>>>(
                cc, P2, 1024, 10, 1, -1, 0, 0,
                PA, PP, 0,
                nullptr, 0, 0, PBT, PBS, 511,
                1024, 1536, f1[j], f2[j],
                nullptr, 0, 0, 0,
                cn, P2, 0, 1, 0,
                BIG, 0, -1,
                2048, alE[j], h, 1024, 1,
                nullptr, 0, nullptr, nullptr, 0, 0, BIG, nullptr, BIG);
            unsigned short* t = cc; cc = cn; cn = t;
        }  // 2 swaps -> final in CH1
    }
    tspp_k<<<dim3(32, 32), blk, 0, stream>>>(CH1, P2, 0, PE, PP);
    gtspp_k<<<dim3(16, 32, 2), blk, 0, stream>>>(CH1 + (1 << 20), P2, PG, PP, h);

    // ---- 4. u -> single-limb plane (8 MB) ----
    split1_pl_k<<<dim3(16384), blk, 0, stream>>>(u, PU, 9, (long)1 << 22);

    // ---- 5. c-staging (A 1-limb, 2 limb-products): Yout[t] = [u_{t-1}|u_t]@Gcat^T
    //      + w1 planes (rows 8i+1) -> WB ----
    gemm_pp<128, 4, 1><<<dim3(64, 8), blk5, 0, stream>>>(
        PU, 0, 512, 9, 0, -1, 0, 0,
        PG, PP, 0,
        nullptr, 0, 0, nullptr, 0, -1,
        0, BIG, 0.f, 0.f,
        Yout, 1024, 1024, 0,
        WB, PP, 1, 1, 0,
        BIG, 0, -1,
        GT - 1, 1.f, 1.f, BIG, 0,
        nullptr, 0, nullptr, nullptr, 0, 0, BIG, nullptr, BIG);

    // ---- 6. phase 1 (serial s=2..8) fused with E-squarings + E^3 power ----
    // F1: s=2 | dual: E^2T = E^T@planes(E) -> SQa ; PoutT: planes(E^2) -> PW2
    gemm_pp<64, 2, 2><<<dim3(32, 16), blk5, 0, stream>>>(
        WB, PP, 1024, 10, 1, -1, 0, 0,
        PE, PP, 0,
        Yout, 2 * 1024, 8192, nullptr, 0, -1,
        0, BIG, 1.f, 0.f,
        Yout, 2 * 1024, 8192, 0,
        PW3, PP, 0, 1, 0,                       // w2 planes -> PW3 region
        BIG, 0, -1,
        2048, 1.f, 1.f, BIG, 0,
        CH1, P2, PE, SQa, PP, 0, 1024, PW2, 1024);
    // F2: s=3 | dual: E^4T = E^2T@planes(E^2) -> SQb ; PoutT: planes(E^4) -> PW4
    gemm_pp<64, 2, 2><<<dim3(32, 16), blk5, 0, stream>>>(
        PW3, PP, 1024, 10, 1, -1, 0, 0,
        PE, PP, 0,
        Yout, 3 * 1024, 8192, nullptr, 0, -1,
        0, BIG, 1.f, 0.f,
        Yout, 3 * 1024, 8192, 0,
        WB, PP, 0, 1, 0,                        // w3 -> WB
        BIG, 0, -1,
        2048, 1.f, 1.f, BIG, 0,
        SQa, PP, PW2, SQb, PP, 0, 1024, PW4, 1024);
    // F3: s=4 | dual: E^8T -> PZW1 rows 1024+ ; PoutT: planes(E^8) -> PWt0
    gemm_pp<64, 2, 2><<<dim3(32, 16), blk5, 0, stream>>>(
        WB, PP, 1024, 10, 1, -1, 0, 0,
        PE, PP, 0,
        Yout, 4 * 1024, 8192, nullptr, 0, -1,
        0, BIG, 1.f, 0.f,
        Yout, 4 * 1024, 8192, 0,
        WA, PP, 0, 1, 0,                        // w4 -> WA
        BIG, 0, -1,
        2048, 1.f, 1.f, BIG, 0,
        SQb, PP, PW4, PZW1, P2, 1024, 1024, PWt0, 1024);
    // s=5 | dual: E^3T = E^2T@planes(E) ; PoutT: planes(E^3) -> PW3
    gemm_pp<64, 2, 2><<<dim3(32, 16), blk5, 0, stream>>>(
        WA, PP, 1024, 10, 1, -1, 0, 0,
        PE, PP, 0,
        Yout, 5 * 1024, 8192, nullptr, 0, -1,
        0, BIG, 1.f, 0.f,
        Yout, 5 * 1024, 8192, 0,
        WB, PP, 0, 1, 0,                        // w5 -> WB
        BIG, 0, -1,
        2048, 1.f, 1.f, BIG, 0,
        SQa, PP, PE, nullptr, 0, 0, 1024, PW3, 1024);
    // s=6, s=7 solo
    gemm_pp<64, 2, 2><<<dim3(16, 16), blk5, 0, stream>>>(
        WB, PP, 1024, 10, 1, -1, 0, 0,
        PE, PP, 0,
        Yout, 6 * 1024, 8192, nullptr, 0, -1,
        0, BIG, 1.f, 0.f,
        Yout, 6 * 1024, 8192, 0,
        WA, PP, 0, 1, 0,
        BIG, 0, -1,
        1024, 1.f, 1.f, BIG, 0,
        nullptr, 0, nullptr, nullptr, 0, 0, BIG, nullptr, BIG);
    gemm_pp<64, 2, 2><<<dim3(16, 16), blk5, 0, stream>>>(
        WA, PP, 1024, 10, 1, -1, 0, 0,
        PE, PP, 0,
        Yout, 7 * 1024, 8192, nullptr, 0, -1,
        0, BIG, 1.f, 0.f,
        Yout, 7 * 1024, 8192, 0,
        WB, PP, 0, 1, 0,
        BIG, 0, -1,
        1024, 1.f, 1.f, BIG, 0,
        nullptr, 0, nullptr, nullptr, 0, 0, BIG, nullptr, BIG);
    // s=8 -> boundary rows 8(i+1): z planes -> PZW1 rows 1..1023 (zoff=1)
    gemm_pp<64, 2, 2><<<dim3(16, 16), blk5, 0, stream>>>(
        WB, PP, 1024, 10, 1, -1, 0, 0,
        PE, PP, 0,
        Yout, 0, 8192, nullptr, 0, -1,
        0, BIG, 1.f, 0.f,
        Yout, 0, 8192, 0,
        PZW1, P2, 0, 1, 0,
        BIG, 1, -1,
        1023, 1.f, 1.f, BIG, 0,
        nullptr, 0, nullptr, nullptr, 0, 0, BIG, nullptr, BIG);
    // z_0 = y0 -> PZW1 plane row 0
    split_pl_k<<<dim3(4), blk, 0, stream>>>(y0, PZW1, P2, 10, 1.f, 1024);

    // ---- 7. fused doubling: one GEMM per round, W-transpose in epilogue ----
    {
        unsigned short* PZc = PZW1; unsigned short* PZn = PZW2;
        for (int p = 0; p < 10; ++p) {
            int o = 1 << p;
            int Mr = (p == 9) ? 1024 : 2048;
            unsigned short* PWc = (p & 1) ? WA : PWt0;
            unsigned short* PWn = (p & 1) ? PWt0 : WA;
            gemm_pp<64, 2, 2><<<dim3(Mr / 64, 16), blk5, 0, stream>>>(
                PZc, P2, 1024, 10, 1, -1, o, 1024,
                PWc, PP, 0,
                nullptr, 0, 0,
                PZc, P2, 0x7fffffff,
                0, 1024, 1.f, 0.f,
                (p == 9) ? Yout : nullptr, 0, 8192, 0,
                PZn, P2, 0, 1, 0,
                1024, 0, -1,
                Mr, 0.f, 1.f, o, 0,
                nullptr, 0, nullptr, nullptr, 0, 0, BIG,
                (p < 9) ? PWn : nullptr, 1024);
            unsigned short* t = PZc; PZc = PZn; PZn = t;
        }  // final Z planes in PZW1
    }
    copy_rows_k<<<dim3(4, 1), blk, 0, stream>>>(Yout, 0, 0, y0, 0, 0, 1024);

    // ---- 8. phase 3 via powers: L1 [Q1..Q4]=Z@[E..E^4]^T ; L2 [Q5..Q7]=[Q1..Q3]@E^4T
    gemm_pp<64, 2, 2><<<dim3(64, 16), blk5, 0, stream>>>(
        PZW1, P2, 1024, 10, 1, 1023, 0, 0,      // A row = gr & 1023 (Z)
        PWR, PP, (long)(1 << 21),               // B = powers[row0>>10]
        Yout, 1024, 8192, nullptr, 0, -1,
        0, BIG, 1.f, 0.f,
        Yout, 1024, 8192, 1024,                 // s = 1 + segk
        QPL, P4, 0, 2, 1024,                    // Q planes row = gr, pure product
        0, 0, 1023,
        4096, 1.f, 1.f, BIG, 0,
        nullptr, 0, nullptr, nullptr, 0, 0, BIG, nullptr, BIG);
    gemm_pp<64, 2, 2><<<dim3(48, 16), blk5, 0, stream>>>(
        QPL, P4, 1024, 10, 1, -1, 0, 0,         // A row = gr (Q1..Q3)
        PW4, PP, 0,
        Yout, 5 * 1024, 8192, nullptr, 0, -1,
        0, BIG, 1.f, 0.f,
        Yout, 5 * 1024, 8192, 1024,             // s = 5 + segk
        nullptr, 0, 0, 1, 0,
        0, 0, 1023,
        3072, 1.f, 1.f, BIG, 0,
        nullptr, 0, nullptr, nullptr, 0, 0, BIG, nullptr, BIG);
}

// Round 12
// 690.376 us; speedup vs baseline: 2.2321x; 1.0215x over previous
//
#include <hip/hip_runtime.h>

// Problem constants (fixed in the reference file)
#define GT 8192      // time steps
#define GN 1024      // state dim
#define GM 512       // input dim
#define CCH 1024     // scan chunks
#define SCH 8        // steps per chunk

typedef __attribute__((ext_vector_type(8))) short bf16x8;
typedef __attribute__((ext_vector_type(4))) float f32x4;

__device__ __forceinline__ unsigned short f2bf(float x) {   // RNE fp32->bf16
    unsigned int u = __float_as_uint(x);
    u += 0x7FFF + ((u >> 16) & 1);
    return (unsigned short)(u >> 16);
}
__device__ __forceinline__ float bf2f(unsigned short b) {
    return __uint_as_float(((unsigned int)b) << 16);
}
__device__ __forceinline__ void split2(float x, unsigned short& h0, unsigned short& h1) {
    h0 = f2bf(x);
    h1 = f2bf(x - bf2f(h0));
}
__device__ __forceinline__ void split3(float x, unsigned short& s0,
                                       unsigned short& s1, unsigned short& s2) {
    s0 = f2bf(x); float r = x - bf2f(s0);
    s1 = f2bf(r); r -= bf2f(s1);
    s2 = f2bf(r);
}
// storage swizzle: XOR element bits 3-4 with (row>>1)&3 (row = e>>sh). Involution.
__device__ __forceinline__ long swz(long e, int sh) {
    return e ^ (((e >> (sh + 1)) & 3) << 3);
}
// async 16B global->LDS (dest wave-uniform base; HW scatters lane*16; src per-lane)
__device__ __forceinline__ void gl16(const unsigned short* g, unsigned short* l) {
    __builtin_amdgcn_global_load_lds(
        (const __attribute__((address_space(1))) unsigned int*)g,
        (__attribute__((address_space(3))) unsigned int*)l, 16, 0, 0);
}

// ---------------------------------------------------------------------------
// Plane x plane GEMM; 512 threads = 8 waves = (2 x WN quads) x KS k-groups.
// KS=2: waves 0-3 / 4-7 split the 64-k step; f32 LDS reduce at end.
// Out = aa * A @ B^T (+ bb*Cin) (+I), K=1024, N=1024, 2-limb bf16 planes,
// 3 limb products (2 if a2limb==0: A is single-limb bf16).
// A element (r,k) at swz(r*alda+k, aldsh), limb1 +apsz.
// A row: ar = (row0+lr)&amask, then if ar<ashiftN: ar = max(ar-ashift,0).
// B base += (row0>>10)*bstride (power-table select); limb1 at +bpsz.
// trow = (((gr<segN)? gr+zoff : gr)) & trmask.
// aa = trow<asplit? alpha:alphaB; bb = trow<bzero? 0 : (trow<bsplit? beta:betaB).
// Of addr = ofb + (row0>>10)*ofstep + trow*ofld; Cin likewise (shared ofstep).
// Pout row = (pstep8? trow>>3 : trow) + (row0>>10)*prowstep; pmode 1=v, 2=aa*acc.
// DUAL (Ap2 set): blocks row0>=seg2 compute Ap2@Bp2^T pure (A row gr-seg2),
//   planes -> Pout2 (nullable) row gr-seg2+p2off (stride ppsz2). Always 2-limb.
// TRANSPOSE (PoutT set, BM==64): blocks row0>=tposeN also emit transposed tile
//   planes to PoutT (limb stride 1M): PoutT[col0+i][row0-tposeN+j].
// segswz > 0: remap blockIdx.x so XCD (flat%8) clusters by segk:
//   bx_log = (bx % segswz)*(gridDim.x/segswz) + bx/segswz.
// ---------------------------------------------------------------------------
template <int BM, int WN, int KS>
__global__ __launch_bounds__(512) void gemm_pp(
    const unsigned short* __restrict__ Ap, long apsz, int alda, int aldsh, int a2limb,
    int amask, int ashift, int ashiftN,
    const unsigned short* __restrict__ Bp, long bpsz, long bstride,
    const float* __restrict__ Cf, long cfb, long cfld,
    const unsigned short* __restrict__ Cp, long cpsz, int cmask,
    int bzero, int bsplit, float beta, float betaB,
    float* __restrict__ Of, long ofb, long ofld, long ofstep,
    unsigned short* __restrict__ Pout, long ppsz, int pstep8, int pmode, int prowstep,
    int segN, int zoff, int trmask,
    int M, float alpha, float alphaB, int asplit, int add_id,
    const unsigned short* __restrict__ Ap2, long apsz2,
    const unsigned short* __restrict__ Bp2,
    unsigned short* __restrict__ Pout2, long ppsz2, int p2off, int seg2,
    unsigned short* __restrict__ PoutT, int tposeN, int segswz)
{
    constexpr int NQ = 2 * WN;             // output quads
    constexpr int MTM = BM / 32;           // 16-tiles in M per wave
    constexpr int MTN = BM / (WN * 16);    // 16-tiles in N per wave
    constexpr int CPW = KS * BM / 32;      // staging chunks per wave
    __shared__ __align__(16) unsigned short At[2][KS][2][BM][32];
    __shared__ __align__(16) unsigned short Bt[2][KS][2][BM][32];

    const int tid = threadIdx.x;
    const int lane = tid & 63;
    const int w = tid >> 6;
    const int ksub = w / NQ;
    const int quad = w % NQ;
    const int wr = (quad / WN) * (BM / 2);
    const int wc = (quad % WN) * (BM / WN);
    const int l16 = lane & 15, koff = lane >> 4;
    int bx = blockIdx.x;
    if (segswz > 0) bx = (bx % segswz) * ((int)gridDim.x / segswz) + bx / segswz;
    const int row0 = bx * BM;
    const int col0 = blockIdx.y * BM;
    const int lr4 = lane >> 2;
    const int lg = lane & 3;
    const bool s2 = (Ap2 != nullptr) && (row0 >= seg2);
    const bool lead = (KS == 1) || (ksub == 0);
    const int segk = row0 >> 10;
    const bool alimb2 = a2limb || s2;

    f32x4 acc[MTM][MTN] = {};

    auto stage = [&](int bsel, int k0) {
        #pragma unroll
        for (int ci = 0; ci < CPW; ++ci) {
            const int c = w * CPW + ci;
            const int op = c / (KS * BM / 8);
            const int rem = c % (KS * BM / 8);
            const int limb = rem / (KS * BM / 16);
            const int rem2 = rem % (KS * BM / 16);
            const int kk = rem2 / (BM / 16);
            const int rb = (rem2 % (BM / 16)) * 16;
            const int lr = rb + lr4;
            const int q = lg ^ ((lr >> 1) & 3);
            if (op == 0 && limb == 1 && !alimb2) continue;   // 1-limb A
            long e; int sh; const unsigned short* base;
            if (op == 0) {
                if (!s2) {
                    int ar = (row0 + lr) & amask;
                    if (ar < ashiftN) { ar -= ashift; if (ar < 0) ar = 0; }
                    e = (long)ar * alda + k0 + kk * 32 + (q << 3); sh = aldsh;
                    base = Ap + (limb ? apsz : 0);
                } else {
                    e = (long)(row0 - seg2 + lr) * 1024 + k0 + kk * 32 + (q << 3); sh = 10;
                    base = Ap2 + (limb ? apsz2 : 0);
                }
            } else {
                e = (long)(col0 + lr) * 1024 + k0 + kk * 32 + (q << 3); sh = 10;
                base = (s2 ? Bp2 : (Bp + (long)segk * bstride)) + (limb ? bpsz : 0);
            }
            long f = swz(e, sh);
            unsigned short* l = (op == 0 ? &At[bsel][kk][limb][rb][0]
                                         : &Bt[bsel][kk][limb][rb][0]);
            gl16(base + f, l);
        }
    };

    stage(0, 0);
    __syncthreads();
    int cur = 0;
    for (int k0 = 0; k0 < 1024; k0 += KS * 32) {
        if (k0 + KS * 32 < 1024) stage(cur ^ 1, k0 + KS * 32);

        const int kk = ksub;
        bf16x8 a0[MTM], a1[MTM], b0[MTN], b1[MTN];
        #pragma unroll
        for (int mi = 0; mi < MTM; ++mi) {
            int lr = wr + mi * 16 + l16;
            int off = (koff ^ ((lr >> 1) & 3)) << 3;
            a0[mi] = *(const bf16x8*)&At[cur][kk][0][lr][off];
            if (alimb2) a1[mi] = *(const bf16x8*)&At[cur][kk][1][lr][off];
        }
        #pragma unroll
        for (int ni = 0; ni < MTN; ++ni) {
            int lr = wc + ni * 16 + l16;
            int off = (koff ^ ((lr >> 1) & 3)) << 3;
            b0[ni] = *(const bf16x8*)&Bt[cur][kk][0][lr][off];
            b1[ni] = *(const bf16x8*)&Bt[cur][kk][1][lr][off];
        }
        #pragma unroll
        for (int mi = 0; mi < MTM; ++mi)
            #pragma unroll
            for (int ni = 0; ni < MTN; ++ni) {
                f32x4 cc = acc[mi][ni];
                cc = __builtin_amdgcn_mfma_f32_16x16x32_bf16(a0[mi], b0[ni], cc, 0, 0, 0);
                cc = __builtin_amdgcn_mfma_f32_16x16x32_bf16(a0[mi], b1[ni], cc, 0, 0, 0);
                if (alimb2)
                    cc = __builtin_amdgcn_mfma_f32_16x16x32_bf16(a1[mi], b0[ni], cc, 0, 0, 0);
                acc[mi][ni] = cc;
            }
        __syncthreads();
        cur ^= 1;
    }

    if (KS == 2) {   // cross-ksub reduce (alias At as f32 scratch)
        float* red = (float*)&At[0][0][0][0][0];
        if (ksub == 1) {
            #pragma unroll
            for (int mi = 0; mi < MTM; ++mi)
                #pragma unroll
                for (int ni = 0; ni < MTN; ++ni)
                    *(f32x4*)&red[(((quad * MTM + mi) * MTN + ni) * 64 + lane) * 4] =
                        acc[mi][ni];
        }
        __syncthreads();
        if (ksub == 0) {
            #pragma unroll
            for (int mi = 0; mi < MTM; ++mi)
                #pragma unroll
                for (int ni = 0; ni < MTN; ++ni) {
                    f32x4 o = *(const f32x4*)
                        &red[(((quad * MTM + mi) * MTN + ni) * 64 + lane) * 4];
                    acc[mi][ni][0] += o[0]; acc[mi][ni][1] += o[1];
                    acc[mi][ni][2] += o[2]; acc[mi][ni][3] += o[3];
                }
        }
    }

    const bool tp = (PoutT != nullptr) && (row0 >= tposeN);
    float* T = (float*)&Bt[0][0][0][0][0];   // 64x65 f32, Bt dead

    if (s2) {                               // dual: pure product (+planes/T)
        if (lead) {
            #pragma unroll
            for (int mi = 0; mi < MTM; ++mi)
                #pragma unroll
                for (int r = 0; r < 4; ++r) {
                    const int gr = row0 + wr + mi * 16 + koff * 4 + r;
                    if (gr >= M) continue;
                    const int prow = gr - seg2 + p2off;
                    #pragma unroll
                    for (int ni = 0; ni < MTN; ++ni) {
                        const int gc = col0 + wc + ni * 16 + l16;
                        float pv = acc[mi][ni][r];
                        if (Pout2) {
                            long f = swz((long)prow * 1024 + gc, 10);
                            unsigned short h0 = f2bf(pv);
                            Pout2[f] = h0;
                            Pout2[ppsz2 + f] = f2bf(pv - bf2f(h0));
                        }
                        if (tp) T[(wr + mi * 16 + koff * 4 + r) * 65 + gc - col0] = pv;
                    }
                }
        }
    } else {
        if (lead) {
            const long ofe = ofb + (long)segk * ofstep;
            const long cfe = cfb + (long)segk * ofstep;
            #pragma unroll
            for (int mi = 0; mi < MTM; ++mi) {
                #pragma unroll
                for (int r = 0; r < 4; ++r) {
                    const int gr = row0 + wr + mi * 16 + koff * 4 + r;
                    if (gr >= M) continue;
                    const int trow = (((gr < segN) ? gr + zoff : gr)) & trmask;
                    if (gr < segN && trow >= segN) continue;
                    const float aa = (trow < asplit) ? alpha : alphaB;
                    const float bb = (trow < bzero) ? 0.f
                                    : ((trow < bsplit) ? beta : betaB);
                    #pragma unroll
                    for (int ni = 0; ni < MTN; ++ni) {
                        const int gc = col0 + wc + ni * 16 + l16;
                        float vp = aa * acc[mi][ni][r];
                        float v = vp;
                        if (bb != 0.f) {
                            int crow = trow & cmask;
                            if (Cf) v += bb * Cf[cfe + (long)crow * cfld + gc];
                            else if (Cp) {
                                long f = swz((long)crow * 1024 + gc, 10);
                                v += bb * (bf2f(Cp[f]) + bf2f(Cp[cpsz + f]));
                            }
                        }
                        if (add_id && gr == gc) v += 1.f;
                        if (Of) Of[ofe + (long)trow * ofld + gc] = v;
                        if (Pout && (!pstep8 || (trow & 7) == 0)) {
                            int prow = (pstep8 ? (trow >> 3) : trow) + segk * prowstep;
                            long f = swz((long)prow * 1024 + gc, 10);
                            float pv = (pmode == 2) ? vp : v;
                            unsigned short h0 = f2bf(pv);
                            Pout[f] = h0;
                            Pout[ppsz + f] = f2bf(pv - bf2f(h0));
                        }
                        if (tp) T[(wr + mi * 16 + koff * 4 + r) * 65 + gc - col0] = v;
                    }
                }
            }
        }
    }

    if (BM == 64 && tp) {                   // transposed plane emission
        __syncthreads();
        if (tid < 256) {
            const int i = tid >> 2;
            const int jb = (tid & 3) * 16;
            const int prow = col0 + i;
            #pragma unroll
            for (int e2 = 0; e2 < 16; ++e2) {
                int j = jb + e2;
                float v = T[j * 65 + i];
                long f = swz((long)prow * 1024 + (row0 - tposeN + j), 10);
                unsigned short h0 = f2bf(v);
                PoutT[f] = h0;
                PoutT[(long)(1 << 20) + f] = f2bf(v - bf2f(h0));
            }
        }
    }
}

// ---------------------------------------------------------------------------
// Fused prep: z=0 Am->PA planes; z=1 CH1 rows 0-1023 = I+(h/3)A^T;
// z=2/3 CH1 rows 1024+/1536+ = B^T/6, B^T/24; z=4 PBT = B^T; z=5 u->PU 1-limb.
// Grid (32,32,6) x 256 threads.
// ---------------------------------------------------------------------------
__global__ void prep_k(const float* __restrict__ Am, const float* __restrict__ Bm,
                       const float* __restrict__ u,
                       unsigned short* __restrict__ PA, unsigned short* __restrict__ CH1,
                       unsigned short* __restrict__ PBT, unsigned short* __restrict__ PU,
                       float h)
{
    const int z = blockIdx.z;
    const int tx = threadIdx.x & 31, ty4 = threadIdx.x >> 5;
    if (z == 0) {                          // straight split of Am
        const int r0 = blockIdx.x * 32, c0 = blockIdx.y * 32;
        #pragma unroll
        for (int i = 0; i < 4; ++i) {
            long e = (long)(r0 + ty4 * 4 + i) * 1024 + c0 + tx;
            float v = Am[e];
            long f = swz(e, 10);
            unsigned short h0 = f2bf(v);
            PA[f] = h0;
            PA[(long)(1 << 20) + f] = f2bf(v - bf2f(h0));
        }
        return;
    }
    if (z == 5) {                          // u -> 1-limb plane, grid-stride
        long base = ((long)blockIdx.y * 32 + blockIdx.x) * 256 + threadIdx.x;
        for (long i = base; i < (1L << 22); i += 262144)
            PU[swz(i, 9)] = f2bf(u[i]);
        return;
    }
    // trsp variants
    const int R = (z == 1) ? 1024 : 512;
    if (blockIdx.x * 32 >= R) return;
    const float s = (z == 1) ? h / 3.f : (z == 2) ? 1.f / 6.f
                   : (z == 3) ? 1.f / 24.f : 1.f;
    const int add_id = (z == 1) ? 1 : 0;
    const int roff = (z == 2) ? 1024 : (z == 3) ? 1536 : 0;
    unsigned short* P = (z == 4) ? PBT : CH1;
    const long psz = (z == 4) ? (long)(1 << 19) : (long)(1 << 21);
    const float* in = (z == 1) ? Am : Bm;

    __shared__ float t[32][33];
    const int r0 = blockIdx.x * 32, c0 = blockIdx.y * 32;
    #pragma unroll
    for (int i = 0; i < 4; ++i)
        t[ty4 * 4 + i][tx] = in[(long)(c0 + ty4 * 4 + i) * R + r0 + tx];
    __syncthreads();
    #pragma unroll
    for (int i = 0; i < 4; ++i) {
        int r = r0 + ty4 * 4 + i, c = c0 + tx;
        float v = s * t[tx][ty4 * 4 + i];
        if (add_id && r == c) v += 1.f;
        long f = swz((long)(r + roff) * 1024 + c, 10);
        unsigned short h0 = f2bf(v);
        P[f] = h0;
        P[psz + f] = f2bf(v - bf2f(h0));
    }
}

// ---- X (cnt fp32, rows of length 2^ldsh) -> swizzled 2-limb planes ----
__global__ void split_pl_k(const float* __restrict__ X, unsigned short* __restrict__ P,
                           long psz, int ldsh, float s, long cnt)
{
    long i = (long)blockIdx.x * 256 + threadIdx.x;
    if (i >= cnt) return;
    float v = s * X[i];
    long f = swz(i, ldsh);
    unsigned short h0 = f2bf(v);
    P[f] = h0;
    P[psz + f] = f2bf(v - bf2f(h0));
}

// ---- planes(X) from planes(X^T): OUT[c][r] = IN[irow0+r][c] ----
__global__ void tspp_k(const unsigned short* __restrict__ IN, long ipsz, long irow0,
                       unsigned short* __restrict__ OUT, long opsz)
{
    __shared__ float t[32][33];
    const int tx = threadIdx.x & 31, ty4 = threadIdx.x >> 5;
    const int r0 = blockIdx.x * 32, c0 = blockIdx.y * 32;
    #pragma unroll
    for (int i = 0; i < 4; ++i) {
        long f = swz((irow0 + r0 + ty4 * 4 + i) * 1024 + c0 + tx, 10);
        t[ty4 * 4 + i][tx] = bf2f(IN[f]) + bf2f(IN[ipsz + f]);
    }
    __syncthreads();
    #pragma unroll
    for (int i = 0; i < 4; ++i) {
        int orow = c0 + ty4 * 4 + i;
        long f = swz((long)orow * 1024 + r0 + tx, 10);
        float v = t[tx][ty4 * 4 + i];
        unsigned short h0 = f2bf(v);
        OUT[f] = h0;
        OUT[opsz + f] = f2bf(v - bf2f(h0));
    }
}

// ---- Gcat planes from stacked [V1^T; V2^T] planes ----
__global__ void gtspp_k(const unsigned short* __restrict__ PV, long vpsz,
                        unsigned short* __restrict__ PG, long gpsz, float h)
{
    __shared__ float t[32][33];
    const int tx = threadIdx.x & 31, ty4 = threadIdx.x >> 5;
    const int k0 = blockIdx.x * 32, n0 = blockIdx.y * 32, z = blockIdx.z;
    #pragma unroll
    for (int i = 0; i < 4; ++i) {
        int k = k0 + ty4 * 4 + i, n = n0 + tx;
        long f2 = swz((long)(512 + k) * 1024 + n, 10);
        float v2 = bf2f(PV[f2]) + bf2f(PV[vpsz + f2]);
        float v;
        if (z == 0) {
            long f1 = swz((long)k * 1024 + n, 10);
            v = h * (bf2f(PV[f1]) + bf2f(PV[vpsz + f1]) - v2);
        } else v = h * v2;
        t[ty4 * 4 + i][tx] = v;
    }
    __syncthreads();
    #pragma unroll
    for (int i = 0; i < 4; ++i) {
        int n = n0 + ty4 * 4 + i, kk = z * 512 + k0 + tx;
        long f = swz((long)n * 1024 + kk, 10);
        float v = t[tx][ty4 * 4 + i];
        unsigned short h0 = f2bf(v);
        PG[f] = h0;
        PG[gpsz + f] = f2bf(v - bf2f(h0));
    }
}

// dst[db + r*ds + c] = src[sb + r*ss + c]
__global__ void copy_rows_k(float* __restrict__ dst, long db, long ds,
                            const float* __restrict__ src, long sb, long ss, int ncols)
{
    int r = blockIdx.y;
    int c = blockIdx.x * 256 + threadIdx.x;
    if (c < ncols) dst[db + (long)r * ds + c] = src[sb + (long)r * ss + c];
}

// dst[db + r*ds + c] += src[r*ncols + c]
__global__ void add_rows_k(float* __restrict__ dst, long db, long ds,
                           const float* __restrict__ src, int ncols)
{
    int r = blockIdx.y;
    int c = blockIdx.x * 256 + threadIdx.x;
    if (c < ncols) dst[db + (long)r * ds + c] += src[(long)r * ncols + c];
}

__global__ void scale_add_id_k(float* __restrict__ dst, const float* __restrict__ src,
                               float s, int n)
{
    int r = blockIdx.y;
    int c = blockIdx.x * 256 + threadIdx.x;
    if (c < n) dst[(long)r * n + c] = s * src[(long)r * n + c] + ((r == c) ? 1.f : 0.f);
}

__global__ void scale_copy_k(float* __restrict__ dst, const float* __restrict__ src,
                             float s, long cnt)
{
    long i = (long)blockIdx.x * 256 + threadIdx.x;
    if (i < cnt) dst[i] = s * src[i];
}

__global__ void g1g2_k(float* __restrict__ g1, float* __restrict__ g2,
                       const float* __restrict__ v1, const float* __restrict__ v2,
                       float h, long cnt)
{
    long i = (long)blockIdx.x * 256 + threadIdx.x;
    if (i < cnt) {
        float a = v1[i], b = v2[i];
        g1[i] = h * (a - b);
        g2[i] = h * b;
    }
}

// ---------------------------------------------------------------------------
// FALLBACK (round-3, 3-limb, 30 MB ws) — only if ws_size < 46 MB.
// ---------------------------------------------------------------------------
template <int BM, int BN, bool TRANSB>
__global__ __launch_bounds__(256) void gemm_mfma(
    const float* __restrict__ A, long ab, long lda,
    const float* __restrict__ B,
    const float* __restrict__ Cin, long cb, long ldc, float beta,
    float* __restrict__ Out, long ob, long ldo,
    int M, int Nn, int K, float alpha, int add_id)
{
    constexpr int LDT = 40;
    __shared__ unsigned short At[3][BM][LDT];
    __shared__ unsigned short Bt[3][BN][LDT];
    const int tid = threadIdx.x;
    const int lane = tid & 63;
    const int wid = tid >> 6;
    const int row0 = blockIdx.x * BM;
    const int col0 = blockIdx.y * BN;
    constexpr int MR = BM / 32;
    constexpr int NR = BN / 32;
    const int wrow = (wid >> 1) * (BM / 2);
    const int wcol = (wid & 1) * (BN / 2);
    const int l16 = lane & 15;
    const int koff = lane >> 4;
    f32x4 acc[MR][NR] = {};

    for (int k0 = 0; k0 < K; k0 += 32) {
        #pragma unroll
        for (int i = 0; i < BM / 32; ++i) {
            int r = i * 32 + (tid >> 3);
            int kl = (tid & 7) * 4;
            int gr = row0 + r;
            float4 v = make_float4(0.f, 0.f, 0.f, 0.f);
            if (gr < M) v = *(const float4*)&A[ab + (long)gr * lda + (k0 + kl)];
            unsigned short h0[4], h1[4], h2[4];
            split3(v.x, h0[0], h1[0], h2[0]);
            split3(v.y, h0[1], h1[1], h2[1]);
            split3(v.z, h0[2], h1[2], h2[2]);
            split3(v.w, h0[3], h1[3], h2[3]);
            *(ushort4*)&At[0][r][kl] = make_ushort4(h0[0], h0[1], h0[2], h0[3]);
            *(ushort4*)&At[1][r][kl] = make_ushort4(h1[0], h1[1], h1[2], h1[3]);
            *(ushort4*)&At[2][r][kl] = make_ushort4(h2[0], h2[1], h2[2], h2[3]);
        }
        if (TRANSB) {
            #pragma unroll
            for (int i = 0; i < BN / 32; ++i) {
                int r = i * 32 + (tid >> 3);
                int kl = (tid & 7) * 4;
                float4 v = *(const float4*)&B[(long)(col0 + r) * K + (k0 + kl)];
                unsigned short h0[4], h1[4], h2[4];
                split3(v.x, h0[0], h1[0], h2[0]);
                split3(v.y, h0[1], h1[1], h2[1]);
                split3(v.z, h0[2], h1[2], h2[2]);
                split3(v.w, h0[3], h1[3], h2[3]);
                *(ushort4*)&Bt[0][r][kl] = make_ushort4(h0[0], h0[1], h0[2], h0[3]);
                *(ushort4*)&Bt[1][r][kl] = make_ushort4(h1[0], h1[1], h1[2], h1[3]);
                *(ushort4*)&Bt[2][r][kl] = make_ushort4(h2[0], h2[1], h2[2], h2[3]);
            }
        } else {
            constexpr int TPK = BN / 4;
            #pragma unroll
            for (int i = 0; i < BN / 32; ++i) {
                int kl = i * (256 / TPK) + tid / TPK;
                int nl = (tid % TPK) * 4;
                float4 v = *(const float4*)&B[(long)(k0 + kl) * Nn + (col0 + nl)];
                unsigned short s0, s1, s2;
                split3(v.x, s0, s1, s2);
                Bt[0][nl + 0][kl] = s0; Bt[1][nl + 0][kl] = s1; Bt[2][nl + 0][kl] = s2;
                split3(v.y, s0, s1, s2);
                Bt[0][nl + 1][kl] = s0; Bt[1][nl + 1][kl] = s1; Bt[2][nl + 1][kl] = s2;
                split3(v.z, s0, s1, s2);
                Bt[0][nl + 2][kl] = s0; Bt[1][nl + 2][kl] = s1; Bt[2][nl + 2][kl] = s2;
                split3(v.w, s0, s1, s2);
                Bt[0][nl + 3][kl] = s0; Bt[1][nl + 3][kl] = s1; Bt[2][nl + 3][kl] = s2;
            }
        }
        __syncthreads();
        bf16x8 bf[NR][3];
        #pragma unroll
        for (int nr = 0; nr < NR; ++nr) {
            int brow = wcol + nr * 16 + l16;
            #pragma unroll
            for (int s = 0; s < 3; ++s)
                bf[nr][s] = *(const bf16x8*)&Bt[s][brow][koff * 8];
        }
        #pragma unroll
        for (int mr = 0; mr < MR; ++mr) {
            int arow = wrow + mr * 16 + l16;
            bf16x8 a0 = *(const bf16x8*)&At[0][arow][koff * 8];
            bf16x8 a1 = *(const bf16x8*)&At[1][arow][koff * 8];
            bf16x8 a2 = *(const bf16x8*)&At[2][arow][koff * 8];
            #pragma unroll
            for (int nr = 0; nr < NR; ++nr) {
                f32x4 c = acc[mr][nr];
                c = __builtin_amdgcn_mfma_f32_16x16x32_bf16(a0, bf[nr][0], c, 0, 0, 0);
                c = __builtin_amdgcn_mfma_f32_16x16x32_bf16(a0, bf[nr][1], c, 0, 0, 0);
                c = __builtin_amdgcn_mfma_f32_16x16x32_bf16(a1, bf[nr][0], c, 0, 0, 0);
                c = __builtin_amdgcn_mfma_f32_16x16x32_bf16(a0, bf[nr][2], c, 0, 0, 0);
                c = __builtin_amdgcn_mfma_f32_16x16x32_bf16(a1, bf[nr][1], c, 0, 0, 0);
                c = __builtin_amdgcn_mfma_f32_16x16x32_bf16(a2, bf[nr][0], c, 0, 0, 0);
                acc[mr][nr] = c;
            }
        }
        __syncthreads();
    }
    #pragma unroll
    for (int mr = 0; mr < MR; ++mr) {
        #pragma unroll
        for (int r = 0; r < 4; ++r) {
            int gr = row0 + wrow + mr * 16 + koff * 4 + r;
            if (gr >= M) continue;
            #pragma unroll
            for (int nr = 0; nr < NR; ++nr) {
                int gc = col0 + wcol + nr * 16 + l16;
                float v = alpha * acc[mr][nr][r];
                if (Cin) v += beta * Cin[cb + (long)gr * ldc + gc];
                if (add_id && gr == gc) v += 1.f;
                Out[ob + (long)gr * ldo + gc] = v;
            }
        }
    }
}

static void fallback_launch(void* const* d_in, void* d_out, void* d_ws,
                            hipStream_t stream)
{
    const float* y0 = (const float*)d_in[1];
    const float* u  = (const float*)d_in[2];
    const float* Am = (const float*)d_in[3];
    const float* Bm = (const float*)d_in[4];
    float* Yout = (float*)d_out;
    float* w = (float*)d_ws;
    const float h = 0.01f;
    const int N = GN;

    float* Eyy = w;
    float* T1  = Eyy + (long)N * N;
    float* T2  = T1  + (long)N * N;
    float* V1  = T2  + (long)N * N;
    float* Vt  = V1  + (long)N * GM;
    float* V2  = Vt  + (long)N * GM;
    float* G1  = V2  + (long)N * GM;
    float* G2  = G1  + (long)N * GM;
    float* Z   = G2  + (long)N * GM;
    float* Zt  = Z   + (long)CCH * N;
    dim3 blk(256);

    auto gemm = [&](bool transb, const float* A, long ab, long lda,
                    const float* B, const float* Cin, long cb, long ldc, float beta,
                    float* Out, long ob, long ldo,
                    int M, int Nn, int K, float alpha, int add_id) {
        if (M > 1536 && (Nn % 128) == 0) {
            dim3 grid((M + 127) / 128, Nn / 128);
            if (transb)
                gemm_mfma<128, 128, true><<<grid, blk, 0, stream>>>(A, ab, lda, B, Cin, cb, ldc, beta, Out, ob, ldo, M, Nn, K, alpha, add_id);
            else
                gemm_mfma<128, 128, false><<<grid, blk, 0, stream>>>(A, ab, lda, B, Cin, cb, ldc, beta, Out, ob, ldo, M, Nn, K, alpha, add_id);
        } else {
            dim3 grid((M + 63) / 64, Nn / 64);
            if (transb)
                gemm_mfma<64, 64, true><<<grid, blk, 0, stream>>>(A, ab, lda, B, Cin, cb, ldc, beta, Out, ob, ldo, M, Nn, K, alpha, add_id);
            else
                gemm_mfma<64, 64, false><<<grid, blk, 0, stream>>>(A, ab, lda, B, Cin, cb, ldc, beta, Out, ob, ldo, M, Nn, K, alpha, add_id);
        }
    };

    scale_add_id_k<<<dim3(4, N), blk, 0, stream>>>(T1, Am, h / 5.f, N);
    {
        float* pc = T1; float* pn = T2;
        for (int k = 4; k >= 1; --k) {
            float* out = (k == 1) ? Eyy : pn;
            gemm(false, Am, 0, N, pc, nullptr, 0, 0, 0.f, out, 0, N, N, N, N, h / (float)k, 1);
            pn = pc; pc = out;
        }
    }
    const long NM = (long)N * GM;
    scale_copy_k<<<dim3((unsigned)((NM + 255) / 256)), blk, 0, stream>>>(V1, Bm, 1.f / 120.f, NM);
    {
        const float f1[4] = {1.f / 24.f, 1.f / 6.f, 0.5f, 1.f};
        float* pc = V1; float* pn = Vt;
        for (int j = 3; j >= 0; --j) {
            gemm(false, Am, 0, N, pc, Bm, 0, GM, f1[3 - j], pn, 0, GM, N, GM, N, h, 0);
            float* t = pc; pc = pn; pn = t;
        }
    }
    scale_copy_k<<<dim3((unsigned)((NM + 255) / 256)), blk, 0, stream>>>(V2, Bm, 1.f / 720.f, NM);
    {
        const float f2[4] = {1.f / 120.f, 1.f / 24.f, 1.f / 6.f, 0.5f};
        float* pc = V2; float* pn = Vt;
        for (int j = 3; j >= 0; --j) {
            gemm(false, Am, 0, N, pc, Bm, 0, GM, f2[3 - j], pn, 0, GM, N, GM, N, h, 0);
            float* t = pc; pc = pn; pn = t;
        }
    }
    g1g2_k<<<dim3((unsigned)((NM + 255) / 256)), blk, 0, stream>>>(G1, G2, V1, V2, h, NM);
    gemm(true, u, 0, GM, G1, nullptr, 0, 0, 0.f, Yout, (long)N, N, GT - 1, N, GM, 1.f, 0);
    gemm(true, u, GM, GM, G2, Yout, (long)N, N, 1.f, Yout, (long)N, N, GT - 1, N, GM, 1.f, 0);
    copy_rows_k<<<dim3(4, 1), blk, 0, stream>>>(Yout, 0, 0, y0, 0, 0, N);
    for (int s = 2; s <= SCH; ++s) {
        int Mr = (GT - 1 - s) / SCH + 1;
        gemm(true, Yout, (long)(s - 1) * N, (long)SCH * N, Eyy,
             Yout, (long)s * N, (long)SCH * N, 1.f,
             Yout, (long)s * N, (long)SCH * N, Mr, N, N, 1.f, 0);
    }
    copy_rows_k<<<dim3(4, 1), blk, 0, stream>>>(Z, 0, 0, y0, 0, 0, N);
    copy_rows_k<<<dim3(4, CCH - 1), blk, 0, stream>>>(Z, (long)N, (long)N,
                                                      Yout, (long)SCH * N, (long)SCH * N, N);
    gemm(false, Eyy, 0, N, Eyy, nullptr, 0, 0, 0.f, T1, 0, N, N, N, N, 1.f, 0);
    gemm(false, T1, 0, N, T1, nullptr, 0, 0, 0.f, T2, 0, N, N, N, N, 1.f, 0);
    gemm(false, T2, 0, N, T2, nullptr, 0, 0, 0.f, T1, 0, N, N, N, N, 1.f, 0);
    {
        float* Mc = T1; float* Mo = T2;
        float* Zc = Z;  float* Zn = Zt;
        for (int p = 0; p < 10; ++p) {
            int o = 1 << p;
            gemm(true, Zc, 0, N, Mc, Zc, (long)o * N, N, 1.f,
                 Zn, (long)o * N, N, CCH - o, N, N, 1.f, 0);
            copy_rows_k<<<dim3(4, o), blk, 0, stream>>>(Zn, 0, N, Zc, 0, N, N);
            if (p < 9) {
                gemm(false, Mc, 0, N, Mc, nullptr, 0, 0, 0.f, Mo, 0, N, N, N, N, 1.f, 0);
                float* t = Mc; Mc = Mo; Mo = t;
            }
            float* t = Zc; Zc = Zn; Zn = t;
        }
        copy_rows_k<<<dim3(4, CCH), blk, 0, stream>>>(Yout, 0, (long)SCH * N, Zc, 0, N, N);
        float* Q = Zc; float* Qt = Zn;
        for (int s = 1; s <= SCH - 1; ++s) {
            gemm(true, Q, 0, N, Eyy, nullptr, 0, 0, 0.f, Qt, 0, N, CCH, N, N, 1.f, 0);
            int Mr = (GT - 1 - s) / SCH + 1;
            add_rows_k<<<dim3(4, Mr), blk, 0, stream>>>(Yout, (long)s * N, (long)SCH * N, Qt, N);
            float* t = Q; Q = Qt; Qt = t;
        }
    }
}

// ---------------------------------------------------------------------------
extern "C" void kernel_launch(void* const* d_in, const int* in_sizes, int n_in,
                              void* d_out, int out_size, void* d_ws, size_t ws_size,
                              hipStream_t stream)
{
    (void)in_sizes; (void)n_in; (void)out_size;
    const size_t NEED = 46ull * 1024 * 1024;
    if (ws_size < NEED) { fallback_launch(d_in, d_out, d_ws, stream); return; }

    const float* y0 = (const float*)d_in[1];
    const float* u  = (const float*)d_in[2];
    const float* Am = (const float*)d_in[3];
    const float* Bm = (const float*)d_in[4];
    float* Yout = (float*)d_out;
    char* w = (char*)d_ws;
    const float h = 0.01f;
    const size_t MB = 1024 * 1024;
    const long PP  = 1 << 20;
    const long P2  = 1 << 21;
    const long P4  = 1 << 22;
    const int  BIG = 1 << 30;

    // ws layout (46 MB, time-phased):
    unsigned short* PU   = (unsigned short*)(w);            // [0,8)   u 1-limb plane
    unsigned short* PZW1 = (unsigned short*)(w);            // [0,8)   z+W^T ping
    unsigned short* PA   = (unsigned short*)(w + 8 * MB);   // [8,12)  planes(Am)
    unsigned short* SQa  = (unsigned short*)(w + 8 * MB);   // [8,12)  E^2T
    unsigned short* SQb  = (unsigned short*)(w + 12 * MB);  // [12,16) E^4T
    unsigned short* PZW2 = (unsigned short*)(w + 8 * MB);   // [8,16)  z pong
    unsigned short* CH1  = (unsigned short*)(w + 16 * MB);  // [16,24) chain ping
    unsigned short* WA   = (unsigned short*)(w + 16 * MB);  // [16,20) w-slot / PWt pong
    unsigned short* PWt0 = (unsigned short*)(w + 20 * MB);  // [20,24) E^8 planes / PWt ping
    unsigned short* CH2  = (unsigned short*)(w + 24 * MB);  // [24,32) chain pong
    unsigned short* WB   = (unsigned short*)(w + 24 * MB);  // [24,28) w-slot
    unsigned short* PE   = (unsigned short*)(w + 28 * MB);  // [28,32) planes(E) = PWR+0
    unsigned short* PG   = (unsigned short*)(w + 32 * MB);  // [32,36) Gcat -> E^2
    unsigned short* PW2  = PG;
    unsigned short* PW3  = (unsigned short*)(w + 36 * MB);  // [36,40) w2 -> planes(E^3)
    unsigned short* PW4  = (unsigned short*)(w + 40 * MB);  // [40,44) planes(E^4)
    unsigned short* PBT  = (unsigned short*)(w + 44 * MB);  // [44,46) planes(B^T)
    unsigned short* QPL  = (unsigned short*)(w + 8 * MB);   // [8,24)  Q planes (phase3)
    unsigned short* PWR  = PE;                              // powers table base

    dim3 blk(256), blk5(512);

    // ---- 1. fused prep: Am planes, chain seeds, B^T planes, u plane ----
    prep_k<<<dim3(32, 32, 6), blk, 0, stream>>>(Am, Bm, u, PA, CH1, PBT, PU, h);

    // ---- 2. fused chain x2: exp deg-3 (rows<1024) + phi 3-term (rows 1024+) ----
    {
        const float alE[2] = {h / 2.f, h};
        const float f1[2] = {0.5f, 1.f};
        const float f2[2] = {1.f / 6.f, 0.5f};
        unsigned short* cc = CH1; unsigned short* cn = CH2;
        for (int j = 0; j < 2; ++j) {
            gemm_pp<64, 2, 2><<<dim3(32, 16), blk5, 0, stream>>>(
                cc, P2, 1024, 10, 1, -1, 0, 0,
                PA, PP, 0,
                nullptr, 0, 0, PBT, (long)(1 << 19), 511,
                1024, 1536, f1[j], f2[j],
                nullptr, 0, 0, 0,
                cn, P2, 0, 1, 0,
                BIG, 0, -1,
                2048, alE[j], h, 1024, 1,
                nullptr, 0, nullptr, nullptr, 0, 0, BIG, nullptr, BIG, 0);
            unsigned short* t = cc; cc = cn; cn = t;
        }  // 2 swaps -> final in CH1
    }
    tspp_k<<<dim3(32, 32), blk, 0, stream>>>(CH1, P2, 0, PE, PP);
    gtspp_k<<<dim3(16, 32, 2), blk, 0, stream>>>(CH1 + (1 << 20), P2, PG, PP, h);

    // ---- 3. c-staging (A 1-limb): Yout[t] = [u_{t-1}|u_t]@Gcat^T
    //      + w1 planes (rows 8i+1) -> WB ----
    gemm_pp<128, 4, 1><<<dim3(64, 8), blk5, 0, stream>>>(
        PU, 0, 512, 9, 0, -1, 0, 0,
        PG, PP, 0,
        nullptr, 0, 0, nullptr, 0, -1,
        0, BIG, 0.f, 0.f,
        Yout, 1024, 1024, 0,
        WB, PP, 1, 1, 0,
        BIG, 0, -1,
        GT - 1, 1.f, 1.f, BIG, 0,
        nullptr, 0, nullptr, nullptr, 0, 0, BIG, nullptr, BIG, 0);

    // ---- 4. phase 1 (serial s=2..8) fused with E-squarings + E^3 power ----
    // F1: s=2 | dual: E^2T = E^T@planes(E) -> SQa ; PoutT: planes(E^2) -> PW2
    gemm_pp<64, 2, 2><<<dim3(32, 16), blk5, 0, stream>>>(
        WB, PP, 1024, 10, 1, -1, 0, 0,
        PE, PP, 0,
        Yout, 2 * 1024, 8192, nullptr, 0, -1,
        0, BIG, 1.f, 0.f,
        Yout, 2 * 1024, 8192, 0,
        PW3, PP, 0, 1, 0,                       // w2 planes -> PW3 region
        BIG, 0, -1,
        2048, 1.f, 1.f, BIG, 0,
        CH1, P2, PE, SQa, PP, 0, 1024, PW2, 1024, 0);
    // F2: s=3 | dual: E^4T = E^2T@planes(E^2) -> SQb ; PoutT: planes(E^4) -> PW4
    gemm_pp<64, 2, 2><<<dim3(32, 16), blk5, 0, stream>>>(
        PW3, PP, 1024, 10, 1, -1, 0, 0,
        PE, PP, 0,
        Yout, 3 * 1024, 8192, nullptr, 0, -1,
        0, BIG, 1.f, 0.f,
        Yout, 3 * 1024, 8192, 0,
        WB, PP, 0, 1, 0,                        // w3 -> WB
        BIG, 0, -1,
        2048, 1.f, 1.f, BIG, 0,
        SQa, PP, PW2, SQb, PP, 0, 1024, PW4, 1024, 0);
    // F3: s=4 | dual: E^8T -> PZW1 rows 1024+ ; PoutT: planes(E^8) -> PWt0
    gemm_pp<64, 2, 2><<<dim3(32, 16), blk5, 0, stream>>>(
        WB, PP, 1024, 10, 1, -1, 0, 0,
        PE, PP, 0,
        Yout, 4 * 1024, 8192, nullptr, 0, -1,
        0, BIG, 1.f, 0.f,
        Yout, 4 * 1024, 8192, 0,
        WA, PP, 0, 1, 0,                        // w4 -> WA
        BIG, 0, -1,
        2048, 1.f, 1.f, BIG, 0,
        SQb, PP, PW4, PZW1, P2, 1024, 1024, PWt0, 1024, 0);
    // s=5 | dual: E^3T = E^2T@planes(E) ; PoutT: planes(E^3) -> PW3
    gemm_pp<64, 2, 2><<<dim3(32, 16), blk5, 0, stream>>>(
        WA, PP, 1024, 10, 1, -1, 0, 0,
        PE, PP, 0,
        Yout, 5 * 1024, 8192, nullptr, 0, -1,
        0, BIG, 1.f, 0.f,
        Yout, 5 * 1024, 8192, 0,
        WB, PP, 0, 1, 0,                        // w5 -> WB
        BIG, 0, -1,
        2048, 1.f, 1.f, BIG, 0,
        SQa, PP, PE, nullptr, 0, 0, 1024, PW3, 1024, 0);
    // s=6, s=7 solo
    gemm_pp<64, 2, 2><<<dim3(16, 16), blk5, 0, stream>>>(
        WB, PP, 1024, 10, 1, -1, 0, 0,
        PE, PP, 0,
        Yout, 6 * 1024, 8192, nullptr, 0, -1,
        0, BIG, 1.f, 0.f,
        Yout, 6 * 1024, 8192, 0,
        WA, PP, 0, 1, 0,
        BIG, 0, -1,
        1024, 1.f, 1.f, BIG, 0,
        nullptr, 0, nullptr, nullptr, 0, 0, BIG, nullptr, BIG, 0);
    gemm_pp<64, 2, 2><<<dim3(16, 16), blk5, 0, stream>>>(
        WA, PP, 1024, 10, 1, -1, 0, 0,
        PE, PP, 0,
        Yout, 7 * 1024, 8192, nullptr, 0, -1,
        0, BIG, 1.f, 0.f,
        Yout, 7 * 1024, 8192, 0,
        WB, PP, 0, 1, 0,
        BIG, 0, -1,
        1024, 1.f, 1.f, BIG, 0,
        nullptr, 0, nullptr, nullptr, 0, 0, BIG, nullptr, BIG, 0);
    // s=8 -> boundary rows 8(i+1): z planes -> PZW1 rows 1..1023 (zoff=1)
    gemm_pp<64, 2, 2><<<dim3(16, 16), blk5, 0, stream>>>(
        WB, PP, 1024, 10, 1, -1, 0, 0,
        PE, PP, 0,
        Yout, 0, 8192, nullptr, 0, -1,
        0, BIG, 1.f, 0.f,
        Yout, 0, 8192, 0,
        PZW1, P2, 0, 1, 0,
        BIG, 1, -1,
        1023, 1.f, 1.f, BIG, 0,
        nullptr, 0, nullptr, nullptr, 0, 0, BIG, nullptr, BIG, 0);
    // z_0 = y0 -> PZW1 plane row 0
    split_pl_k<<<dim3(4), blk, 0, stream>>>(y0, PZW1, P2, 10, 1.f, 1024);

    // ---- 5. fused doubling: one GEMM per round, W-transpose in epilogue ----
    {
        unsigned short* PZc = PZW1; unsigned short* PZn = PZW2;
        for (int p = 0; p < 10; ++p) {
            int o = 1 << p;
            int Mr = (p == 9) ? 1024 : 2048;
            unsigned short* PWc = (p & 1) ? WA : PWt0;
            unsigned short* PWn = (p & 1) ? PWt0 : WA;
            gemm_pp<64, 2, 2><<<dim3(Mr / 64, 16), blk5, 0, stream>>>(
                PZc, P2, 1024, 10, 1, -1, o, 1024,
                PWc, PP, 0,
                nullptr, 0, 0,
                PZc, P2, 0x7fffffff,
                0, 1024, 1.f, 0.f,
                (p == 9) ? Yout : nullptr, 0, 8192, 0,
                PZn, P2, 0, 1, 0,
                1024, 0, -1,
                Mr, 0.f, 1.f, o, 0,
                nullptr, 0, nullptr, nullptr, 0, 0, BIG,
                (p < 9) ? PWn : nullptr, 1024, 0);
            unsigned short* t = PZc; PZc = PZn; PZn = t;
        }  // final Z planes in PZW1; Yout[8i] = z_i written at p=9 (incl. row 0)
    }

    // ---- 6. phase 3 via powers: L1 [Q1..Q4]=Z@[E..E^4]^T (XCD seg-swizzled);
    //      L2 [Q5..Q7]=[Q1..Q3]@E^4T ----
    gemm_pp<64, 2, 2><<<dim3(64, 16), blk5, 0, stream>>>(
        PZW1, P2, 1024, 10, 1, 1023, 0, 0,      // A row = gr & 1023 (Z)
        PWR, PP, (long)(1 << 21),               // B = powers[row0>>10]
        Yout, 1024, 8192, nullptr, 0, -1,
        0, BIG, 1.f, 0.f,
        Yout, 1024, 8192, 1024,                 // s = 1 + segk
        QPL, P4, 0, 2, 1024,                    // Q planes row = gr, pure product
        0, 0, 1023,
        4096, 1.f, 1.f, BIG, 0,
        nullptr, 0, nullptr, nullptr, 0, 0, BIG, nullptr, BIG, 4);
    gemm_pp<64, 2, 2><<<dim3(48, 16), blk5, 0, stream>>>(
        QPL, P4, 1024, 10, 1, -1, 0, 0,         // A row = gr (Q1..Q3)
        PW4, PP, 0,
        Yout, 5 * 1024, 8192, nullptr, 0, -1,
        0, BIG, 1.f, 0.f,
        Yout, 5 * 1024, 8192, 1024,             // s = 5 + segk
        nullptr, 0, 0, 1, 0,
        0, 0, 1023,
        3072, 1.f, 1.f, BIG, 0,
        nullptr, 0, nullptr, nullptr, 0, 0, BIG, nullptr, BIG, 0);
}

// Round 13
// 686.681 us; speedup vs baseline: 2.2442x; 1.0054x over previous
//
#include <hip/hip_runtime.h>

// Problem constants (fixed in the reference file)
#define GT 8192      // time steps
#define GN 1024      // state dim
#define GM 512       // input dim
#define CCH 1024     // scan chunks
#define SCH 8        // steps per chunk

typedef __attribute__((ext_vector_type(8))) short bf16x8;
typedef __attribute__((ext_vector_type(4))) float f32x4;

__device__ __forceinline__ unsigned short f2bf(float x) {   // RNE fp32->bf16
    unsigned int u = __float_as_uint(x);
    u += 0x7FFF + ((u >> 16) & 1);
    return (unsigned short)(u >> 16);
}
__device__ __forceinline__ float bf2f(unsigned short b) {
    return __uint_as_float(((unsigned int)b) << 16);
}
__device__ __forceinline__ void split2(float x, unsigned short& h0, unsigned short& h1) {
    h0 = f2bf(x);
    h1 = f2bf(x - bf2f(h0));
}
__device__ __forceinline__ void split3(float x, unsigned short& s0,
                                       unsigned short& s1, unsigned short& s2) {
    s0 = f2bf(x); float r = x - bf2f(s0);
    s1 = f2bf(r); r -= bf2f(s1);
    s2 = f2bf(r);
}
// storage swizzle: XOR element bits 3-4 with (row>>1)&3 (row = e>>sh). Involution.
__device__ __forceinline__ long swz(long e, int sh) {
    return e ^ (((e >> (sh + 1)) & 3) << 3);
}
// async 16B global->LDS (dest wave-uniform base; HW scatters lane*16; src per-lane)
__device__ __forceinline__ void gl16(const unsigned short* g, unsigned short* l) {
    __builtin_amdgcn_global_load_lds(
        (const __attribute__((address_space(1))) unsigned int*)g,
        (__attribute__((address_space(3))) unsigned int*)l, 16, 0, 0);
}

// ---------------------------------------------------------------------------
// Plane x plane GEMM; 512 threads = 8 waves = (2 x WN quads) x KS k-groups.
// KS=2: waves 0-3 / 4-7 split the 64-k step; f32 LDS reduce at end.
// Out = aa * A @ B^T (+ bb*Cin) (+I), K=1024, N=1024, 2-limb bf16 planes,
// 3 limb products (2 if a2limb==0: A is single-limb bf16).
// A element (r,k) at swz(r*alda+k, aldsh), limb1 +apsz.
// A row: ar = (row0+lr)&amask, then if ar<ashiftN: ar = max(ar-ashift,0).
// B base += (row0>>10)*bstride (power-table select); limb1 at +bpsz.
// trow = (((gr<segN)? gr+zoff : gr)) & trmask.
// aa = trow<asplit? alpha:alphaB; bb = trow<bzero? 0 : (trow<bsplit? beta:betaB).
// Of addr = ofb + (row0>>10)*ofstep + trow*ofld; Cin likewise (shared ofstep).
// Pout row = (pstep8? trow>>3 : trow) + (row0>>10)*prowstep; pmode 1=v, 2=aa*acc;
// emitted only while segk < pseglim.
// DUAL (Ap2 set): blocks row0>=seg2 compute Ap2@Bp2^T pure (A row gr-seg2),
//   planes -> Pout2 (nullable) row gr-seg2+p2off (stride ppsz2). Always 2-limb.
// TRANSPOSE (PoutT set, BM==64): blocks row0>=tposeN also emit transposed tile
//   planes to PoutT (limb stride 1M): PoutT[col0+i][row0-tposeN+j].
// segswz > 0: remap blockIdx.x so XCD (flat%8) clusters by segk.
// ---------------------------------------------------------------------------
template <int BM, int WN, int KS>
__global__ __launch_bounds__(512) void gemm_pp(
    const unsigned short* __restrict__ Ap, long apsz, int alda, int aldsh, int a2limb,
    int amask, int ashift, int ashiftN,
    const unsigned short* __restrict__ Bp, long bpsz, long bstride,
    const float* __restrict__ Cf, long cfb, long cfld,
    const unsigned short* __restrict__ Cp, long cpsz, int cmask,
    int bzero, int bsplit, float beta, float betaB,
    float* __restrict__ Of, long ofb, long ofld, long ofstep,
    unsigned short* __restrict__ Pout, long ppsz, int pstep8, int pmode, int prowstep,
    int pseglim,
    int segN, int zoff, int trmask,
    int M, float alpha, float alphaB, int asplit, int add_id,
    const unsigned short* __restrict__ Ap2, long apsz2,
    const unsigned short* __restrict__ Bp2,
    unsigned short* __restrict__ Pout2, long ppsz2, int p2off, int seg2,
    unsigned short* __restrict__ PoutT, int tposeN, int segswz)
{
    constexpr int NQ = 2 * WN;             // output quads
    constexpr int MTM = BM / 32;           // 16-tiles in M per wave
    constexpr int MTN = BM / (WN * 16);    // 16-tiles in N per wave
    constexpr int CPW = KS * BM / 32;      // staging chunks per wave
    __shared__ __align__(16) unsigned short At[2][KS][2][BM][32];
    __shared__ __align__(16) unsigned short Bt[2][KS][2][BM][32];

    const int tid = threadIdx.x;
    const int lane = tid & 63;
    const int w = tid >> 6;
    const int ksub = w / NQ;
    const int quad = w % NQ;
    const int wr = (quad / WN) * (BM / 2);
    const int wc = (quad % WN) * (BM / WN);
    const int l16 = lane & 15, koff = lane >> 4;
    int bx = blockIdx.x;
    if (segswz > 0) bx = (bx % segswz) * ((int)gridDim.x / segswz) + bx / segswz;
    const int row0 = bx * BM;
    const int col0 = blockIdx.y * BM;
    const int lr4 = lane >> 2;
    const int lg = lane & 3;
    const bool s2 = (Ap2 != nullptr) && (row0 >= seg2);
    const bool lead = (KS == 1) || (ksub == 0);
    const int segk = row0 >> 10;
    const bool alimb2 = a2limb || s2;

    f32x4 acc[MTM][MTN] = {};

    auto stage = [&](int bsel, int k0) {
        #pragma unroll
        for (int ci = 0; ci < CPW; ++ci) {
            const int c = w * CPW + ci;
            const int op = c / (KS * BM / 8);
            const int rem = c % (KS * BM / 8);
            const int limb = rem / (KS * BM / 16);
            const int rem2 = rem % (KS * BM / 16);
            const int kk = rem2 / (BM / 16);
            const int rb = (rem2 % (BM / 16)) * 16;
            const int lr = rb + lr4;
            const int q = lg ^ ((lr >> 1) & 3);
            if (op == 0 && limb == 1 && !alimb2) continue;   // 1-limb A
            long e; int sh; const unsigned short* base;
            if (op == 0) {
                if (!s2) {
                    int ar = (row0 + lr) & amask;
                    if (ar < ashiftN) { ar -= ashift; if (ar < 0) ar = 0; }
                    e = (long)ar * alda + k0 + kk * 32 + (q << 3); sh = aldsh;
                    base = Ap + (limb ? apsz : 0);
                } else {
                    e = (long)(row0 - seg2 + lr) * 1024 + k0 + kk * 32 + (q << 3); sh = 10;
                    base = Ap2 + (limb ? apsz2 : 0);
                }
            } else {
                e = (long)(col0 + lr) * 1024 + k0 + kk * 32 + (q << 3); sh = 10;
                base = (s2 ? Bp2 : (Bp + (long)segk * bstride)) + (limb ? bpsz : 0);
            }
            long f = swz(e, sh);
            unsigned short* l = (op == 0 ? &At[bsel][kk][limb][rb][0]
                                         : &Bt[bsel][kk][limb][rb][0]);
            gl16(base + f, l);
        }
    };

    stage(0, 0);
    __syncthreads();
    int cur = 0;
    for (int k0 = 0; k0 < 1024; k0 += KS * 32) {
        if (k0 + KS * 32 < 1024) stage(cur ^ 1, k0 + KS * 32);

        const int kk = ksub;
        bf16x8 a0[MTM], a1[MTM], b0[MTN], b1[MTN];
        #pragma unroll
        for (int mi = 0; mi < MTM; ++mi) {
            int lr = wr + mi * 16 + l16;
            int off = (koff ^ ((lr >> 1) & 3)) << 3;
            a0[mi] = *(const bf16x8*)&At[cur][kk][0][lr][off];
            if (alimb2) a1[mi] = *(const bf16x8*)&At[cur][kk][1][lr][off];
        }
        #pragma unroll
        for (int ni = 0; ni < MTN; ++ni) {
            int lr = wc + ni * 16 + l16;
            int off = (koff ^ ((lr >> 1) & 3)) << 3;
            b0[ni] = *(const bf16x8*)&Bt[cur][kk][0][lr][off];
            b1[ni] = *(const bf16x8*)&Bt[cur][kk][1][lr][off];
        }
        #pragma unroll
        for (int mi = 0; mi < MTM; ++mi)
            #pragma unroll
            for (int ni = 0; ni < MTN; ++ni) {
                f32x4 cc = acc[mi][ni];
                cc = __builtin_amdgcn_mfma_f32_16x16x32_bf16(a0[mi], b0[ni], cc, 0, 0, 0);
                cc = __builtin_amdgcn_mfma_f32_16x16x32_bf16(a0[mi], b1[ni], cc, 0, 0, 0);
                if (alimb2)
                    cc = __builtin_amdgcn_mfma_f32_16x16x32_bf16(a1[mi], b0[ni], cc, 0, 0, 0);
                acc[mi][ni] = cc;
            }
        __syncthreads();
        cur ^= 1;
    }

    if (KS == 2) {   // cross-ksub reduce (alias At as f32 scratch)
        float* red = (float*)&At[0][0][0][0][0];
        if (ksub == 1) {
            #pragma unroll
            for (int mi = 0; mi < MTM; ++mi)
                #pragma unroll
                for (int ni = 0; ni < MTN; ++ni)
                    *(f32x4*)&red[(((quad * MTM + mi) * MTN + ni) * 64 + lane) * 4] =
                        acc[mi][ni];
        }
        __syncthreads();
        if (ksub == 0) {
            #pragma unroll
            for (int mi = 0; mi < MTM; ++mi)
                #pragma unroll
                for (int ni = 0; ni < MTN; ++ni) {
                    f32x4 o = *(const f32x4*)
                        &red[(((quad * MTM + mi) * MTN + ni) * 64 + lane) * 4];
                    acc[mi][ni][0] += o[0]; acc[mi][ni][1] += o[1];
                    acc[mi][ni][2] += o[2]; acc[mi][ni][3] += o[3];
                }
        }
    }

    const bool tp = (PoutT != nullptr) && (row0 >= tposeN);
    float* T = (float*)&Bt[0][0][0][0][0];   // 64x65 f32, Bt dead

    if (s2) {                               // dual: pure product (+planes/T)
        if (lead) {
            #pragma unroll
            for (int mi = 0; mi < MTM; ++mi)
                #pragma unroll
                for (int r = 0; r < 4; ++r) {
                    const int gr = row0 + wr + mi * 16 + koff * 4 + r;
                    if (gr >= M) continue;
                    const int prow = gr - seg2 + p2off;
                    #pragma unroll
                    for (int ni = 0; ni < MTN; ++ni) {
                        const int gc = col0 + wc + ni * 16 + l16;
                        float pv = acc[mi][ni][r];
                        if (Pout2) {
                            long f = swz((long)prow * 1024 + gc, 10);
                            unsigned short h0 = f2bf(pv);
                            Pout2[f] = h0;
                            Pout2[ppsz2 + f] = f2bf(pv - bf2f(h0));
                        }
                        if (tp) T[(wr + mi * 16 + koff * 4 + r) * 65 + gc - col0] = pv;
                    }
                }
        }
    } else {
        if (lead) {
            const long ofe = ofb + (long)segk * ofstep;
            const long cfe = cfb + (long)segk * ofstep;
            const bool pemit = (Pout != nullptr) && (segk < pseglim);
            #pragma unroll
            for (int mi = 0; mi < MTM; ++mi) {
                #pragma unroll
                for (int r = 0; r < 4; ++r) {
                    const int gr = row0 + wr + mi * 16 + koff * 4 + r;
                    if (gr >= M) continue;
                    const int trow = (((gr < segN) ? gr + zoff : gr)) & trmask;
                    if (gr < segN && trow >= segN) continue;
                    const float aa = (trow < asplit) ? alpha : alphaB;
                    const float bb = (trow < bzero) ? 0.f
                                    : ((trow < bsplit) ? beta : betaB);
                    #pragma unroll
                    for (int ni = 0; ni < MTN; ++ni) {
                        const int gc = col0 + wc + ni * 16 + l16;
                        float vp = aa * acc[mi][ni][r];
                        float v = vp;
                        if (bb != 0.f) {
                            int crow = trow & cmask;
                            if (Cf) v += bb * Cf[cfe + (long)crow * cfld + gc];
                            else if (Cp) {
                                long f = swz((long)crow * 1024 + gc, 10);
                                v += bb * (bf2f(Cp[f]) + bf2f(Cp[cpsz + f]));
                            }
                        }
                        if (add_id && gr == gc) v += 1.f;
                        if (Of) Of[ofe + (long)trow * ofld + gc] = v;
                        if (pemit && (!pstep8 || (trow & 7) == 0)) {
                            int prow = (pstep8 ? (trow >> 3) : trow) + segk * prowstep;
                            long f = swz((long)prow * 1024 + gc, 10);
                            float pv = (pmode == 2) ? vp : v;
                            unsigned short h0 = f2bf(pv);
                            Pout[f] = h0;
                            Pout[ppsz + f] = f2bf(pv - bf2f(h0));
                        }
                        if (tp) T[(wr + mi * 16 + koff * 4 + r) * 65 + gc - col0] = v;
                    }
                }
            }
        }
    }

    if (BM == 64 && tp) {                   // transposed plane emission
        __syncthreads();
        if (tid < 256) {
            const int i = tid >> 2;
            const int jb = (tid & 3) * 16;
            const int prow = col0 + i;
            #pragma unroll
            for (int e2 = 0; e2 < 16; ++e2) {
                int j = jb + e2;
                float v = T[j * 65 + i];
                long f = swz((long)prow * 1024 + (row0 - tposeN + j), 10);
                unsigned short h0 = f2bf(v);
                PoutT[f] = h0;
                PoutT[(long)(1 << 20) + f] = f2bf(v - bf2f(h0));
            }
        }
    }
}

// ---------------------------------------------------------------------------
// Fused prep: z=0 Am->PA planes; z=1 CH1 rows 0-1023 = I+(h/3)A^T;
// z=2/3 CH1 rows 1024+/1536+ = B^T/6, B^T/24; z=4 PBT = B^T; z=5 u->PU 1-limb.
// Grid (32,32,6) x 256 threads.
// ---------------------------------------------------------------------------
__global__ void prep_k(const float* __restrict__ Am, const float* __restrict__ Bm,
                       const float* __restrict__ u,
                       unsigned short* __restrict__ PA, unsigned short* __restrict__ CH1,
                       unsigned short* __restrict__ PBT, unsigned short* __restrict__ PU,
                       float h)
{
    const int z = blockIdx.z;
    const int tx = threadIdx.x & 31, ty4 = threadIdx.x >> 5;
    if (z == 0) {                          // straight split of Am
        const int r0 = blockIdx.x * 32, c0 = blockIdx.y * 32;
        #pragma unroll
        for (int i = 0; i < 4; ++i) {
            long e = (long)(r0 + ty4 * 4 + i) * 1024 + c0 + tx;
            float v = Am[e];
            long f = swz(e, 10);
            unsigned short h0 = f2bf(v);
            PA[f] = h0;
            PA[(long)(1 << 20) + f] = f2bf(v - bf2f(h0));
        }
        return;
    }
    if (z == 5) {                          // u -> 1-limb plane, grid-stride
        long base = ((long)blockIdx.y * 32 + blockIdx.x) * 256 + threadIdx.x;
        for (long i = base; i < (1L << 22); i += 262144)
            PU[swz(i, 9)] = f2bf(u[i]);
        return;
    }
    // trsp variants
    const int R = (z == 1) ? 1024 : 512;
    if (blockIdx.x * 32 >= R) return;
    const float s = (z == 1) ? h / 3.f : (z == 2) ? 1.f / 6.f
                   : (z == 3) ? 1.f / 24.f : 1.f;
    const int add_id = (z == 1) ? 1 : 0;
    const int roff = (z == 2) ? 1024 : (z == 3) ? 1536 : 0;
    unsigned short* P = (z == 4) ? PBT : CH1;
    const long psz = (z == 4) ? (long)(1 << 19) : (long)(1 << 21);
    const float* in = (z == 1) ? Am : Bm;

    __shared__ float t[32][33];
    const int r0 = blockIdx.x * 32, c0 = blockIdx.y * 32;
    #pragma unroll
    for (int i = 0; i < 4; ++i)
        t[ty4 * 4 + i][tx] = in[(long)(c0 + ty4 * 4 + i) * R + r0 + tx];
    __syncthreads();
    #pragma unroll
    for (int i = 0; i < 4; ++i) {
        int r = r0 + ty4 * 4 + i, c = c0 + tx;
        float v = s * t[tx][ty4 * 4 + i];
        if (add_id && r == c) v += 1.f;
        long f = swz((long)(r + roff) * 1024 + c, 10);
        unsigned short h0 = f2bf(v);
        P[f] = h0;
        P[psz + f] = f2bf(v - bf2f(h0));
    }
}

// ---------------------------------------------------------------------------
// Fused post-chain: z=0 tspp (PE = planes(E) from CH1 rows 0-1023);
// z=1,2 gtspp (PG = Gcat planes from CH1 rows 1024+). Grid (32,32,3).
// ---------------------------------------------------------------------------
__global__ void postchain_k(const unsigned short* __restrict__ CH1,
                            unsigned short* __restrict__ PE,
                            unsigned short* __restrict__ PG, float h)
{
    __shared__ float t[32][33];
    const int tx = threadIdx.x & 31, ty4 = threadIdx.x >> 5;
    const long P2 = 1 << 21;
    const int z = blockIdx.z;
    if (z == 0) {                          // planes(E): OUT[c][r] = CH1[r][c]
        const int r0 = blockIdx.x * 32, c0 = blockIdx.y * 32;
        #pragma unroll
        for (int i = 0; i < 4; ++i) {
            long f = swz((long)(r0 + ty4 * 4 + i) * 1024 + c0 + tx, 10);
            t[ty4 * 4 + i][tx] = bf2f(CH1[f]) + bf2f(CH1[P2 + f]);
        }
        __syncthreads();
        #pragma unroll
        for (int i = 0; i < 4; ++i) {
            int orow = c0 + ty4 * 4 + i;
            long f = swz((long)orow * 1024 + r0 + tx, 10);
            float v = t[tx][ty4 * 4 + i];
            unsigned short h0 = f2bf(v);
            PE[f] = h0;
            PE[(long)(1 << 20) + f] = f2bf(v - bf2f(h0));
        }
        return;
    }
    if (blockIdx.x >= 16) return;          // gtspp: k range 0..511
    const unsigned short* PV = CH1 + (1 << 20);   // rows 1024+ view
    const int k0 = blockIdx.x * 32, n0 = blockIdx.y * 32, zz = z - 1;
    #pragma unroll
    for (int i = 0; i < 4; ++i) {
        int k = k0 + ty4 * 4 + i, n = n0 + tx;
        long f2 = swz((long)(512 + k) * 1024 + n, 10);
        float v2 = bf2f(PV[f2]) + bf2f(PV[P2 + f2]);
        float v;
        if (zz == 0) {
            long f1 = swz((long)k * 1024 + n, 10);
            v = h * (bf2f(PV[f1]) + bf2f(PV[P2 + f1]) - v2);
        } else v = h * v2;
        t[ty4 * 4 + i][tx] = v;
    }
    __syncthreads();
    #pragma unroll
    for (int i = 0; i < 4; ++i) {
        int n = n0 + ty4 * 4 + i, kk = zz * 512 + k0 + tx;
        long f = swz((long)n * 1024 + kk, 10);
        float v = t[tx][ty4 * 4 + i];
        unsigned short h0 = f2bf(v);
        PG[f] = h0;
        PG[(long)(1 << 20) + f] = f2bf(v - bf2f(h0));
    }
}

// ---- X (cnt fp32, rows of length 2^ldsh) -> swizzled 2-limb planes ----
__global__ void split_pl_k(const float* __restrict__ X, unsigned short* __restrict__ P,
                           long psz, int ldsh, float s, long cnt)
{
    long i = (long)blockIdx.x * 256 + threadIdx.x;
    if (i >= cnt) return;
    float v = s * X[i];
    long f = swz(i, ldsh);
    unsigned short h0 = f2bf(v);
    P[f] = h0;
    P[psz + f] = f2bf(v - bf2f(h0));
}

// dst[db + r*ds + c] = src[sb + r*ss + c]
__global__ void copy_rows_k(float* __restrict__ dst, long db, long ds,
                            const float* __restrict__ src, long sb, long ss, int ncols)
{
    int r = blockIdx.y;
    int c = blockIdx.x * 256 + threadIdx.x;
    if (c < ncols) dst[db + (long)r * ds + c] = src[sb + (long)r * ss + c];
}

// dst[db + r*ds + c] += src[r*ncols + c]
__global__ void add_rows_k(float* __restrict__ dst, long db, long ds,
                           const float* __restrict__ src, int ncols)
{
    int r = blockIdx.y;
    int c = blockIdx.x * 256 + threadIdx.x;
    if (c < ncols) dst[db + (long)r * ds + c] += src[(long)r * ncols + c];
}

__global__ void scale_add_id_k(float* __restrict__ dst, const float* __restrict__ src,
                               float s, int n)
{
    int r = blockIdx.y;
    int c = blockIdx.x * 256 + threadIdx.x;
    if (c < n) dst[(long)r * n + c] = s * src[(long)r * n + c] + ((r == c) ? 1.f : 0.f);
}

__global__ void scale_copy_k(float* __restrict__ dst, const float* __restrict__ src,
                             float s, long cnt)
{
    long i = (long)blockIdx.x * 256 + threadIdx.x;
    if (i < cnt) dst[i] = s * src[i];
}

__global__ void g1g2_k(float* __restrict__ g1, float* __restrict__ g2,
                       const float* __restrict__ v1, const float* __restrict__ v2,
                       float h, long cnt)
{
    long i = (long)blockIdx.x * 256 + threadIdx.x;
    if (i < cnt) {
        float a = v1[i], b = v2[i];
        g1[i] = h * (a - b);
        g2[i] = h * b;
    }
}

// ---------------------------------------------------------------------------
// FALLBACK (round-3, 3-limb, 30 MB ws) — only if ws_size < 46 MB.
// ---------------------------------------------------------------------------
template <int BM, int BN, bool TRANSB>
__global__ __launch_bounds__(256) void gemm_mfma(
    const float* __restrict__ A, long ab, long lda,
    const float* __restrict__ B,
    const float* __restrict__ Cin, long cb, long ldc, float beta,
    float* __restrict__ Out, long ob, long ldo,
    int M, int Nn, int K, float alpha, int add_id)
{
    constexpr int LDT = 40;
    __shared__ unsigned short At[3][BM][LDT];
    __shared__ unsigned short Bt[3][BN][LDT];
    const int tid = threadIdx.x;
    const int lane = tid & 63;
    const int wid = tid >> 6;
    const int row0 = blockIdx.x * BM;
    const int col0 = blockIdx.y * BN;
    constexpr int MR = BM / 32;
    constexpr int NR = BN / 32;
    const int wrow = (wid >> 1) * (BM / 2);
    const int wcol = (wid & 1) * (BN / 2);
    const int l16 = lane & 15;
    const int koff = lane >> 4;
    f32x4 acc[MR][NR] = {};

    for (int k0 = 0; k0 < K; k0 += 32) {
        #pragma unroll
        for (int i = 0; i < BM / 32; ++i) {
            int r = i * 32 + (tid >> 3);
            int kl = (tid & 7) * 4;
            int gr = row0 + r;
            float4 v = make_float4(0.f, 0.f, 0.f, 0.f);
            if (gr < M) v = *(const float4*)&A[ab + (long)gr * lda + (k0 + kl)];
            unsigned short h0[4], h1[4], h2[4];
            split3(v.x, h0[0], h1[0], h2[0]);
            split3(v.y, h0[1], h1[1], h2[1]);
            split3(v.z, h0[2], h1[2], h2[2]);
            split3(v.w, h0[3], h1[3], h2[3]);
            *(ushort4*)&At[0][r][kl] = make_ushort4(h0[0], h0[1], h0[2], h0[3]);
            *(ushort4*)&At[1][r][kl] = make_ushort4(h1[0], h1[1], h1[2], h1[3]);
            *(ushort4*)&At[2][r][kl] = make_ushort4(h2[0], h2[1], h2[2], h2[3]);
        }
        if (TRANSB) {
            #pragma unroll
            for (int i = 0; i < BN / 32; ++i) {
                int r = i * 32 + (tid >> 3);
                int kl = (tid & 7) * 4;
                float4 v = *(const float4*)&B[(long)(col0 + r) * K + (k0 + kl)];
                unsigned short h0[4], h1[4], h2[4];
                split3(v.x, h0[0], h1[0], h2[0]);
                split3(v.y, h0[1], h1[1], h2[1]);
                split3(v.z, h0[2], h1[2], h2[2]);
                split3(v.w, h0[3], h1[3], h2[3]);
                *(ushort4*)&Bt[0][r][kl] = make_ushort4(h0[0], h0[1], h0[2], h0[3]);
                *(ushort4*)&Bt[1][r][kl] = make_ushort4(h1[0], h1[1], h1[2], h1[3]);
                *(ushort4*)&Bt[2][r][kl] = make_ushort4(h2[0], h2[1], h2[2], h2[3]);
            }
        } else {
            constexpr int TPK = BN / 4;
            #pragma unroll
            for (int i = 0; i < BN / 32; ++i) {
                int kl = i * (256 / TPK) + tid / TPK;
                int nl = (tid % TPK) * 4;
                float4 v = *(const float4*)&B[(long)(k0 + kl) * Nn + (col0 + nl)];
                unsigned short s0, s1, s2;
                split3(v.x, s0, s1, s2);
                Bt[0][nl + 0][kl] = s0; Bt[1][nl + 0][kl] = s1; Bt[2][nl + 0][kl] = s2;
                split3(v.y, s0, s1, s2);
                Bt[0][nl + 1][kl] = s0; Bt[1][nl + 1][kl] = s1; Bt[2][nl + 1][kl] = s2;
                split3(v.z, s0, s1, s2);
                Bt[0][nl + 2][kl] = s0; Bt[1][nl + 2][kl] = s1; Bt[2][nl + 2][kl] = s2;
                split3(v.w, s0, s1, s2);
                Bt[0][nl + 3][kl] = s0; Bt[1][nl + 3][kl] = s1; Bt[2][nl + 3][kl] = s2;
            }
        }
        __syncthreads();
        bf16x8 bf[NR][3];
        #pragma unroll
        for (int nr = 0; nr < NR; ++nr) {
            int brow = wcol + nr * 16 + l16;
            #pragma unroll
            for (int s = 0; s < 3; ++s)
                bf[nr][s] = *(const bf16x8*)&Bt[s][brow][koff * 8];
        }
        #pragma unroll
        for (int mr = 0; mr < MR; ++mr) {
            int arow = wrow + mr * 16 + l16;
            bf16x8 a0 = *(const bf16x8*)&At[0][arow][koff * 8];
            bf16x8 a1 = *(const bf16x8*)&At[1][arow][koff * 8];
            bf16x8 a2 = *(const bf16x8*)&At[2][arow][koff * 8];
            #pragma unroll
            for (int nr = 0; nr < NR; ++nr) {
                f32x4 c = acc[mr][nr];
                c = __builtin_amdgcn_mfma_f32_16x16x32_bf16(a0, bf[nr][0], c, 0, 0, 0);
                c = __builtin_amdgcn_mfma_f32_16x16x32_bf16(a0, bf[nr][1], c, 0, 0, 0);
                c = __builtin_amdgcn_mfma_f32_16x16x32_bf16(a1, bf[nr][0], c, 0, 0, 0);
                c = __builtin_amdgcn_mfma_f32_16x16x32_bf16(a0, bf[nr][2], c, 0, 0, 0);
                c = __builtin_amdgcn_mfma_f32_16x16x32_bf16(a1, bf[nr][1], c, 0, 0, 0);
                c = __builtin_amdgcn_mfma_f32_16x16x32_bf16(a2, bf[nr][0], c, 0, 0, 0);
                acc[mr][nr] = c;
            }
        }
        __syncthreads();
    }
    #pragma unroll
    for (int mr = 0; mr < MR; ++mr) {
        #pragma unroll
        for (int r = 0; r < 4; ++r) {
            int gr = row0 + wrow + mr * 16 + koff * 4 + r;
            if (gr >= M) continue;
            #pragma unroll
            for (int nr = 0; nr < NR; ++nr) {
                int gc = col0 + wcol + nr * 16 + l16;
                float v = alpha * acc[mr][nr][r];
                if (Cin) v += beta * Cin[cb + (long)gr * ldc + gc];
                if (add_id && gr == gc) v += 1.f;
                Out[ob + (long)gr * ldo + gc] = v;
            }
        }
    }
}

static void fallback_launch(void* const* d_in, void* d_out, void* d_ws,
                            hipStream_t stream)
{
    const float* y0 = (const float*)d_in[1];
    const float* u  = (const float*)d_in[2];
    const float* Am = (const float*)d_in[3];
    const float* Bm = (const float*)d_in[4];
    float* Yout = (float*)d_out;
    float* w = (float*)d_ws;
    const float h = 0.01f;
    const int N = GN;

    float* Eyy = w;
    float* T1  = Eyy + (long)N * N;
    float* T2  = T1  + (long)N * N;
    float* V1  = T2  + (long)N * N;
    float* Vt  = V1  + (long)N * GM;
    float* V2  = Vt  + (long)N * GM;
    float* G1  = V2  + (long)N * GM;
    float* G2  = G1  + (long)N * GM;
    float* Z   = G2  + (long)N * GM;
    float* Zt  = Z   + (long)CCH * N;
    dim3 blk(256);

    auto gemm = [&](bool transb, const float* A, long ab, long lda,
                    const float* B, const float* Cin, long cb, long ldc, float beta,
                    float* Out, long ob, long ldo,
                    int M, int Nn, int K, float alpha, int add_id) {
        if (M > 1536 && (Nn % 128) == 0) {
            dim3 grid((M + 127) / 128, Nn / 128);
            if (transb)
                gemm_mfma<128, 128, true><<<grid, blk, 0, stream>>>(A, ab, lda, B, Cin, cb, ldc, beta, Out, ob, ldo, M, Nn, K, alpha, add_id);
            else
                gemm_mfma<128, 128, false><<<grid, blk, 0, stream>>>(A, ab, lda, B, Cin, cb, ldc, beta, Out, ob, ldo, M, Nn, K, alpha, add_id);
        } else {
            dim3 grid((M + 63) / 64, Nn / 64);
            if (transb)
                gemm_mfma<64, 64, true><<<grid, blk, 0, stream>>>(A, ab, lda, B, Cin, cb, ldc, beta, Out, ob, ldo, M, Nn, K, alpha, add_id);
            else
                gemm_mfma<64, 64, false><<<grid, blk, 0, stream>>>(A, ab, lda, B, Cin, cb, ldc, beta, Out, ob, ldo, M, Nn, K, alpha, add_id);
        }
    };

    scale_add_id_k<<<dim3(4, N), blk, 0, stream>>>(T1, Am, h / 5.f, N);
    {
        float* pc = T1; float* pn = T2;
        for (int k = 4; k >= 1; --k) {
            float* out = (k == 1) ? Eyy : pn;
            gemm(false, Am, 0, N, pc, nullptr, 0, 0, 0.f, out, 0, N, N, N, N, h / (float)k, 1);
            pn = pc; pc = out;
        }
    }
    const long NM = (long)N * GM;
    scale_copy_k<<<dim3((unsigned)((NM + 255) / 256)), blk, 0, stream>>>(V1, Bm, 1.f / 120.f, NM);
    {
        const float f1[4] = {1.f / 24.f, 1.f / 6.f, 0.5f, 1.f};
        float* pc = V1; float* pn = Vt;
        for (int j = 3; j >= 0; --j) {
            gemm(false, Am, 0, N, pc, Bm, 0, GM, f1[3 - j], pn, 0, GM, N, GM, N, h, 0);
            float* t = pc; pc = pn; pn = t;
        }
    }
    scale_copy_k<<<dim3((unsigned)((NM + 255) / 256)), blk, 0, stream>>>(V2, Bm, 1.f / 720.f, NM);
    {
        const float f2[4] = {1.f / 120.f, 1.f / 24.f, 1.f / 6.f, 0.5f};
        float* pc = V2; float* pn = Vt;
        for (int j = 3; j >= 0; --j) {
            gemm(false, Am, 0, N, pc, Bm, 0, GM, f2[3 - j], pn, 0, GM, N, GM, N, h, 0);
            float* t = pc; pc = pn; pn = t;
        }
    }
    g1g2_k<<<dim3((unsigned)((NM + 255) / 256)), blk, 0, stream>>>(G1, G2, V1, V2, h, NM);
    gemm(true, u, 0, GM, G1, nullptr, 0, 0, 0.f, Yout, (long)N, N, GT - 1, N, GM, 1.f, 0);
    gemm(true, u, GM, GM, G2, Yout, (long)N, N, 1.f, Yout, (long)N, N, GT - 1, N, GM, 1.f, 0);
    copy_rows_k<<<dim3(4, 1), blk, 0, stream>>>(Yout, 0, 0, y0, 0, 0, N);
    for (int s = 2; s <= SCH; ++s) {
        int Mr = (GT - 1 - s) / SCH + 1;
        gemm(true, Yout, (long)(s - 1) * N, (long)SCH * N, Eyy,
             Yout, (long)s * N, (long)SCH * N, 1.f,
             Yout, (long)s * N, (long)SCH * N, Mr, N, N, 1.f, 0);
    }
    copy_rows_k<<<dim3(4, 1), blk, 0, stream>>>(Z, 0, 0, y0, 0, 0, N);
    copy_rows_k<<<dim3(4, CCH - 1), blk, 0, stream>>>(Z, (long)N, (long)N,
                                                      Yout, (long)SCH * N, (long)SCH * N, N);
    gemm(false, Eyy, 0, N, Eyy, nullptr, 0, 0, 0.f, T1, 0, N, N, N, N, 1.f, 0);
    gemm(false, T1, 0, N, T1, nullptr, 0, 0, 0.f, T2, 0, N, N, N, N, 1.f, 0);
    gemm(false, T2, 0, N, T2, nullptr, 0, 0, 0.f, T1, 0, N, N, N, N, 1.f, 0);
    {
        float* Mc = T1; float* Mo = T2;
        float* Zc = Z;  float* Zn = Zt;
        for (int p = 0; p < 10; ++p) {
            int o = 1 << p;
            gemm(true, Zc, 0, N, Mc, Zc, (long)o * N, N, 1.f,
                 Zn, (long)o * N, N, CCH - o, N, N, 1.f, 0);
            copy_rows_k<<<dim3(4, o), blk, 0, stream>>>(Zn, 0, N, Zc, 0, N, N);
            if (p < 9) {
                gemm(false, Mc, 0, N, Mc, nullptr, 0, 0, 0.f, Mo, 0, N, N, N, N, 1.f, 0);
                float* t = Mc; Mc = Mo; Mo = t;
            }
            float* t = Zc; Zc = Zn; Zn = t;
        }
        copy_rows_k<<<dim3(4, CCH), blk, 0, stream>>>(Yout, 0, (long)SCH * N, Zc, 0, N, N);
        float* Q = Zc; float* Qt = Zn;
        for (int s = 1; s <= SCH - 1; ++s) {
            gemm(true, Q, 0, N, Eyy, nullptr, 0, 0, 0.f, Qt, 0, N, CCH, N, N, 1.f, 0);
            int Mr = (GT - 1 - s) / SCH + 1;
            add_rows_k<<<dim3(4, Mr), blk, 0, stream>>>(Yout, (long)s * N, (long)SCH * N, Qt, N);
            float* t = Q; Q = Qt; Qt = t;
        }
    }
}

// ---------------------------------------------------------------------------
extern "C" void kernel_launch(void* const* d_in, const int* in_sizes, int n_in,
                              void* d_out, int out_size, void* d_ws, size_t ws_size,
                              hipStream_t stream)
{
    (void)in_sizes; (void)n_in; (void)out_size;
    const size_t NEED = 46ull * 1024 * 1024;
    if (ws_size < NEED) { fallback_launch(d_in, d_out, d_ws, stream); return; }

    const float* y0 = (const float*)d_in[1];
    const float* u  = (const float*)d_in[2];
    const float* Am = (const float*)d_in[3];
    const float* Bm = (const float*)d_in[4];
    float* Yout = (float*)d_out;
    char* w = (char*)d_ws;
    const float h = 0.01f;
    const size_t MB = 1024 * 1024;
    const long PP  = 1 << 20;
    const long P2  = 1 << 21;
    const long P4  = 1 << 22;
    const int  BIG = 1 << 30;

    // ws layout (46 MB, time-phased):
    unsigned short* PU   = (unsigned short*)(w);            // [0,8)   u 1-limb plane
    unsigned short* PZW1 = (unsigned short*)(w);            // [0,8)   z+W^T ping
    unsigned short* PA   = (unsigned short*)(w + 8 * MB);   // [8,12)  planes(Am)
    unsigned short* SQa  = (unsigned short*)(w + 8 * MB);   // [8,12)  E^2T
    unsigned short* SQb  = (unsigned short*)(w + 12 * MB);  // [12,16) E^4T
    unsigned short* PZW2 = (unsigned short*)(w + 8 * MB);   // [8,16)  z pong
    unsigned short* CH1  = (unsigned short*)(w + 16 * MB);  // [16,24) chain ping
    unsigned short* WA   = (unsigned short*)(w + 16 * MB);  // [16,20) w-slot / PWt pong
    unsigned short* PWt0 = (unsigned short*)(w + 20 * MB);  // [20,24) E^8 planes / PWt ping
    unsigned short* CH2  = (unsigned short*)(w + 24 * MB);  // [24,32) chain pong
    unsigned short* WB   = (unsigned short*)(w + 24 * MB);  // [24,28) w-slot
    unsigned short* PE   = (unsigned short*)(w + 28 * MB);  // [28,32) planes(E) = PWR+0
    unsigned short* PG   = (unsigned short*)(w + 32 * MB);  // [32,36) Gcat -> E^2
    unsigned short* PW2  = PG;
    unsigned short* PW3  = (unsigned short*)(w + 36 * MB);  // [36,40) w2 -> planes(E^3)
    unsigned short* PW4  = (unsigned short*)(w + 40 * MB);  // [40,44) planes(E^4)
    unsigned short* PBT  = (unsigned short*)(w + 44 * MB);  // [44,46) planes(B^T)
    unsigned short* QPL  = (unsigned short*)(w + 8 * MB);   // [8,24)  Q planes (phase3)
    unsigned short* PWR  = PE;                              // powers table base

    dim3 blk(256), blk5(512);

    // ---- 1. fused prep: Am planes, chain seeds, B^T planes, u plane ----
    prep_k<<<dim3(32, 32, 6), blk, 0, stream>>>(Am, Bm, u, PA, CH1, PBT, PU, h);
    // z_0 = y0 -> PZW1 plane row 0 (early; no deps; PZW1 region untouched until doubling)
    split_pl_k<<<dim3(4), blk, 0, stream>>>(y0, PZW1, P2, 10, 1.f, 1024);

    // ---- 2. fused chain x2: exp deg-3 (rows<1024) + phi 3-term (rows 1024+) ----
    {
        const float alE[2] = {h / 2.f, h};
        const float f1[2] = {0.5f, 1.f};
        const float f2[2] = {1.f / 6.f, 0.5f};
        unsigned short* cc = CH1; unsigned short* cn = CH2;
        for (int j = 0; j < 2; ++j) {
            gemm_pp<64, 2, 2><<<dim3(32, 16), blk5, 0, stream>>>(
                cc, P2, 1024, 10, 1, -1, 0, 0,
                PA, PP, 0,
                nullptr, 0, 0, PBT, (long)(1 << 19), 511,
                1024, 1536, f1[j], f2[j],
                nullptr, 0, 0, 0,
                cn, P2, 0, 1, 0, BIG,
                BIG, 0, -1,
                2048, alE[j], h, 1024, 1,
                nullptr, 0, nullptr, nullptr, 0, 0, BIG, nullptr, BIG, 0);
            unsigned short* t = cc; cc = cn; cn = t;
        }  // 2 swaps -> final in CH1
    }
    // ---- 3. fused post-chain: PE = planes(E); PG = Gcat planes ----
    postchain_k<<<dim3(32, 32, 3), blk, 0, stream>>>(CH1, PE, PG, h);

    // ---- 4. c-staging (A 1-limb): Yout[t] = [u_{t-1}|u_t]@Gcat^T
    //      + w1 planes (rows 8i+1) -> WB ----
    gemm_pp<128, 4, 1><<<dim3(64, 8), blk5, 0, stream>>>(
        PU, 0, 512, 9, 0, -1, 0, 0,
        PG, PP, 0,
        nullptr, 0, 0, nullptr, 0, -1,
        0, BIG, 0.f, 0.f,
        Yout, 1024, 1024, 0,
        WB, PP, 1, 1, 0, BIG,
        BIG, 0, -1,
        GT - 1, 1.f, 1.f, BIG, 0,
        nullptr, 0, nullptr, nullptr, 0, 0, BIG, nullptr, BIG, 0);

    // ---- 5. phase 1 (serial s=2..8) fused with E-squarings + E^3 power ----
    // F1: s=2 | dual: E^2T = E^T@planes(E) -> SQa ; PoutT: planes(E^2) -> PW2
    gemm_pp<64, 2, 2><<<dim3(32, 16), blk5, 0, stream>>>(
        WB, PP, 1024, 10, 1, -1, 0, 0,
        PE, PP, 0,
        Yout, 2 * 1024, 8192, nullptr, 0, -1,
        0, BIG, 1.f, 0.f,
        Yout, 2 * 1024, 8192, 0,
        PW3, PP, 0, 1, 0, BIG,
        BIG, 0, -1,
        2048, 1.f, 1.f, BIG, 0,
        CH1, P2, PE, SQa, PP, 0, 1024, PW2, 1024, 0);
    // F2: s=3 | dual: E^4T = E^2T@planes(E^2) -> SQb ; PoutT: planes(E^4) -> PW4
    gemm_pp<64, 2, 2><<<dim3(32, 16), blk5, 0, stream>>>(
        PW3, PP, 1024, 10, 1, -1, 0, 0,
        PE, PP, 0,
        Yout, 3 * 1024, 8192, nullptr, 0, -1,
        0, BIG, 1.f, 0.f,
        Yout, 3 * 1024, 8192, 0,
        WB, PP, 0, 1, 0, BIG,
        BIG, 0, -1,
        2048, 1.f, 1.f, BIG, 0,
        SQa, PP, PW2, SQb, PP, 0, 1024, PW4, 1024, 0);
    // F3: s=4 | dual: E^8T -> PZW1 rows 1024+ ; PoutT: planes(E^8) -> PWt0
    gemm_pp<64, 2, 2><<<dim3(32, 16), blk5, 0, stream>>>(
        WB, PP, 1024, 10, 1, -1, 0, 0,
        PE, PP, 0,
        Yout, 4 * 1024, 8192, nullptr, 0, -1,
        0, BIG, 1.f, 0.f,
        Yout, 4 * 1024, 8192, 0,
        WA, PP, 0, 1, 0, BIG,
        BIG, 0, -1,
        2048, 1.f, 1.f, BIG, 0,
        SQb, PP, PW4, PZW1, P2, 1024, 1024, PWt0, 1024, 0);
    // s=5 | dual: E^3T = E^2T@planes(E) ; PoutT: planes(E^3) -> PW3
    gemm_pp<64, 2, 2><<<dim3(32, 16), blk5, 0, stream>>>(
        WA, PP, 1024, 10, 1, -1, 0, 0,
        PE, PP, 0,
        Yout, 5 * 1024, 8192, nullptr, 0, -1,
        0, BIG, 1.f, 0.f,
        Yout, 5 * 1024, 8192, 0,
        WB, PP, 0, 1, 0, BIG,
        BIG, 0, -1,
        2048, 1.f, 1.f, BIG, 0,
        SQa, PP, PE, nullptr, 0, 0, 1024, PW3, 1024, 0);
    // s=6, s=7 solo
    gemm_pp<64, 2, 2><<<dim3(16, 16), blk5, 0, stream>>>(
        WB, PP, 1024, 10, 1, -1, 0, 0,
        PE, PP, 0,
        Yout, 6 * 1024, 8192, nullptr, 0, -1,
        0, BIG, 1.f, 0.f,
        Yout, 6 * 1024, 8192, 0,
        WA, PP, 0, 1, 0, BIG,
        BIG, 0, -1,
        1024, 1.f, 1.f, BIG, 0,
        nullptr, 0, nullptr, nullptr, 0, 0, BIG, nullptr, BIG, 0);
    gemm_pp<64, 2, 2><<<dim3(16, 16), blk5, 0, stream>>>(
        WA, PP, 1024, 10, 1, -1, 0, 0,
        PE, PP, 0,
        Yout, 7 * 1024, 8192, nullptr, 0, -1,
        0, BIG, 1.f, 0.f,
        Yout, 7 * 1024, 8192, 0,
        WB, PP, 0, 1, 0, BIG,
        BIG, 0, -1,
        1024, 1.f, 1.f, BIG, 0,
        nullptr, 0, nullptr, nullptr, 0, 0, BIG, nullptr, BIG, 0);
    // s=8 -> boundary rows 8(i+1): z planes -> PZW1 rows 1..1023 (zoff=1)
    gemm_pp<64, 2, 2><<<dim3(16, 16), blk5, 0, stream>>>(
        WB, PP, 1024, 10, 1, -1, 0, 0,
        PE, PP, 0,
        Yout, 0, 8192, nullptr, 0, -1,
        0, BIG, 1.f, 0.f,
        Yout, 0, 8192, 0,
        PZW1, P2, 0, 1, 0, BIG,
        BIG, 1, -1,
        1023, 1.f, 1.f, BIG, 0,
        nullptr, 0, nullptr, nullptr, 0, 0, BIG, nullptr, BIG, 0);

    // ---- 6. fused doubling: one GEMM per round, W-transpose in epilogue ----
    {
        unsigned short* PZc = PZW1; unsigned short* PZn = PZW2;
        for (int p = 0; p < 10; ++p) {
            int o = 1 << p;
            int Mr = (p == 9) ? 1024 : 2048;
            unsigned short* PWc = (p & 1) ? WA : PWt0;
            unsigned short* PWn = (p & 1) ? PWt0 : WA;
            gemm_pp<64, 2, 2><<<dim3(Mr / 64, 16), blk5, 0, stream>>>(
                PZc, P2, 1024, 10, 1, -1, o, 1024,
                PWc, PP, 0,
                nullptr, 0, 0,
                PZc, P2, 0x7fffffff,
                0, 1024, 1.f, 0.f,
                (p == 9) ? Yout : nullptr, 0, 8192, 0,
                PZn, P2, 0, 1, 0, BIG,
                1024, 0, -1,
                Mr, 0.f, 1.f, o, 0,
                nullptr, 0, nullptr, nullptr, 0, 0, BIG,
                (p < 9) ? PWn : nullptr, 1024, 0);
            unsigned short* t = PZc; PZc = PZn; PZn = t;
        }  // final Z planes in PZW1; Yout[8i] = z_i written at p=9 (incl. row 0)
    }

    // ---- 7. phase 3 via powers: L1 [Q1..Q4]=Z@[E..E^4]^T (XCD seg-swizzled;
    //      plane-emit only Q1..Q3) ; L2 [Q5..Q7]=[Q1..Q3]@E^4T ----
    gemm_pp<64, 2, 2><<<dim3(64, 16), blk5, 0, stream>>>(
        PZW1, P2, 1024, 10, 1, 1023, 0, 0,      // A row = gr & 1023 (Z)
        PWR, PP, (long)(1 << 21),               // B = powers[row0>>10]
        Yout, 1024, 8192, nullptr, 0, -1,
        0, BIG, 1.f, 0.f,
        Yout, 1024, 8192, 1024,                 // s = 1 + segk
        QPL, P4, 0, 2, 1024, 3,                 // Q planes, only segk<3
        0, 0, 1023,
        4096, 1.f, 1.f, BIG, 0,
        nullptr, 0, nullptr, nullptr, 0, 0, BIG, nullptr, BIG, 4);
    gemm_pp<64, 2, 2><<<dim3(48, 16), blk5, 0, stream>>>(
        QPL, P4, 1024, 10, 1, -1, 0, 0,         // A row = gr (Q1..Q3)
        PW4, PP, 0,
        Yout, 5 * 1024, 8192, nullptr, 0, -1,
        0, BIG, 1.f, 0.f,
        Yout, 5 * 1024, 8192, 1024,             // s = 5 + segk
        nullptr, 0, 0, 1, 0, BIG,
        0, 0, 1023,
        3072, 1.f, 1.f, BIG, 0,
        nullptr, 0, nullptr, nullptr, 0, 0, BIG, nullptr, BIG, 0);
}